// Round 2
// baseline (7034.192 us; speedup 1.0000x reference)
//
#include <hip/hip_runtime.h>
#include <hip/hip_bf16.h>
#include <math.h>

// Model_45904610459674: FEDformer-style forecaster, fp32 baseline, compact ws.
// B=128, SEQ=96, DEC_LEN=144, D_MODEL=512, H=8, E=64, D_FF=2048, C=7, NF=4
// M_ENC=48, M_DEC=64, M_KV=48, KMA=25.
// fourier_block uses only q; fourier_cross uses only q,k -> dead k/v
// projections are skipped entirely.
// Workspace plan (floats), liveness-aliased, total 53,735,424 fl = 214.9 MB:
//   T1  9437184 | T2 9437184 (also Q-modes/V) | XD 9437184 | TS 9437184
//   XE  6291456 | POOL 9437184 (K-modes / WT / FFN hidden chunk) | SI/TI 129024 ea

#define PI_F 3.14159265358979323846f

static __device__ __forceinline__ int iclamp(int v, int lo, int hi) {
    return v < lo ? lo : (v > hi ? hi : v);
}

__global__ void zero_out_kernel(float* __restrict__ out, int n) {
    int i = blockIdx.x * 256 + threadIdx.x;
    if (i < n) out[i] = 0.f;
}

// ---------------------------------------------------------------------------
// preprocess: series_decomp(x_enc) -> seasonal_init [B,144,7], trend_init [B,144,7]
__global__ void preprocess_kernel(const float* __restrict__ xe,
                                  float* __restrict__ SI, float* __restrict__ TI) {
    int idx = blockIdx.x * 256 + threadIdx.x;
    if (idx >= 128 * 144 * 7) return;
    int c = idx % 7;
    int l = (idx / 7) % 144;
    int b = idx / (7 * 144);
    const float* xb = xe + (size_t)b * 96 * 7;
    if (l < 48) {
        int p = 48 + l;
        float sum = 0.f;
        for (int j = -12; j <= 12; j++) sum += xb[iclamp(p + j, 0, 95) * 7 + c];
        float ma = sum * (1.0f / 25.0f);
        SI[idx] = xb[p * 7 + c] - ma;
        TI[idx] = ma;
    } else {
        SI[idx] = 0.f;
        float m = 0.f;
        for (int l2 = 0; l2 < 96; l2++) m += xb[l2 * 7 + c];
        TI[idx] = m * (1.0f / 96.0f);
    }
}

// ---------------------------------------------------------------------------
// embed: circular conv1d(k=3) over C=7 + mark @ time_w.T  -> [B,L,512]
__global__ void embed_kernel(const float* __restrict__ x, const float* __restrict__ mark,
                             const float* __restrict__ cw, const float* __restrict__ tw,
                             float* __restrict__ out, int L) {
    size_t idx = (size_t)blockIdx.x * 256 + threadIdx.x;
    if (idx >= (size_t)128 * L * 512) return;
    int o = idx & 511;
    int l = (int)((idx >> 9) % L);
    int b = (int)(idx / ((size_t)512 * L));
    int lm = (l == 0) ? L - 1 : l - 1;
    int lp = (l == L - 1) ? 0 : l + 1;
    const float* x0 = x + (size_t)b * L * 7;
    float v = 0.f;
#pragma unroll
    for (int c = 0; c < 7; c++) {
        const float* w = cw + (o * 7 + c) * 3;
        v += x0[lm * 7 + c] * w[0] + x0[l * 7 + c] * w[1] + x0[lp * 7 + c] * w[2];
    }
    const float* mk = mark + ((size_t)b * L + l) * 4;
#pragma unroll
    for (int f = 0; f < 4; f++) v += mk[f] * tw[o * 4 + f];
    out[idx] = v;
}

// ---------------------------------------------------------------------------
// GEMM: C[r,n] = [accum? C[r,n]:0] + sum_k A[r,k]*W[n,k] (+bias) (+exact GELU).
// 128x128 tile, BK=16, 256 threads, 8x8 micro-tile. rows%128==0, N%128==0, K%16==0.
__global__ __launch_bounds__(256) void gemm_nt(
    const float* __restrict__ A, const float* __restrict__ W,
    const float* __restrict__ bias, float* __restrict__ C,
    int N, int K, int lda, int ldw, int gelu, int accum) {
    __shared__ float As[16][132];
    __shared__ float Ws[16][132];
    const int tid = threadIdx.x;
    const int tx = tid & 15, ty = tid >> 4;
    const size_t bm = (size_t)blockIdx.y * 128;
    const size_t bn = (size_t)blockIdx.x * 128;
    float acc[8][8];
#pragma unroll
    for (int i = 0; i < 8; i++)
#pragma unroll
        for (int j = 0; j < 8; j++) acc[i][j] = 0.f;

    for (int k0 = 0; k0 < K; k0 += 16) {
        for (int j = tid; j < 512; j += 256) {
            int r = j >> 2, c4 = (j & 3) << 2;
            const float4 a = *(const float4*)(A + (bm + r) * lda + k0 + c4);
            As[c4 + 0][r] = a.x; As[c4 + 1][r] = a.y;
            As[c4 + 2][r] = a.z; As[c4 + 3][r] = a.w;
            const float4 b = *(const float4*)(W + (bn + r) * ldw + k0 + c4);
            Ws[c4 + 0][r] = b.x; Ws[c4 + 1][r] = b.y;
            Ws[c4 + 2][r] = b.z; Ws[c4 + 3][r] = b.w;
        }
        __syncthreads();
#pragma unroll
        for (int kk = 0; kk < 16; kk++) {
            float a[8], b[8];
            *(float4*)(a)     = *(const float4*)(&As[kk][ty * 8]);
            *(float4*)(a + 4) = *(const float4*)(&As[kk][ty * 8 + 4]);
            *(float4*)(b)     = *(const float4*)(&Ws[kk][tx * 8]);
            *(float4*)(b + 4) = *(const float4*)(&Ws[kk][tx * 8 + 4]);
#pragma unroll
            for (int i = 0; i < 8; i++)
#pragma unroll
                for (int j = 0; j < 8; j++) acc[i][j] = fmaf(a[i], b[j], acc[i][j]);
        }
        __syncthreads();
    }
#pragma unroll
    for (int i = 0; i < 8; i++) {
        float* crow = C + (bm + ty * 8 + i) * N + bn + tx * 8;
#pragma unroll
        for (int j = 0; j < 8; j++) {
            float v = acc[i][j];
            if (bias) v += bias[bn + tx * 8 + j];
            if (gelu) v = 0.5f * v * (1.f + erff(v * 0.70710678118654752f));
            if (accum) v += crow[j];
            crow[j] = v;
        }
    }
}

// ---------------------------------------------------------------------------
// DFT: Q [B,L,512] -> X[b,h,e,m] (float2), m < M, X[m]=sum_l q[l] e^{-2pi i m l / L}
__global__ void dft_kernel(const float* __restrict__ Q, float2* __restrict__ X,
                           int L, int M) {
    int b = blockIdx.x, h = blockIdx.y;
    __shared__ float q[144 * 64];
    __shared__ float2 tw[144];
    for (int i = threadIdx.x; i < L * 64; i += 256) {
        int l = i >> 6, e = i & 63;
        q[i] = Q[((size_t)b * L + l) * 512 + h * 64 + e];
    }
    for (int k = threadIdx.x; k < L; k += 256) {
        float a = -2.f * PI_F * (float)k / (float)L;
        tw[k] = make_float2(cosf(a), sinf(a));
    }
    __syncthreads();
    for (int i = threadIdx.x; i < 64 * M; i += 256) {
        int e = i / M, m = i - e * M;
        float re = 0.f, im = 0.f;
        int k = 0;
        for (int l = 0; l < L; l++) {
            float v = q[l * 64 + e];
            float2 t = tw[k];
            re = fmaf(v, t.x, re);
            im = fmaf(v, t.y, im);
            k += m; if (k >= L) k -= L;
        }
        X[(((size_t)b * 8 + h) * 64 + e) * M + m] = make_float2(re, im);
    }
}

// ---------------------------------------------------------------------------
// transpose fourier weights [H,E,O,M,(re,im)] -> WT[(h*M+m)*4096 + e*64 + o] float2
__global__ void wtrans_kernel(const float* __restrict__ w, float2* __restrict__ WT, int M) {
    size_t i = (size_t)blockIdx.x * 256 + threadIdx.x;
    if (i >= (size_t)8 * M * 4096) return;
    int hm = (int)(i >> 12);
    int r = (int)(i & 4095);
    int e = r >> 6, o = r & 63;
    int h = hm / M, m = hm - h * M;
    size_t src = ((((size_t)h * 64 + e) * 64 + o) * M + m) * 2;
    WT[i] = make_float2(w[src], w[src + 1]);
}

// mode mix: Y[b,h,o,m] = sum_e X[b,h,e,m] * W[h,e,o,m]   (complex)
__global__ void mix_kernel(const float2* __restrict__ X, const float2* __restrict__ WT,
                           float2* __restrict__ Y, int M) {
    int hm = blockIdx.x;
    int h = hm / M, m = hm - h * M;
    int b0 = blockIdx.y * 32;
    __shared__ float2 Ws[4096];  // [e*64+o]
    __shared__ float2 Xs[2048];  // [bb*64+e]
    const float2* wsrc = WT + (size_t)hm * 4096;
    for (int i = threadIdx.x; i < 4096; i += 256) Ws[i] = wsrc[i];
    for (int i = threadIdx.x; i < 2048; i += 256) {
        int bb = i >> 6, e = i & 63;
        Xs[i] = X[(((size_t)(b0 + bb) * 8 + h) * 64 + e) * M + m];
    }
    __syncthreads();
    for (int i = threadIdx.x; i < 2048; i += 256) {
        int bb = i >> 6, o = i & 63;
        float re = 0.f, im = 0.f;
        const float2* xr = &Xs[bb * 64];
#pragma unroll 8
        for (int e = 0; e < 64; e++) {
            float2 xv = xr[e];
            float2 wv = Ws[e * 64 + o];
            re += xv.x * wv.x - xv.y * wv.y;
            im += xv.x * wv.y + xv.y * wv.x;
        }
        Y[(((size_t)(b0 + bb) * 8 + h) * 64 + o) * M + m] = make_float2(re, im);
    }
}

// ---------------------------------------------------------------------------
// iDFT of M-sparse spectrum (+ torch .view quirk layout):
// out[b*(L*512) + h*64*L + o*L + l] = s*(Re S0 + 2*sum_{m=1}^{M-1} Re(S_m e^{+2pi i m l/L}))
__global__ void idft_kernel(const float2* __restrict__ Y, float* __restrict__ out,
                            int L, int M, float s) {
    int b = blockIdx.x, h = blockIdx.y;
    __shared__ float2 S[4096];
    __shared__ float2 tw[144];
    const float2* src = Y + (((size_t)b * 8 + h) * 64) * M;
    for (int i = threadIdx.x; i < 64 * M; i += 256) S[i] = src[i];
    for (int k = threadIdx.x; k < L; k += 256) {
        float a = 2.f * PI_F * (float)k / (float)L;
        tw[k] = make_float2(cosf(a), sinf(a));
    }
    __syncthreads();
    for (int i = threadIdx.x; i < 64 * L; i += 256) {
        int o = i / L, l = i - o * L;
        const float2* Sr = &S[o * M];
        float sum = 0.f;
        int kk = l;
        for (int m = 1; m < M; m++) {
            float2 t = tw[kk];
            float2 sv = Sr[m];
            sum += sv.x * t.x - sv.y * t.y;
            kk += l; if (kk >= L) kk -= L;
        }
        float acc = Sr[0].x + 2.f * sum;
        out[(size_t)b * (L * 512) + (size_t)h * 64 * L + i] = acc * s;
    }
}

// ---------------------------------------------------------------------------
// cross-attn: G[b,h,x,y] = ctanh(sum_e Q[b,h,e,x] * K[b,h,e,y]); x<64, y<48
__global__ void xqk_kernel(const float2* __restrict__ XQ, const float2* __restrict__ XK,
                           float2* __restrict__ G) {
    int b = blockIdx.x, h = blockIdx.y;
    __shared__ float2 Qs[4096];  // [e*64+x]
    __shared__ float2 Ks[3072];  // [e*48+y]
    const float2* qs = XQ + ((size_t)b * 8 + h) * 4096;
    const float2* ks = XK + ((size_t)b * 8 + h) * 3072;
    for (int i = threadIdx.x; i < 4096; i += 256) Qs[i] = qs[i];
    for (int i = threadIdx.x; i < 3072; i += 256) Ks[i] = ks[i];
    __syncthreads();
    for (int i = threadIdx.x; i < 64 * 48; i += 256) {
        int x = i / 48, y = i - x * 48;
        float re = 0.f, im = 0.f;
#pragma unroll 8
        for (int e = 0; e < 64; e++) {
            float2 qv = Qs[e * 64 + x];
            float2 kv = Ks[e * 48 + y];
            re += qv.x * kv.x - qv.y * kv.y;
            im += qv.x * kv.y + qv.y * kv.x;
        }
        // complex tanh: (sinh 2a + i sin 2b)/(cosh 2a + cos 2b)
        float a2 = 2.f * re, b2 = 2.f * im;
        a2 = fminf(fmaxf(a2, -80.f), 80.f);
        float denom = coshf(a2) + cosf(b2);
        G[((size_t)b * 8 + h) * 3072 + i] = make_float2(sinhf(a2) / denom, sinf(b2) / denom);
    }
}

// V[b,h,e,x] = sum_y G[b,h,x,y] * K[b,h,e,y]
__global__ void xqkv_kernel(const float2* __restrict__ G, const float2* __restrict__ XK,
                            float2* __restrict__ V) {
    int b = blockIdx.x, h = blockIdx.y;
    __shared__ float2 Gs[3072];  // [x*48+y]
    __shared__ float2 Ks[3072];  // [e*48+y]
    const float2* gs = G + ((size_t)b * 8 + h) * 3072;
    const float2* ks = XK + ((size_t)b * 8 + h) * 3072;
    for (int i = threadIdx.x; i < 3072; i += 256) { Gs[i] = gs[i]; Ks[i] = ks[i]; }
    __syncthreads();
    for (int i = threadIdx.x; i < 4096; i += 256) {
        int e = i >> 6, x = i & 63;
        float re = 0.f, im = 0.f;
#pragma unroll 8
        for (int y = 0; y < 48; y++) {
            float2 gv = Gs[x * 48 + y];
            float2 kv = Ks[e * 48 + y];
            re += gv.x * kv.x - gv.y * kv.y;
            im += gv.x * kv.y + gv.y * kv.x;
        }
        V[((size_t)b * 8 + h) * 4096 + i] = make_float2(re, im);
    }
}

// ---------------------------------------------------------------------------
// series_decomp: SO = (P[+Q]) - movavg25(P[+Q]); trend optionally stored/added to TS
__global__ void decomp_kernel(const float* __restrict__ P, const float* __restrict__ Q,
                              float* __restrict__ SO, float* __restrict__ TS,
                              int L, int tmode) {
    int b = blockIdx.x, d0 = blockIdx.y * 64;
    __shared__ float s[144 * 64];
    for (int i = threadIdx.x; i < L * 64; i += 256) {
        int l = i >> 6, d = i & 63;
        size_t idx = ((size_t)b * L + l) * 512 + d0 + d;
        float v = P[idx];
        if (Q) v += Q[idx];
        s[i] = v;
    }
    __syncthreads();
    for (int i = threadIdx.x; i < L * 64; i += 256) {
        int l = i >> 6, d = i & 63;
        float sum = 0.f;
#pragma unroll
        for (int j = -12; j <= 12; j++) sum += s[iclamp(l + j, 0, L - 1) * 64 + d];
        float ma = sum * (1.0f / 25.0f);
        size_t idx = ((size_t)b * L + l) * 512 + d0 + d;
        SO[idx] = s[i] - ma;
        if (tmode == 1) TS[idx] = ma;
        else if (tmode == 2) TS[idx] += ma;
    }
}

// ---------------------------------------------------------------------------
// per-row layernorm over d=512 (eps 1e-5), scale/shift. In-place safe.
__global__ __launch_bounds__(256) void ln_rows_kernel(const float* __restrict__ in,
                                                      const float* __restrict__ w,
                                                      const float* __restrict__ bvec,
                                                      float* __restrict__ out) {
    size_t row = blockIdx.x;
    const float* p = in + row * 512;
    int t = threadIdx.x;
    float v0 = p[t], v1 = p[t + 256];
    float s = v0 + v1, s2 = v0 * v0 + v1 * v1;
    for (int o = 32; o > 0; o >>= 1) {
        s += __shfl_xor(s, o, 64);
        s2 += __shfl_xor(s2, o, 64);
    }
    __shared__ float rs[4], rs2[4];
    int wid = t >> 6;
    if ((t & 63) == 0) { rs[wid] = s; rs2[wid] = s2; }
    __syncthreads();
    s = rs[0] + rs[1] + rs[2] + rs[3];
    s2 = rs2[0] + rs2[1] + rs2[2] + rs2[3];
    float mu = s * (1.0f / 512.0f);
    float var = s2 * (1.0f / 512.0f) - mu * mu;
    float r = rsqrtf(var + 1e-5f);
    out[row * 512 + t] = (v0 - mu) * r * w[t] + bvec[t];
    out[row * 512 + t + 256] = (v1 - mu) * r * w[t + 256] + bvec[t + 256];
}

// subtract per-(b,d) mean over time (in-place)
__global__ void timesub_kernel(float* __restrict__ X, int L) {
    int b = blockIdx.x, d0 = blockIdx.y * 64;
    __shared__ float tile[144 * 64];
    __shared__ float mean[64];
    for (int i = threadIdx.x; i < L * 64; i += 256) {
        int l = i >> 6, d = i & 63;
        tile[i] = X[((size_t)b * L + l) * 512 + d0 + d];
    }
    __syncthreads();
    if (threadIdx.x < 64) {
        float sm = 0.f;
        for (int l = 0; l < L; l++) sm += tile[l * 64 + threadIdx.x];
        mean[threadIdx.x] = sm / (float)L;
    }
    __syncthreads();
    for (int i = threadIdx.x; i < L * 64; i += 256) {
        int l = i >> 6, d = i & 63;
        X[((size_t)b * L + l) * 512 + d0 + d] = tile[i] - mean[d];
    }
}

// ---------------------------------------------------------------------------
// final: out[b,lo,c] = TI + circconv3(TS, trend_w) + XL@proj_w.T + proj_b, l = lo+48
__global__ void final_kernel(const float* __restrict__ XL, const float* __restrict__ TS,
                             const float* __restrict__ TI, const float* __restrict__ trend_w,
                             const float* __restrict__ proj_w, const float* __restrict__ proj_b,
                             float* __restrict__ out) {
    int idx = blockIdx.x * 256 + threadIdx.x;
    if (idx >= 128 * 96 * 7) return;
    int c = idx % 7;
    int lo = (idx / 7) % 96;
    int b = idx / (7 * 96);
    int l = lo + 48;
    int lm = l - 1;
    int lp = (l == 143) ? 0 : l + 1;
    const float* ts = TS + (size_t)b * 144 * 512;
    const float* xl = XL + ((size_t)b * 144 + l) * 512;
    const float* tw = trend_w + c * 512 * 3;
    const float* pw = proj_w + c * 512;
    float acc = TI[((size_t)b * 144 + l) * 7 + c] + proj_b[c];
    const float* r0 = ts + (size_t)lm * 512;
    const float* r1 = ts + (size_t)l * 512;
    const float* r2 = ts + (size_t)lp * 512;
    for (int d = 0; d < 512; d++) {
        acc += r0[d] * tw[d * 3 + 0] + r1[d] * tw[d * 3 + 1] + r2[d] * tw[d * 3 + 2];
        acc = fmaf(xl[d], pw[d], acc);
    }
    out[idx] = acc;
}

// ---------------------------------------------------------------------------
static inline int cdiv(int a, int b) { return (a + b - 1) / b; }

extern "C" void kernel_launch(void* const* d_in, const int* in_sizes, int n_in,
                              void* d_out, int out_size, void* d_ws, size_t ws_size,
                              hipStream_t stream) {
    const float* x_enc      = (const float*)d_in[0];
    const float* x_mark_enc = (const float*)d_in[1];
    const float* x_mark_dec = (const float*)d_in[3];
    const float* enc_emb_conv_w = (const float*)d_in[4];
    const float* enc_emb_time_w = (const float*)d_in[5];
    const float* dec_emb_conv_w = (const float*)d_in[6];
    const float* dec_emb_time_w = (const float*)d_in[7];
    const float* enc_qw = (const float*)d_in[8];
    const float* enc_qb = (const float*)d_in[9];
    const float* enc_ow = (const float*)d_in[14];
    const float* enc_ob = (const float*)d_in[15];
    const float* enc_fw = (const float*)d_in[16];
    const float* enc_c1 = (const float*)d_in[17];
    const float* enc_c2 = (const float*)d_in[18];
    const float* enc_norm_w = (const float*)d_in[19];
    const float* enc_norm_b = (const float*)d_in[20];
    const float* ds_qw = (const float*)d_in[21];
    const float* ds_qb = (const float*)d_in[22];
    const float* ds_ow = (const float*)d_in[27];
    const float* ds_ob = (const float*)d_in[28];
    const float* ds_fw = (const float*)d_in[29];
    const float* dc_qw = (const float*)d_in[30];
    const float* dc_qb = (const float*)d_in[31];
    const float* dc_kw = (const float*)d_in[32];
    const float* dc_kb = (const float*)d_in[33];
    const float* dc_ow = (const float*)d_in[36];
    const float* dc_ob = (const float*)d_in[37];
    const float* dc_fw = (const float*)d_in[38];
    const float* dec_c1 = (const float*)d_in[39];
    const float* dec_c2 = (const float*)d_in[40];
    const float* dec_trend_w = (const float*)d_in[41];
    const float* dec_norm_w = (const float*)d_in[42];
    const float* dec_norm_b = (const float*)d_in[43];
    const float* proj_w = (const float*)d_in[44];
    const float* proj_b = (const float*)d_in[45];

    // workspace layout (floats)
    const size_t NT = 9437184;   // 18432*512
    const size_t NE = 6291456;   // 12288*512
    float* ws = (float*)d_ws;
    float* T1   = ws;
    float* T2   = T1 + NT;       // also Q-mode spectrum / V spectrum
    float* XD   = T2 + NT;
    float* TS   = XD + NT;
    float* XE   = TS + NT;
    float* POOL = XE + NE;       // K-modes / WT / FFN hidden chunk (NT floats)
    float* SI   = POOL + NT;
    float* TI   = SI + 129024;
    const size_t need_bytes = (size_t)(NT * 5 + NE + 2 * 129024) * sizeof(float);
    if (ws_size < need_bytes) {
        // not enough scratch: emit zeros (readable failure instead of a fault)
        zero_out_kernel<<<cdiv(out_size, 256), 256, 0, stream>>>((float*)d_out, out_size);
        return;
    }

    auto gemm = [&](const float* A, const float* W, const float* bias, float* Cout,
                    int rows, int N, int K, int lda, int ldw, int gelu, int accum) {
        dim3 g(N / 128, rows / 128);
        gemm_nt<<<g, 256, 0, stream>>>(A, W, bias, Cout, N, K, lda, ldw, gelu, accum);
    };
    // chunked FFN: x[rows,512] -> gelu(x@c1.T) @ c2.T accumulated into T1
    auto ffn = [&](const float* X, const float* c1, const float* c2, int rows) {
        for (int j0 = 0; j0 < 2048; j0 += 512) {
            gemm(X, c1 + (size_t)j0 * 512, nullptr, POOL, rows, 512, 512, 512, 512, 1, 0);
            gemm(POOL, c2 + j0, nullptr, T1, rows, 512, 512, 512, 2048, 0, j0 > 0);
        }
    };

    // ---- preprocess + encoder embed
    preprocess_kernel<<<cdiv(128 * 144 * 7, 256), 256, 0, stream>>>(x_enc, SI, TI);
    embed_kernel<<<cdiv(128 * 96 * 512, 256), 256, 0, stream>>>(
        x_enc, x_mark_enc, enc_emb_conv_w, enc_emb_time_w, XE, 96);

    // ---- encoder layers
    for (int l = 0; l < 2; l++) {
        const float* qw = enc_qw + (size_t)l * 512 * 512;
        const float* qb = enc_qb + (size_t)l * 512;
        const float* ow = enc_ow + (size_t)l * 512 * 512;
        const float* ob = enc_ob + (size_t)l * 512;
        const float* fw = enc_fw + (size_t)l * 8 * 64 * 64 * 48 * 2;
        const float* c1 = enc_c1 + (size_t)l * 2048 * 512;
        const float* c2 = enc_c2 + (size_t)l * 512 * 2048;
        gemm(XE, qw, qb, T1, 12288, 512, 512, 512, 512, 0, 0);
        dft_kernel<<<dim3(128, 8), 256, 0, stream>>>(T1, (float2*)T2, 96, 48);
        wtrans_kernel<<<cdiv(8 * 48 * 4096, 256), 256, 0, stream>>>(fw, (float2*)POOL, 48);
        mix_kernel<<<dim3(8 * 48, 4), 256, 0, stream>>>((float2*)T2, (float2*)POOL,
                                                        (float2*)T1, 48);
        idft_kernel<<<dim3(128, 8), 256, 0, stream>>>((float2*)T1, T2, 96, 48, 1.0f / 96.0f);
        gemm(T2, ow, ob, T1, 12288, 512, 512, 512, 512, 0, 0);
        decomp_kernel<<<dim3(128, 8), 256, 0, stream>>>(XE, T1, XE, nullptr, 96, 0);
        ffn(XE, c1, c2, 12288);
        decomp_kernel<<<dim3(128, 8), 256, 0, stream>>>(XE, T1, XE, nullptr, 96, 0);
    }
    ln_rows_kernel<<<12288, 256, 0, stream>>>(XE, enc_norm_w, enc_norm_b, XE);
    timesub_kernel<<<dim3(128, 8), 256, 0, stream>>>(XE, 96);  // XE = enc_out

    // ---- decoder embed
    embed_kernel<<<cdiv(128 * 144 * 512, 256), 256, 0, stream>>>(
        SI, x_mark_dec, dec_emb_conv_w, dec_emb_time_w, XD, 144);

    // ---- decoder self fourier block
    gemm(XD, ds_qw, ds_qb, T1, 18432, 512, 512, 512, 512, 0, 0);
    dft_kernel<<<dim3(128, 8), 256, 0, stream>>>(T1, (float2*)T2, 144, 64);
    wtrans_kernel<<<cdiv(8 * 64 * 4096, 256), 256, 0, stream>>>(ds_fw, (float2*)POOL, 64);
    mix_kernel<<<dim3(8 * 64, 4), 256, 0, stream>>>((float2*)T2, (float2*)POOL,
                                                    (float2*)T1, 64);
    idft_kernel<<<dim3(128, 8), 256, 0, stream>>>((float2*)T1, T2, 144, 64, 1.0f / 144.0f);
    gemm(T2, ds_ow, ds_ob, T1, 18432, 512, 512, 512, 512, 0, 0);
    decomp_kernel<<<dim3(128, 8), 256, 0, stream>>>(XD, T1, XD, TS, 144, 1);

    // ---- cross attention (K projection first so Q-modes can live in T2)
    gemm(XE, dc_kw, dc_kb, T1, 12288, 512, 512, 512, 512, 0, 0);
    dft_kernel<<<dim3(128, 8), 256, 0, stream>>>(T1, (float2*)POOL, 96, 48);   // K-modes
    gemm(XD, dc_qw, dc_qb, T1, 18432, 512, 512, 512, 512, 0, 0);
    dft_kernel<<<dim3(128, 8), 256, 0, stream>>>(T1, (float2*)T2, 144, 64);    // Q-modes
    xqk_kernel<<<dim3(128, 8), 256, 0, stream>>>((float2*)T2, (float2*)POOL,
                                                 (float2*)T1);                  // G
    xqkv_kernel<<<dim3(128, 8), 256, 0, stream>>>((float2*)T1, (float2*)POOL,
                                                  (float2*)T2);                 // V
    wtrans_kernel<<<cdiv(8 * 64 * 4096, 256), 256, 0, stream>>>(dc_fw, (float2*)POOL, 64);
    mix_kernel<<<dim3(8 * 64, 4), 256, 0, stream>>>((float2*)T2, (float2*)POOL,
                                                    (float2*)T1, 64);
    idft_kernel<<<dim3(128, 8), 256, 0, stream>>>((float2*)T1, T2, 144, 64,
                                                  1.0f / (144.0f * 262144.0f));
    gemm(T2, dc_ow, dc_ob, T1, 18432, 512, 512, 512, 512, 0, 0);
    decomp_kernel<<<dim3(128, 8), 256, 0, stream>>>(XD, T1, XD, TS, 144, 2);

    // ---- decoder FFN
    ffn(XD, dec_c1, dec_c2, 18432);
    decomp_kernel<<<dim3(128, 8), 256, 0, stream>>>(XD, T1, XD, TS, 144, 2);

    // ---- final norm + trend conv + projection
    ln_rows_kernel<<<18432, 256, 0, stream>>>(XD, dec_norm_w, dec_norm_b, XD);
    timesub_kernel<<<dim3(128, 8), 256, 0, stream>>>(XD, 144);
    final_kernel<<<cdiv(128 * 96 * 7, 256), 256, 0, stream>>>(
        XD, TS, TI, dec_trend_w, proj_w, proj_b, (float*)d_out);
}

// Round 3
// 3663.897 us; speedup vs baseline: 1.9199x; 1.9199x over previous
//
#include <hip/hip_runtime.h>
#include <hip/hip_bf16.h>
#include <math.h>

// Model_45904610459674: FEDformer-style forecaster.
// Round 3: bf16 MFMA GEMMs (in-kernel fp32->bf16 conversion, zero extra ws)
//          + twiddle-recurrence DFT/iDFT (kills 2.9e7 LDS bank conflicts).
// B=128, SEQ=96, DEC_LEN=144, D_MODEL=512, H=8, E=64, D_FF=2048, C=7, NF=4
// M_ENC=48, M_DEC=64, M_KV=48, KMA=25.
// fourier_block uses only q; fourier_cross uses only q,k -> dead k/v
// projections skipped. Workspace: 53,735,424 floats = 214.9 MB (known-good).

#define PI_F 3.14159265358979323846f

typedef short bf16x8 __attribute__((ext_vector_type(8)));
typedef float f32x4 __attribute__((ext_vector_type(4)));

static __device__ __forceinline__ int iclamp(int v, int lo, int hi) {
    return v < lo ? lo : (v > hi ? hi : v);
}

// pack two fp32 -> two bf16 (round-half-up on the dropped 16 bits)
static __device__ __forceinline__ unsigned pack2(float x, float y) {
    unsigned xu = __float_as_uint(x) + 0x8000u;
    unsigned yu = __float_as_uint(y) + 0x8000u;
    return (xu >> 16) | (yu & 0xFFFF0000u);
}

__global__ void zero_out_kernel(float* __restrict__ out, int n) {
    int i = blockIdx.x * 256 + threadIdx.x;
    if (i < n) out[i] = 0.f;
}

// ---------------------------------------------------------------------------
// preprocess: series_decomp(x_enc) -> seasonal_init [B,144,7], trend_init [B,144,7]
__global__ void preprocess_kernel(const float* __restrict__ xe,
                                  float* __restrict__ SI, float* __restrict__ TI) {
    int idx = blockIdx.x * 256 + threadIdx.x;
    if (idx >= 128 * 144 * 7) return;
    int c = idx % 7;
    int l = (idx / 7) % 144;
    int b = idx / (7 * 144);
    const float* xb = xe + (size_t)b * 96 * 7;
    if (l < 48) {
        int p = 48 + l;
        float sum = 0.f;
        for (int j = -12; j <= 12; j++) sum += xb[iclamp(p + j, 0, 95) * 7 + c];
        float ma = sum * (1.0f / 25.0f);
        SI[idx] = xb[p * 7 + c] - ma;
        TI[idx] = ma;
    } else {
        SI[idx] = 0.f;
        float m = 0.f;
        for (int l2 = 0; l2 < 96; l2++) m += xb[l2 * 7 + c];
        TI[idx] = m * (1.0f / 96.0f);
    }
}

// ---------------------------------------------------------------------------
// embed: circular conv1d(k=3) over C=7 + mark @ time_w.T  -> [B,L,512]
__global__ void embed_kernel(const float* __restrict__ x, const float* __restrict__ mark,
                             const float* __restrict__ cw, const float* __restrict__ tw,
                             float* __restrict__ out, int L) {
    size_t idx = (size_t)blockIdx.x * 256 + threadIdx.x;
    if (idx >= (size_t)128 * L * 512) return;
    int o = idx & 511;
    int l = (int)((idx >> 9) % L);
    int b = (int)(idx / ((size_t)512 * L));
    int lm = (l == 0) ? L - 1 : l - 1;
    int lp = (l == L - 1) ? 0 : l + 1;
    const float* x0 = x + (size_t)b * L * 7;
    float v = 0.f;
#pragma unroll
    for (int c = 0; c < 7; c++) {
        const float* w = cw + (o * 7 + c) * 3;
        v += x0[lm * 7 + c] * w[0] + x0[l * 7 + c] * w[1] + x0[lp * 7 + c] * w[2];
    }
    const float* mk = mark + ((size_t)b * L + l) * 4;
#pragma unroll
    for (int f = 0; f < 4; f++) v += mk[f] * tw[o * 4 + f];
    out[idx] = v;
}

// ---------------------------------------------------------------------------
// bf16 MFMA GEMM: C[r,n] = [accum? C:0] + sum_k A[r,k]*W[n,k] (+bias) (+GELU).
// fp32 inputs converted to bf16 during LDS staging. 128x128 tile, BK=64,
// 256 threads = 4 waves, each wave 64x64 via 4x4 grid of 16x16x32 MFMA.
// LDS rows padded to 72 bf16 (144B) to break bank-stride conflicts.
// rows%128==0, N%128==0, K%64==0.
__global__ __launch_bounds__(256) void gemm_bf16_nt(
    const float* __restrict__ A, const float* __restrict__ W,
    const float* __restrict__ bias, float* __restrict__ C,
    int N, int K, int lda, int ldw, int gelu, int accum) {
    __shared__ unsigned short As[128 * 72];
    __shared__ unsigned short Ws[128 * 72];
    const int tid = threadIdx.x;
    const int lane = tid & 63, wv = tid >> 6;
    const int wm = (wv & 1) * 64, wn = (wv >> 1) * 64;
    const int q = lane >> 4, ln = lane & 15;
    const size_t bm = (size_t)blockIdx.y * 128;
    const size_t bn = (size_t)blockIdx.x * 128;

    f32x4 acc[4][4];
#pragma unroll
    for (int i = 0; i < 4; i++)
#pragma unroll
        for (int j = 0; j < 4; j++) acc[i][j] = (f32x4){0.f, 0.f, 0.f, 0.f};

    for (int k0 = 0; k0 < K; k0 += 64) {
        // ---- stage A,W tiles (fp32 -> bf16) into LDS
#pragma unroll
        for (int i = 0; i < 8; i++) {
            int flat = i * 1024 + tid * 4;   // element index in 128x64 tile
            int row = flat >> 6, col = flat & 63;
            const float4 av = *(const float4*)(A + (bm + row) * lda + k0 + col);
            *(uint2*)(&As[row * 72 + col]) =
                make_uint2(pack2(av.x, av.y), pack2(av.z, av.w));
            const float4 wvv = *(const float4*)(W + (bn + row) * ldw + k0 + col);
            *(uint2*)(&Ws[row * 72 + col]) =
                make_uint2(pack2(wvv.x, wvv.y), pack2(wvv.z, wvv.w));
        }
        __syncthreads();
        // ---- MFMA over the two K=32 halves
#pragma unroll
        for (int kk = 0; kk < 64; kk += 32) {
            bf16x8 af[4], bfr[4];
            union U8 { bf16x8 v; uint2 u[2]; };
#pragma unroll
            for (int i = 0; i < 4; i++) {
                U8 ua, ub;
                const unsigned short* pa = &As[(wm + i * 16 + ln) * 72 + kk + q * 8];
                ua.u[0] = *(const uint2*)(pa);
                ua.u[1] = *(const uint2*)(pa + 4);
                af[i] = ua.v;
                const unsigned short* pb = &Ws[(wn + i * 16 + ln) * 72 + kk + q * 8];
                ub.u[0] = *(const uint2*)(pb);
                ub.u[1] = *(const uint2*)(pb + 4);
                bfr[i] = ub.v;
            }
#pragma unroll
            for (int i = 0; i < 4; i++)
#pragma unroll
                for (int j = 0; j < 4; j++)
                    acc[i][j] = __builtin_amdgcn_mfma_f32_16x16x32_bf16(
                        af[i], bfr[j], acc[i][j], 0, 0, 0);
        }
        __syncthreads();
    }

    // ---- epilogue: D row = q*4+reg, col = lane&15 (m89-verified C/D layout)
#pragma unroll
    for (int j = 0; j < 4; j++) {
        int col = (int)bn + wn + j * 16 + ln;
        float bv = bias ? bias[col] : 0.f;
#pragma unroll
        for (int i = 0; i < 4; i++) {
            size_t row0 = bm + wm + i * 16 + q * 4;
#pragma unroll
            for (int r = 0; r < 4; r++) {
                float v = acc[i][j][r] + bv;
                if (gelu) v = 0.5f * v * (1.f + erff(v * 0.70710678118654752f));
                float* p = C + (row0 + r) * N + col;
                if (accum) v += *p;
                *p = v;
            }
        }
    }
}

// ---------------------------------------------------------------------------
// DFT: Q [B,L,512] -> X[b,h,e,m] (float2), m < M, X[m]=sum_l q[l] e^{-2pi i m l / L}
// twiddles via complex-rotation recurrence (no LDS table -> no bank conflicts)
__global__ void dft_kernel(const float* __restrict__ Q, float2* __restrict__ X,
                           int L, int M) {
    int b = blockIdx.x, h = blockIdx.y;
    __shared__ float q[144 * 64];
    for (int i = threadIdx.x; i < L * 64; i += 256) {
        int l = i >> 6, e = i & 63;
        q[i] = Q[((size_t)b * L + l) * 512 + h * 64 + e];
    }
    __syncthreads();
    for (int i = threadIdx.x; i < 64 * M; i += 256) {
        int e = i / M, m = i - e * M;
        float ang = -2.f * PI_F * (float)m / (float)L;
        float co, si;
        __sincosf(ang, &si, &co);
        float pr = 1.f, pi = 0.f;
        float re = 0.f, im = 0.f;
        for (int l = 0; l < L; l++) {
            float v = q[l * 64 + e];
            re = fmaf(v, pr, re);
            im = fmaf(v, pi, im);
            float npr = pr * co - pi * si;
            pi = pr * si + pi * co;
            pr = npr;
        }
        X[(((size_t)b * 8 + h) * 64 + e) * M + m] = make_float2(re, im);
    }
}

// ---------------------------------------------------------------------------
// transpose fourier weights [H,E,O,M,(re,im)] -> WT[(h*M+m)*4096 + e*64 + o] float2
__global__ void wtrans_kernel(const float* __restrict__ w, float2* __restrict__ WT, int M) {
    size_t i = (size_t)blockIdx.x * 256 + threadIdx.x;
    if (i >= (size_t)8 * M * 4096) return;
    int hm = (int)(i >> 12);
    int r = (int)(i & 4095);
    int e = r >> 6, o = r & 63;
    int h = hm / M, m = hm - h * M;
    size_t src = ((((size_t)h * 64 + e) * 64 + o) * M + m) * 2;
    WT[i] = make_float2(w[src], w[src + 1]);
}

// mode mix: Y[b,h,o,m] = sum_e X[b,h,e,m] * W[h,e,o,m]   (complex)
__global__ void mix_kernel(const float2* __restrict__ X, const float2* __restrict__ WT,
                           float2* __restrict__ Y, int M) {
    int hm = blockIdx.x;
    int h = hm / M, m = hm - h * M;
    int b0 = blockIdx.y * 32;
    __shared__ float2 Ws[4096];  // [e*64+o]
    __shared__ float2 Xs[2048];  // [bb*64+e]
    const float2* wsrc = WT + (size_t)hm * 4096;
    for (int i = threadIdx.x; i < 4096; i += 256) Ws[i] = wsrc[i];
    for (int i = threadIdx.x; i < 2048; i += 256) {
        int bb = i >> 6, e = i & 63;
        Xs[i] = X[(((size_t)(b0 + bb) * 8 + h) * 64 + e) * M + m];
    }
    __syncthreads();
    for (int i = threadIdx.x; i < 2048; i += 256) {
        int bb = i >> 6, o = i & 63;
        float re = 0.f, im = 0.f;
        const float2* xr = &Xs[bb * 64];
#pragma unroll 8
        for (int e = 0; e < 64; e++) {
            float2 xv = xr[e];
            float2 wv = Ws[e * 64 + o];
            re += xv.x * wv.x - xv.y * wv.y;
            im += xv.x * wv.y + xv.y * wv.x;
        }
        Y[(((size_t)(b0 + bb) * 8 + h) * 64 + o) * M + m] = make_float2(re, im);
    }
}

// ---------------------------------------------------------------------------
// iDFT of M-sparse spectrum (+ torch .view quirk layout):
// out[b*(L*512) + h*64*L + o*L + l] = s*(Re S0 + 2*sum_{m=1}^{M-1} Re(S_m e^{+2pi i m l/L}))
// rotation recurrence per output (no twiddle table)
__global__ void idft_kernel(const float2* __restrict__ Y, float* __restrict__ out,
                            int L, int M, float s) {
    int b = blockIdx.x, h = blockIdx.y;
    __shared__ float2 S[4096];
    const float2* src = Y + (((size_t)b * 8 + h) * 64) * M;
    for (int i = threadIdx.x; i < 64 * M; i += 256) S[i] = src[i];
    __syncthreads();
    for (int i = threadIdx.x; i < 64 * L; i += 256) {
        int o = i / L, l = i - o * L;
        const float2* Sr = &S[o * M];
        float ang = 2.f * PI_F * (float)l / (float)L;
        float co, si;
        __sincosf(ang, &si, &co);
        float pr = co, pi = si;   // e^{i*theta*l*1}
        float sum = 0.f;
        for (int m = 1; m < M; m++) {
            float2 sv = Sr[m];
            sum += sv.x * pr - sv.y * pi;
            float npr = pr * co - pi * si;
            pi = pr * si + pi * co;
            pr = npr;
        }
        float acc = Sr[0].x + 2.f * sum;
        out[(size_t)b * (L * 512) + (size_t)h * 64 * L + i] = acc * s;
    }
}

// ---------------------------------------------------------------------------
// cross-attn: G[b,h,x,y] = ctanh(sum_e Q[b,h,e,x] * K[b,h,e,y]); x<64, y<48
__global__ void xqk_kernel(const float2* __restrict__ XQ, const float2* __restrict__ XK,
                           float2* __restrict__ G) {
    int b = blockIdx.x, h = blockIdx.y;
    __shared__ float2 Qs[4096];  // [e*64+x]
    __shared__ float2 Ks[3072];  // [e*48+y]
    const float2* qs = XQ + ((size_t)b * 8 + h) * 4096;
    const float2* ks = XK + ((size_t)b * 8 + h) * 3072;
    for (int i = threadIdx.x; i < 4096; i += 256) Qs[i] = qs[i];
    for (int i = threadIdx.x; i < 3072; i += 256) Ks[i] = ks[i];
    __syncthreads();
    for (int i = threadIdx.x; i < 64 * 48; i += 256) {
        int x = i / 48, y = i - x * 48;
        float re = 0.f, im = 0.f;
#pragma unroll 8
        for (int e = 0; e < 64; e++) {
            float2 qv = Qs[e * 64 + x];
            float2 kv = Ks[e * 48 + y];
            re += qv.x * kv.x - qv.y * kv.y;
            im += qv.x * kv.y + qv.y * kv.x;
        }
        // complex tanh: (sinh 2a + i sin 2b)/(cosh 2a + cos 2b)
        float a2 = 2.f * re, b2 = 2.f * im;
        a2 = fminf(fmaxf(a2, -80.f), 80.f);
        float denom = coshf(a2) + cosf(b2);
        G[((size_t)b * 8 + h) * 3072 + i] = make_float2(sinhf(a2) / denom, sinf(b2) / denom);
    }
}

// V[b,h,e,x] = sum_y G[b,h,x,y] * K[b,h,e,y]
__global__ void xqkv_kernel(const float2* __restrict__ G, const float2* __restrict__ XK,
                            float2* __restrict__ V) {
    int b = blockIdx.x, h = blockIdx.y;
    __shared__ float2 Gs[3072];  // [x*48+y]
    __shared__ float2 Ks[3072];  // [e*48+y]
    const float2* gs = G + ((size_t)b * 8 + h) * 3072;
    const float2* ks = XK + ((size_t)b * 8 + h) * 3072;
    for (int i = threadIdx.x; i < 3072; i += 256) { Gs[i] = gs[i]; Ks[i] = ks[i]; }
    __syncthreads();
    for (int i = threadIdx.x; i < 4096; i += 256) {
        int e = i >> 6, x = i & 63;
        float re = 0.f, im = 0.f;
#pragma unroll 8
        for (int y = 0; y < 48; y++) {
            float2 gv = Gs[x * 48 + y];
            float2 kv = Ks[e * 48 + y];
            re += gv.x * kv.x - gv.y * kv.y;
            im += gv.x * kv.y + gv.y * kv.x;
        }
        V[((size_t)b * 8 + h) * 4096 + i] = make_float2(re, im);
    }
}

// ---------------------------------------------------------------------------
// series_decomp: SO = (P[+Q]) - movavg25(P[+Q]); trend optionally stored/added to TS
__global__ void decomp_kernel(const float* __restrict__ P, const float* __restrict__ Q,
                              float* __restrict__ SO, float* __restrict__ TS,
                              int L, int tmode) {
    int b = blockIdx.x, d0 = blockIdx.y * 64;
    __shared__ float s[144 * 64];
    for (int i = threadIdx.x; i < L * 64; i += 256) {
        int l = i >> 6, d = i & 63;
        size_t idx = ((size_t)b * L + l) * 512 + d0 + d;
        float v = P[idx];
        if (Q) v += Q[idx];
        s[i] = v;
    }
    __syncthreads();
    for (int i = threadIdx.x; i < L * 64; i += 256) {
        int l = i >> 6, d = i & 63;
        float sum = 0.f;
#pragma unroll
        for (int j = -12; j <= 12; j++) sum += s[iclamp(l + j, 0, L - 1) * 64 + d];
        float ma = sum * (1.0f / 25.0f);
        size_t idx = ((size_t)b * L + l) * 512 + d0 + d;
        SO[idx] = s[i] - ma;
        if (tmode == 1) TS[idx] = ma;
        else if (tmode == 2) TS[idx] += ma;
    }
}

// ---------------------------------------------------------------------------
// per-row layernorm over d=512 (eps 1e-5), scale/shift. In-place safe.
__global__ __launch_bounds__(256) void ln_rows_kernel(const float* __restrict__ in,
                                                      const float* __restrict__ w,
                                                      const float* __restrict__ bvec,
                                                      float* __restrict__ out) {
    size_t row = blockIdx.x;
    const float* p = in + row * 512;
    int t = threadIdx.x;
    float v0 = p[t], v1 = p[t + 256];
    float s = v0 + v1, s2 = v0 * v0 + v1 * v1;
    for (int o = 32; o > 0; o >>= 1) {
        s += __shfl_xor(s, o, 64);
        s2 += __shfl_xor(s2, o, 64);
    }
    __shared__ float rs[4], rs2[4];
    int wid = t >> 6;
    if ((t & 63) == 0) { rs[wid] = s; rs2[wid] = s2; }
    __syncthreads();
    s = rs[0] + rs[1] + rs[2] + rs[3];
    s2 = rs2[0] + rs2[1] + rs2[2] + rs2[3];
    float mu = s * (1.0f / 512.0f);
    float var = s2 * (1.0f / 512.0f) - mu * mu;
    float r = rsqrtf(var + 1e-5f);
    out[row * 512 + t] = (v0 - mu) * r * w[t] + bvec[t];
    out[row * 512 + t + 256] = (v1 - mu) * r * w[t + 256] + bvec[t + 256];
}

// subtract per-(b,d) mean over time (in-place)
__global__ void timesub_kernel(float* __restrict__ X, int L) {
    int b = blockIdx.x, d0 = blockIdx.y * 64;
    __shared__ float tile[144 * 64];
    __shared__ float mean[64];
    for (int i = threadIdx.x; i < L * 64; i += 256) {
        int l = i >> 6, d = i & 63;
        tile[i] = X[((size_t)b * L + l) * 512 + d0 + d];
    }
    __syncthreads();
    if (threadIdx.x < 64) {
        float sm = 0.f;
        for (int l = 0; l < L; l++) sm += tile[l * 64 + threadIdx.x];
        mean[threadIdx.x] = sm / (float)L;
    }
    __syncthreads();
    for (int i = threadIdx.x; i < L * 64; i += 256) {
        int l = i >> 6, d = i & 63;
        X[((size_t)b * L + l) * 512 + d0 + d] = tile[i] - mean[d];
    }
}

// ---------------------------------------------------------------------------
// final: out[b,lo,c] = TI + circconv3(TS, trend_w) + XL@proj_w.T + proj_b, l = lo+48
__global__ void final_kernel(const float* __restrict__ XL, const float* __restrict__ TS,
                             const float* __restrict__ TI, const float* __restrict__ trend_w,
                             const float* __restrict__ proj_w, const float* __restrict__ proj_b,
                             float* __restrict__ out) {
    int idx = blockIdx.x * 256 + threadIdx.x;
    if (idx >= 128 * 96 * 7) return;
    int c = idx % 7;
    int lo = (idx / 7) % 96;
    int b = idx / (7 * 96);
    int l = lo + 48;
    int lm = l - 1;
    int lp = (l == 143) ? 0 : l + 1;
    const float* ts = TS + (size_t)b * 144 * 512;
    const float* xl = XL + ((size_t)b * 144 + l) * 512;
    const float* tw = trend_w + c * 512 * 3;
    const float* pw = proj_w + c * 512;
    float acc = TI[((size_t)b * 144 + l) * 7 + c] + proj_b[c];
    const float* r0 = ts + (size_t)lm * 512;
    const float* r1 = ts + (size_t)l * 512;
    const float* r2 = ts + (size_t)lp * 512;
    for (int d = 0; d < 512; d++) {
        acc += r0[d] * tw[d * 3 + 0] + r1[d] * tw[d * 3 + 1] + r2[d] * tw[d * 3 + 2];
        acc = fmaf(xl[d], pw[d], acc);
    }
    out[idx] = acc;
}

// ---------------------------------------------------------------------------
static inline int cdiv(int a, int b) { return (a + b - 1) / b; }

extern "C" void kernel_launch(void* const* d_in, const int* in_sizes, int n_in,
                              void* d_out, int out_size, void* d_ws, size_t ws_size,
                              hipStream_t stream) {
    const float* x_enc      = (const float*)d_in[0];
    const float* x_mark_enc = (const float*)d_in[1];
    const float* x_mark_dec = (const float*)d_in[3];
    const float* enc_emb_conv_w = (const float*)d_in[4];
    const float* enc_emb_time_w = (const float*)d_in[5];
    const float* dec_emb_conv_w = (const float*)d_in[6];
    const float* dec_emb_time_w = (const float*)d_in[7];
    const float* enc_qw = (const float*)d_in[8];
    const float* enc_qb = (const float*)d_in[9];
    const float* enc_ow = (const float*)d_in[14];
    const float* enc_ob = (const float*)d_in[15];
    const float* enc_fw = (const float*)d_in[16];
    const float* enc_c1 = (const float*)d_in[17];
    const float* enc_c2 = (const float*)d_in[18];
    const float* enc_norm_w = (const float*)d_in[19];
    const float* enc_norm_b = (const float*)d_in[20];
    const float* ds_qw = (const float*)d_in[21];
    const float* ds_qb = (const float*)d_in[22];
    const float* ds_ow = (const float*)d_in[27];
    const float* ds_ob = (const float*)d_in[28];
    const float* ds_fw = (const float*)d_in[29];
    const float* dc_qw = (const float*)d_in[30];
    const float* dc_qb = (const float*)d_in[31];
    const float* dc_kw = (const float*)d_in[32];
    const float* dc_kb = (const float*)d_in[33];
    const float* dc_ow = (const float*)d_in[36];
    const float* dc_ob = (const float*)d_in[37];
    const float* dc_fw = (const float*)d_in[38];
    const float* dec_c1 = (const float*)d_in[39];
    const float* dec_c2 = (const float*)d_in[40];
    const float* dec_trend_w = (const float*)d_in[41];
    const float* dec_norm_w = (const float*)d_in[42];
    const float* dec_norm_b = (const float*)d_in[43];
    const float* proj_w = (const float*)d_in[44];
    const float* proj_b = (const float*)d_in[45];

    // workspace layout (floats)
    const size_t NT = 9437184;   // 18432*512
    const size_t NE = 6291456;   // 12288*512
    float* ws = (float*)d_ws;
    float* T1   = ws;
    float* T2   = T1 + NT;       // also Q-mode spectrum / V spectrum
    float* XD   = T2 + NT;
    float* TS   = XD + NT;
    float* XE   = TS + NT;
    float* POOL = XE + NE;       // K-modes / WT / FFN hidden chunk (NT floats)
    float* SI   = POOL + NT;
    float* TI   = SI + 129024;
    const size_t need_bytes = (size_t)(NT * 5 + NE + 2 * 129024) * sizeof(float);
    if (ws_size < need_bytes) {
        zero_out_kernel<<<cdiv(out_size, 256), 256, 0, stream>>>((float*)d_out, out_size);
        return;
    }

    auto gemm = [&](const float* A, const float* W, const float* bias, float* Cout,
                    int rows, int N, int K, int lda, int ldw, int gelu, int accum) {
        dim3 g(N / 128, rows / 128);
        gemm_bf16_nt<<<g, 256, 0, stream>>>(A, W, bias, Cout, N, K, lda, ldw, gelu, accum);
    };
    // chunked FFN: x[rows,512] -> gelu(x@c1.T) @ c2.T accumulated into T1
    auto ffn = [&](const float* X, const float* c1, const float* c2, int rows) {
        for (int j0 = 0; j0 < 2048; j0 += 512) {
            gemm(X, c1 + (size_t)j0 * 512, nullptr, POOL, rows, 512, 512, 512, 512, 1, 0);
            gemm(POOL, c2 + j0, nullptr, T1, rows, 512, 512, 512, 2048, 0, j0 > 0);
        }
    };

    // ---- preprocess + encoder embed
    preprocess_kernel<<<cdiv(128 * 144 * 7, 256), 256, 0, stream>>>(x_enc, SI, TI);
    embed_kernel<<<cdiv(128 * 96 * 512, 256), 256, 0, stream>>>(
        x_enc, x_mark_enc, enc_emb_conv_w, enc_emb_time_w, XE, 96);

    // ---- encoder layers
    for (int l = 0; l < 2; l++) {
        const float* qw = enc_qw + (size_t)l * 512 * 512;
        const float* qb = enc_qb + (size_t)l * 512;
        const float* ow = enc_ow + (size_t)l * 512 * 512;
        const float* ob = enc_ob + (size_t)l * 512;
        const float* fw = enc_fw + (size_t)l * 8 * 64 * 64 * 48 * 2;
        const float* c1 = enc_c1 + (size_t)l * 2048 * 512;
        const float* c2 = enc_c2 + (size_t)l * 512 * 2048;
        gemm(XE, qw, qb, T1, 12288, 512, 512, 512, 512, 0, 0);
        dft_kernel<<<dim3(128, 8), 256, 0, stream>>>(T1, (float2*)T2, 96, 48);
        wtrans_kernel<<<cdiv(8 * 48 * 4096, 256), 256, 0, stream>>>(fw, (float2*)POOL, 48);
        mix_kernel<<<dim3(8 * 48, 4), 256, 0, stream>>>((float2*)T2, (float2*)POOL,
                                                        (float2*)T1, 48);
        idft_kernel<<<dim3(128, 8), 256, 0, stream>>>((float2*)T1, T2, 96, 48, 1.0f / 96.0f);
        gemm(T2, ow, ob, T1, 12288, 512, 512, 512, 512, 0, 0);
        decomp_kernel<<<dim3(128, 8), 256, 0, stream>>>(XE, T1, XE, nullptr, 96, 0);
        ffn(XE, c1, c2, 12288);
        decomp_kernel<<<dim3(128, 8), 256, 0, stream>>>(XE, T1, XE, nullptr, 96, 0);
    }
    ln_rows_kernel<<<12288, 256, 0, stream>>>(XE, enc_norm_w, enc_norm_b, XE);
    timesub_kernel<<<dim3(128, 8), 256, 0, stream>>>(XE, 96);  // XE = enc_out

    // ---- decoder embed
    embed_kernel<<<cdiv(128 * 144 * 512, 256), 256, 0, stream>>>(
        SI, x_mark_dec, dec_emb_conv_w, dec_emb_time_w, XD, 144);

    // ---- decoder self fourier block
    gemm(XD, ds_qw, ds_qb, T1, 18432, 512, 512, 512, 512, 0, 0);
    dft_kernel<<<dim3(128, 8), 256, 0, stream>>>(T1, (float2*)T2, 144, 64);
    wtrans_kernel<<<cdiv(8 * 64 * 4096, 256), 256, 0, stream>>>(ds_fw, (float2*)POOL, 64);
    mix_kernel<<<dim3(8 * 64, 4), 256, 0, stream>>>((float2*)T2, (float2*)POOL,
                                                    (float2*)T1, 64);
    idft_kernel<<<dim3(128, 8), 256, 0, stream>>>((float2*)T1, T2, 144, 64, 1.0f / 144.0f);
    gemm(T2, ds_ow, ds_ob, T1, 18432, 512, 512, 512, 512, 0, 0);
    decomp_kernel<<<dim3(128, 8), 256, 0, stream>>>(XD, T1, XD, TS, 144, 1);

    // ---- cross attention (K projection first so Q-modes can live in T2)
    gemm(XE, dc_kw, dc_kb, T1, 12288, 512, 512, 512, 512, 0, 0);
    dft_kernel<<<dim3(128, 8), 256, 0, stream>>>(T1, (float2*)POOL, 96, 48);   // K-modes
    gemm(XD, dc_qw, dc_qb, T1, 18432, 512, 512, 512, 512, 0, 0);
    dft_kernel<<<dim3(128, 8), 256, 0, stream>>>(T1, (float2*)T2, 144, 64);    // Q-modes
    xqk_kernel<<<dim3(128, 8), 256, 0, stream>>>((float2*)T2, (float2*)POOL,
                                                 (float2*)T1);                  // G
    xqkv_kernel<<<dim3(128, 8), 256, 0, stream>>>((float2*)T1, (float2*)POOL,
                                                  (float2*)T2);                 // V
    wtrans_kernel<<<cdiv(8 * 64 * 4096, 256), 256, 0, stream>>>(dc_fw, (float2*)POOL, 64);
    mix_kernel<<<dim3(8 * 64, 4), 256, 0, stream>>>((float2*)T2, (float2*)POOL,
                                                    (float2*)T1, 64);
    idft_kernel<<<dim3(128, 8), 256, 0, stream>>>((float2*)T1, T2, 144, 64,
                                                  1.0f / (144.0f * 262144.0f));
    gemm(T2, dc_ow, dc_ob, T1, 18432, 512, 512, 512, 512, 0, 0);
    decomp_kernel<<<dim3(128, 8), 256, 0, stream>>>(XD, T1, XD, TS, 144, 2);

    // ---- decoder FFN
    ffn(XD, dec_c1, dec_c2, 18432);
    decomp_kernel<<<dim3(128, 8), 256, 0, stream>>>(XD, T1, XD, TS, 144, 2);

    // ---- final norm + trend conv + projection
    ln_rows_kernel<<<18432, 256, 0, stream>>>(XD, dec_norm_w, dec_norm_b, XD);
    timesub_kernel<<<dim3(128, 8), 256, 0, stream>>>(XD, 144);
    final_kernel<<<cdiv(128 * 96 * 7, 256), 256, 0, stream>>>(
        XD, TS, TI, dec_trend_w, proj_w, proj_b, (float*)d_out);
}

// Round 4
// 2988.246 us; speedup vs baseline: 2.3540x; 1.2261x over previous
//
#include <hip/hip_runtime.h>
#include <hip/hip_bf16.h>
#include <math.h>

// Model_45904610459674: FEDformer-style forecaster.
// Round 4: Fourier path (dft / mode-mix / idft) as bf16 MFMA GEMMs.
//   dft:  X[(b,h,e),2m+p] = sum_l P[(b,l),(h,e)] * Td[n,l]   (transpose fused)
//   mix:  per (h,m) complex matmul via interleaved-real embedding, MFMA
//   idft: out[(b,h,o),l] = Y @ Ti  (writes the torch .view quirk layout directly)
// B=128, SEQ=96, DEC_LEN=144, D_MODEL=512, H=8, E=64, D_FF=2048, C=7
// M_ENC=48, M_DEC=64, M_KV=48, KMA=25. Dead k/v projections skipped.
// Workspace: 53,735,424 floats = 214.9 MB (known-good), liveness-aliased per phase.

#define PI_F 3.14159265358979323846f

typedef short bf16x8 __attribute__((ext_vector_type(8)));
typedef float f32x4 __attribute__((ext_vector_type(4)));

static __device__ __forceinline__ int iclamp(int v, int lo, int hi) {
    return v < lo ? lo : (v > hi ? hi : v);
}

static __device__ __forceinline__ unsigned pack2(float x, float y) {
    unsigned xu = __float_as_uint(x) + 0x8000u;
    unsigned yu = __float_as_uint(y) + 0x8000u;
    return (xu >> 16) | (yu & 0xFFFF0000u);
}
static __device__ __forceinline__ unsigned short bfr(float x) {
    return (unsigned short)((__float_as_uint(x) + 0x8000u) >> 16);
}

__global__ void zero_out_kernel(float* __restrict__ out, int n) {
    int i = blockIdx.x * 256 + threadIdx.x;
    if (i < n) out[i] = 0.f;
}

// ---------------------------------------------------------------------------
// preprocess: series_decomp(x_enc) -> seasonal_init [B,144,7], trend_init
__global__ void preprocess_kernel(const float* __restrict__ xe,
                                  float* __restrict__ SI, float* __restrict__ TI) {
    int idx = blockIdx.x * 256 + threadIdx.x;
    if (idx >= 128 * 144 * 7) return;
    int c = idx % 7;
    int l = (idx / 7) % 144;
    int b = idx / (7 * 144);
    const float* xb = xe + (size_t)b * 96 * 7;
    if (l < 48) {
        int p = 48 + l;
        float sum = 0.f;
        for (int j = -12; j <= 12; j++) sum += xb[iclamp(p + j, 0, 95) * 7 + c];
        float ma = sum * (1.0f / 25.0f);
        SI[idx] = xb[p * 7 + c] - ma;
        TI[idx] = ma;
    } else {
        SI[idx] = 0.f;
        float m = 0.f;
        for (int l2 = 0; l2 < 96; l2++) m += xb[l2 * 7 + c];
        TI[idx] = m * (1.0f / 96.0f);
    }
}

// ---------------------------------------------------------------------------
// embed: circular conv1d(k=3) over C=7 + mark @ time_w.T  -> [B,L,512]
__global__ void embed_kernel(const float* __restrict__ x, const float* __restrict__ mark,
                             const float* __restrict__ cw, const float* __restrict__ tw,
                             float* __restrict__ out, int L) {
    size_t idx = (size_t)blockIdx.x * 256 + threadIdx.x;
    if (idx >= (size_t)128 * L * 512) return;
    int o = idx & 511;
    int l = (int)((idx >> 9) % L);
    int b = (int)(idx / ((size_t)512 * L));
    int lm = (l == 0) ? L - 1 : l - 1;
    int lp = (l == L - 1) ? 0 : l + 1;
    const float* x0 = x + (size_t)b * L * 7;
    float v = 0.f;
#pragma unroll
    for (int c = 0; c < 7; c++) {
        const float* w = cw + (o * 7 + c) * 3;
        v += x0[lm * 7 + c] * w[0] + x0[l * 7 + c] * w[1] + x0[lp * 7 + c] * w[2];
    }
    const float* mk = mark + ((size_t)b * L + l) * 4;
#pragma unroll
    for (int f = 0; f < 4; f++) v += mk[f] * tw[o * 4 + f];
    out[idx] = v;
}

// ---------------------------------------------------------------------------
// bf16 MFMA GEMM (projections/FFN): C = [accum?C:0] + A@W.T (+bias)(+GELU)
__global__ __launch_bounds__(256) void gemm_bf16_nt(
    const float* __restrict__ A, const float* __restrict__ W,
    const float* __restrict__ bias, float* __restrict__ C,
    int N, int K, int lda, int ldw, int gelu, int accum) {
    __shared__ unsigned short As[128 * 72];
    __shared__ unsigned short Ws[128 * 72];
    const int tid = threadIdx.x;
    const int lane = tid & 63, wv = tid >> 6;
    const int wm = (wv & 1) * 64, wn = (wv >> 1) * 64;
    const int q = lane >> 4, ln = lane & 15;
    const size_t bm = (size_t)blockIdx.y * 128;
    const size_t bn = (size_t)blockIdx.x * 128;

    f32x4 acc[4][4];
#pragma unroll
    for (int i = 0; i < 4; i++)
#pragma unroll
        for (int j = 0; j < 4; j++) acc[i][j] = (f32x4){0.f, 0.f, 0.f, 0.f};

    for (int k0 = 0; k0 < K; k0 += 64) {
#pragma unroll
        for (int i = 0; i < 8; i++) {
            int flat = i * 1024 + tid * 4;
            int row = flat >> 6, col = flat & 63;
            const float4 a = *(const float4*)(A + (bm + row) * lda + k0 + col);
            *(uint2*)(&As[row * 72 + col]) =
                make_uint2(pack2(a.x, a.y), pack2(a.z, a.w));
            const float4 b = *(const float4*)(W + (bn + row) * ldw + k0 + col);
            *(uint2*)(&Ws[row * 72 + col]) =
                make_uint2(pack2(b.x, b.y), pack2(b.z, b.w));
        }
        __syncthreads();
#pragma unroll
        for (int kk = 0; kk < 64; kk += 32) {
            bf16x8 af[4], bfr4[4];
            union U8 { bf16x8 v; uint2 u[2]; };
#pragma unroll
            for (int i = 0; i < 4; i++) {
                U8 ua, ub;
                const unsigned short* pa = &As[(wm + i * 16 + ln) * 72 + kk + q * 8];
                ua.u[0] = *(const uint2*)(pa);
                ua.u[1] = *(const uint2*)(pa + 4);
                af[i] = ua.v;
                const unsigned short* pb = &Ws[(wn + i * 16 + ln) * 72 + kk + q * 8];
                ub.u[0] = *(const uint2*)(pb);
                ub.u[1] = *(const uint2*)(pb + 4);
                bfr4[i] = ub.v;
            }
#pragma unroll
            for (int i = 0; i < 4; i++)
#pragma unroll
                for (int j = 0; j < 4; j++)
                    acc[i][j] = __builtin_amdgcn_mfma_f32_16x16x32_bf16(
                        af[i], bfr4[j], acc[i][j], 0, 0, 0);
        }
        __syncthreads();
    }
#pragma unroll
    for (int j = 0; j < 4; j++) {
        int col = (int)bn + wn + j * 16 + ln;
        float bv = bias ? bias[col] : 0.f;
#pragma unroll
        for (int i = 0; i < 4; i++) {
            size_t row0 = bm + wm + i * 16 + q * 4;
#pragma unroll
            for (int r = 0; r < 4; r++) {
                float v = acc[i][j][r] + bv;
                if (gelu) v = 0.5f * v * (1.f + erff(v * 0.70710678118654752f));
                float* p = C + (row0 + r) * N + col;
                if (accum) v += *p;
                *p = v;
            }
        }
    }
}

// ---------------------------------------------------------------------------
// twiddle tables (bf16). dtab: Td[n=2m+p][k=l], ld=ldk, 128 rows, zero pad.
__global__ void dtab_kernel(unsigned short* __restrict__ T, int M, int L, int ldk) {
    int i = blockIdx.x * 256 + threadIdx.x;
    if (i >= 128 * ldk) return;
    int n = i / ldk, k = i - n * ldk;
    float val = 0.f;
    if (n < 2 * M && k < L) {
        int m = n >> 1;
        int r = (m * k) % L;
        float ang = -2.f * PI_F * (float)r / (float)L;
        val = (n & 1) ? sinf(ang) : cosf(ang);
    }
    T[i] = bfr(val);
}
// itab: Ti[n=l][k=2m+p], ld=K. Ti[l,2m]=cm*cos, Ti[l,2m+1]=-cm*sin, cm=(m?2:1)
__global__ void itab_kernel(unsigned short* __restrict__ T, int M, int L, int K) {
    int i = blockIdx.x * 256 + threadIdx.x;
    if (i >= L * K) return;
    int n = i / K, k = i - n * K;
    int m = k >> 1;
    float c = (m == 0) ? 1.f : 2.f;
    int r = (m * n) % L;
    float ang = 2.f * PI_F * (float)r / (float)L;
    float val = (k & 1) ? -c * sinf(ang) : c * cosf(ang);
    T[i] = bfr(val);
}

// WB[(h*M+m)][n=2o+q][k=2e+p] bf16, interleaved-real complex embedding:
// q0p0=re, q0p1=-im, q1p0=im, q1p1=re   (from w[h][e][o][m][2])
__global__ void wtrans2_kernel(const float* __restrict__ w,
                               unsigned short* __restrict__ WB, int M) {
    int i = blockIdx.x * 256 + threadIdx.x;
    if (i >= 8 * M * 16384) return;
    int hm = i >> 14;
    int rr = i & 16383;
    int n = rr >> 7, k = rr & 127;
    int h = hm / M, m = hm - h * M;
    int o = n >> 1, qn = n & 1, e = k >> 1, p = k & 1;
    size_t src = ((((size_t)h * 64 + e) * 64 + o) * M + m) * 2;
    float re = w[src], im = w[src + 1];
    float val = qn ? (p ? re : im) : (p ? -im : re);
    WB[i] = bfr(val);
}

// ---------------------------------------------------------------------------
// dft MFMA: X[(b*512+c)*128 + n] = sum_l P[(b*L+l)*512 + c] * Td[n][l]
// grid (1, 512); LDS-free: A gathered per-lane (guarded), B direct b128 loads.
__global__ __launch_bounds__(256) void dft_mfma(
    const float* __restrict__ P, const unsigned short* __restrict__ Tdb,
    float* __restrict__ X, int L, int ldk) {
    const int tid = threadIdx.x;
    const int lane = tid & 63, wv = tid >> 6;
    const int wm = (wv & 1) * 64, wn = (wv >> 1) * 64;
    const int q = lane >> 4, ln = lane & 15;
    const int bm = blockIdx.y * 128;
    const int b = bm >> 9, c0 = bm & 511;
    const float* Pb = P + (size_t)b * L * 512;

    f32x4 acc[4][4];
#pragma unroll
    for (int i = 0; i < 4; i++)
#pragma unroll
        for (int j = 0; j < 4; j++) acc[i][j] = (f32x4){0.f, 0.f, 0.f, 0.f};

    for (int k0 = 0; k0 < L; k0 += 32) {
        bf16x8 af[4], bf[4];
        union FR { bf16x8 v; unsigned short s[8]; };
#pragma unroll
        for (int i = 0; i < 4; i++) {
            int c = c0 + wm + i * 16 + ln;
            FR fr;
#pragma unroll
            for (int t = 0; t < 8; t++) {
                int l = k0 + q * 8 + t;
                fr.s[t] = bfr(l < L ? Pb[(size_t)l * 512 + c] : 0.f);
            }
            af[i] = fr.v;
        }
#pragma unroll
        for (int j = 0; j < 4; j++) {
            int n = wn + j * 16 + ln;
            bf[j] = *(const bf16x8*)(Tdb + (size_t)n * ldk + k0 + q * 8);
        }
#pragma unroll
        for (int i = 0; i < 4; i++)
#pragma unroll
            for (int j = 0; j < 4; j++)
                acc[i][j] = __builtin_amdgcn_mfma_f32_16x16x32_bf16(
                    af[i], bf[j], acc[i][j], 0, 0, 0);
    }
#pragma unroll
    for (int j = 0; j < 4; j++) {
        int col = wn + j * 16 + ln;
#pragma unroll
        for (int i = 0; i < 4; i++) {
            int row0 = bm + wm + i * 16 + q * 4;
#pragma unroll
            for (int r = 0; r < 4; r++)
                X[(size_t)(row0 + r) * 128 + col] = acc[i][j][r];
        }
    }
}

// ---------------------------------------------------------------------------
// mix MFMA: per (h,m): C[b][n] = sum_k A[b][k]*WB[hm][n][k], K=128
// A[b][2e+p] = X[((b*8+h)*64+e)*128 + 2m+p]; writes Y[((b*8+h)*64+o)*128+2m+q]
__global__ __launch_bounds__(256) void mix_mfma(
    const float* __restrict__ X, const unsigned short* __restrict__ WB,
    float* __restrict__ Y, int M) {
    const int m = blockIdx.x, h = blockIdx.y;
    const int tid = threadIdx.x;
    const int lane = tid & 63, wv = tid >> 6;
    const int wm = (wv & 1) * 64, wn = (wv >> 1) * 64;
    const int q = lane >> 4, ln = lane & 15;
    const float2* X2 = (const float2*)X;
    const unsigned short* WBh = WB + ((size_t)(h * M + m)) * 16384;

    f32x4 acc[4][4];
#pragma unroll
    for (int i = 0; i < 4; i++)
#pragma unroll
        for (int j = 0; j < 4; j++) acc[i][j] = (f32x4){0.f, 0.f, 0.f, 0.f};

#pragma unroll
    for (int k0 = 0; k0 < 128; k0 += 32) {
        bf16x8 af[4], bf[4];
        union FR { bf16x8 v; unsigned short s[8]; };
#pragma unroll
        for (int i = 0; i < 4; i++) {
            int b = wm + i * 16 + ln;
            FR fr;
            int e0 = (k0 >> 1) + q * 4;
#pragma unroll
            for (int u = 0; u < 4; u++) {
                float2 xv = X2[((size_t)(b * 8 + h) * 64 + e0 + u) * 64 + m];
                fr.s[2 * u] = bfr(xv.x);
                fr.s[2 * u + 1] = bfr(xv.y);
            }
            af[i] = fr.v;
        }
#pragma unroll
        for (int j = 0; j < 4; j++) {
            int n = wn + j * 16 + ln;
            bf[j] = *(const bf16x8*)(WBh + (size_t)n * 128 + k0 + q * 8);
        }
#pragma unroll
        for (int i = 0; i < 4; i++)
#pragma unroll
            for (int j = 0; j < 4; j++)
                acc[i][j] = __builtin_amdgcn_mfma_f32_16x16x32_bf16(
                    af[i], bf[j], acc[i][j], 0, 0, 0);
    }
#pragma unroll
    for (int j = 0; j < 4; j++) {
        int n = wn + j * 16 + ln;
        int o = n >> 1, qq = n & 1;
#pragma unroll
        for (int i = 0; i < 4; i++) {
            int b0 = wm + i * 16 + q * 4;
#pragma unroll
            for (int r = 0; r < 4; r++)
                Y[((size_t)((b0 + r) * 8 + h) * 64 + o) * 128 + 2 * m + qq] =
                    acc[i][j][r];
        }
    }
}

// ---------------------------------------------------------------------------
// idft MFMA: Out[(b,h,o)*L + l] = s * sum_k Y[row*128+k]*Ti[l][k], K=2M
// grid (cdiv(L,128), 512)
__global__ __launch_bounds__(256) void idft_mfma(
    const float* __restrict__ Y, const unsigned short* __restrict__ Tib,
    float* __restrict__ Out, int L, int K, float s) {
    const int tid = threadIdx.x;
    const int lane = tid & 63, wv = tid >> 6;
    const int wm = (wv & 1) * 64, wn = (wv >> 1) * 64;
    const int q = lane >> 4, ln = lane & 15;
    const int bm = blockIdx.y * 128;
    const int bn = blockIdx.x * 128;

    f32x4 acc[4][4];
#pragma unroll
    for (int i = 0; i < 4; i++)
#pragma unroll
        for (int j = 0; j < 4; j++) acc[i][j] = (f32x4){0.f, 0.f, 0.f, 0.f};

    for (int k0 = 0; k0 < K; k0 += 32) {
        bf16x8 af[4], bf[4];
        union FR { bf16x8 v; unsigned short s[8]; };
#pragma unroll
        for (int i = 0; i < 4; i++) {
            const float* ar = Y + (size_t)(bm + wm + i * 16 + ln) * 128 + k0 + q * 8;
            FR fr;
#pragma unroll
            for (int t = 0; t < 8; t++) fr.s[t] = bfr(ar[t]);
            af[i] = fr.v;
        }
#pragma unroll
        for (int j = 0; j < 4; j++) {
            int n = bn + wn + j * 16 + ln;
            if (n < L) bf[j] = *(const bf16x8*)(Tib + (size_t)n * K + k0 + q * 8);
            else bf[j] = (bf16x8){0, 0, 0, 0, 0, 0, 0, 0};
        }
#pragma unroll
        for (int i = 0; i < 4; i++)
#pragma unroll
            for (int j = 0; j < 4; j++)
                acc[i][j] = __builtin_amdgcn_mfma_f32_16x16x32_bf16(
                    af[i], bf[j], acc[i][j], 0, 0, 0);
    }
#pragma unroll
    for (int j = 0; j < 4; j++) {
        int col = bn + wn + j * 16 + ln;
        if (col >= L) continue;
#pragma unroll
        for (int i = 0; i < 4; i++) {
            int row0 = bm + wm + i * 16 + q * 4;
#pragma unroll
            for (int r = 0; r < 4; r++)
                Out[(size_t)(row0 + r) * L + col] = acc[i][j][r] * s;
        }
    }
}

// ---------------------------------------------------------------------------
// cross-attn: G[b,h,x,y] = ctanh(sum_e Q[..e,x]*K[..e,y]); XQ/XK ld = 64 f2
__global__ void xqk_kernel(const float2* __restrict__ XQ, const float2* __restrict__ XK,
                           float2* __restrict__ G) {
    int b = blockIdx.x, h = blockIdx.y;
    __shared__ float2 Qs[4096];  // [e*64+x]
    __shared__ float2 Ks[3072];  // [e*48+y]
    const float2* qs = XQ + ((size_t)b * 8 + h) * 4096;
    const float2* ks = XK + ((size_t)b * 8 + h) * 4096;
    for (int i = threadIdx.x; i < 4096; i += 256) Qs[i] = qs[i];
    for (int i = threadIdx.x; i < 3072; i += 256) {
        int e = i / 48, y = i - e * 48;
        Ks[i] = ks[e * 64 + y];
    }
    __syncthreads();
    for (int i = threadIdx.x; i < 64 * 48; i += 256) {
        int x = i / 48, y = i - x * 48;
        float re = 0.f, im = 0.f;
#pragma unroll 8
        for (int e = 0; e < 64; e++) {
            float2 qv = Qs[e * 64 + x];
            float2 kv = Ks[e * 48 + y];
            re += qv.x * kv.x - qv.y * kv.y;
            im += qv.x * kv.y + qv.y * kv.x;
        }
        float a2 = 2.f * re, b2 = 2.f * im;
        a2 = fminf(fmaxf(a2, -80.f), 80.f);
        float denom = coshf(a2) + cosf(b2);
        G[((size_t)b * 8 + h) * 3072 + i] = make_float2(sinhf(a2) / denom, sinf(b2) / denom);
    }
}

// V[((b*8+h)*64+e)*64 + x] = sum_y G[b,h,x,y] * K[..e,y]
__global__ void xqkv_kernel(const float2* __restrict__ G, const float2* __restrict__ XK,
                            float2* __restrict__ V) {
    int b = blockIdx.x, h = blockIdx.y;
    __shared__ float2 Gs[3072];  // [x*48+y]
    __shared__ float2 Ks[3072];  // [e*48+y]
    const float2* gs = G + ((size_t)b * 8 + h) * 3072;
    const float2* ks = XK + ((size_t)b * 8 + h) * 4096;
    for (int i = threadIdx.x; i < 3072; i += 256) {
        Gs[i] = gs[i];
        int e = i / 48, y = i - e * 48;
        Ks[i] = ks[e * 64 + y];
    }
    __syncthreads();
    for (int i = threadIdx.x; i < 4096; i += 256) {
        int e = i >> 6, x = i & 63;
        float re = 0.f, im = 0.f;
#pragma unroll 8
        for (int y = 0; y < 48; y++) {
            float2 gv = Gs[x * 48 + y];
            float2 kv = Ks[e * 48 + y];
            re += gv.x * kv.x - gv.y * kv.y;
            im += gv.x * kv.y + gv.y * kv.x;
        }
        V[((size_t)b * 8 + h) * 4096 + i] = make_float2(re, im);
    }
}

// ---------------------------------------------------------------------------
// series_decomp: SO = (P[+Q]) - movavg25(P[+Q]); trend stored/added to TS
__global__ void decomp_kernel(const float* __restrict__ P, const float* __restrict__ Q,
                              float* __restrict__ SO, float* __restrict__ TS,
                              int L, int tmode) {
    int b = blockIdx.x, d0 = blockIdx.y * 64;
    __shared__ float s[144 * 64];
    for (int i = threadIdx.x; i < L * 64; i += 256) {
        int l = i >> 6, d = i & 63;
        size_t idx = ((size_t)b * L + l) * 512 + d0 + d;
        float v = P[idx];
        if (Q) v += Q[idx];
        s[i] = v;
    }
    __syncthreads();
    for (int i = threadIdx.x; i < L * 64; i += 256) {
        int l = i >> 6, d = i & 63;
        float sum = 0.f;
#pragma unroll
        for (int j = -12; j <= 12; j++) sum += s[iclamp(l + j, 0, L - 1) * 64 + d];
        float ma = sum * (1.0f / 25.0f);
        size_t idx = ((size_t)b * L + l) * 512 + d0 + d;
        SO[idx] = s[i] - ma;
        if (tmode == 1) TS[idx] = ma;
        else if (tmode == 2) TS[idx] += ma;
    }
}

// ---------------------------------------------------------------------------
__global__ __launch_bounds__(256) void ln_rows_kernel(const float* __restrict__ in,
                                                      const float* __restrict__ w,
                                                      const float* __restrict__ bvec,
                                                      float* __restrict__ out) {
    size_t row = blockIdx.x;
    const float* p = in + row * 512;
    int t = threadIdx.x;
    float v0 = p[t], v1 = p[t + 256];
    float s = v0 + v1, s2 = v0 * v0 + v1 * v1;
    for (int o = 32; o > 0; o >>= 1) {
        s += __shfl_xor(s, o, 64);
        s2 += __shfl_xor(s2, o, 64);
    }
    __shared__ float rs[4], rs2[4];
    int wid = t >> 6;
    if ((t & 63) == 0) { rs[wid] = s; rs2[wid] = s2; }
    __syncthreads();
    s = rs[0] + rs[1] + rs[2] + rs[3];
    s2 = rs2[0] + rs2[1] + rs2[2] + rs2[3];
    float mu = s * (1.0f / 512.0f);
    float var = s2 * (1.0f / 512.0f) - mu * mu;
    float r = rsqrtf(var + 1e-5f);
    out[row * 512 + t] = (v0 - mu) * r * w[t] + bvec[t];
    out[row * 512 + t + 256] = (v1 - mu) * r * w[t + 256] + bvec[t + 256];
}

__global__ void timesub_kernel(float* __restrict__ X, int L) {
    int b = blockIdx.x, d0 = blockIdx.y * 64;
    __shared__ float tile[144 * 64];
    __shared__ float mean[64];
    for (int i = threadIdx.x; i < L * 64; i += 256) {
        int l = i >> 6, d = i & 63;
        tile[i] = X[((size_t)b * L + l) * 512 + d0 + d];
    }
    __syncthreads();
    if (threadIdx.x < 64) {
        float sm = 0.f;
        for (int l = 0; l < L; l++) sm += tile[l * 64 + threadIdx.x];
        mean[threadIdx.x] = sm / (float)L;
    }
    __syncthreads();
    for (int i = threadIdx.x; i < L * 64; i += 256) {
        int l = i >> 6, d = i & 63;
        X[((size_t)b * L + l) * 512 + d0 + d] = tile[i] - mean[d];
    }
}

// ---------------------------------------------------------------------------
__global__ void final_kernel(const float* __restrict__ XL, const float* __restrict__ TS,
                             const float* __restrict__ TI, const float* __restrict__ trend_w,
                             const float* __restrict__ proj_w, const float* __restrict__ proj_b,
                             float* __restrict__ out) {
    int idx = blockIdx.x * 256 + threadIdx.x;
    if (idx >= 128 * 96 * 7) return;
    int c = idx % 7;
    int lo = (idx / 7) % 96;
    int b = idx / (7 * 96);
    int l = lo + 48;
    int lm = l - 1;
    int lp = (l == 143) ? 0 : l + 1;
    const float* ts = TS + (size_t)b * 144 * 512;
    const float* xl = XL + ((size_t)b * 144 + l) * 512;
    const float* tw = trend_w + c * 512 * 3;
    const float* pw = proj_w + c * 512;
    float acc = TI[((size_t)b * 144 + l) * 7 + c] + proj_b[c];
    const float* r0 = ts + (size_t)lm * 512;
    const float* r1 = ts + (size_t)l * 512;
    const float* r2 = ts + (size_t)lp * 512;
    for (int d = 0; d < 512; d++) {
        acc += r0[d] * tw[d * 3 + 0] + r1[d] * tw[d * 3 + 1] + r2[d] * tw[d * 3 + 2];
        acc = fmaf(xl[d], pw[d], acc);
    }
    out[idx] = acc;
}

// ---------------------------------------------------------------------------
static inline int cdiv(int a, int b) { return (a + b - 1) / b; }

extern "C" void kernel_launch(void* const* d_in, const int* in_sizes, int n_in,
                              void* d_out, int out_size, void* d_ws, size_t ws_size,
                              hipStream_t stream) {
    const float* x_enc      = (const float*)d_in[0];
    const float* x_mark_enc = (const float*)d_in[1];
    const float* x_mark_dec = (const float*)d_in[3];
    const float* enc_emb_conv_w = (const float*)d_in[4];
    const float* enc_emb_time_w = (const float*)d_in[5];
    const float* dec_emb_conv_w = (const float*)d_in[6];
    const float* dec_emb_time_w = (const float*)d_in[7];
    const float* enc_qw = (const float*)d_in[8];
    const float* enc_qb = (const float*)d_in[9];
    const float* enc_ow = (const float*)d_in[14];
    const float* enc_ob = (const float*)d_in[15];
    const float* enc_fw = (const float*)d_in[16];
    const float* enc_c1 = (const float*)d_in[17];
    const float* enc_c2 = (const float*)d_in[18];
    const float* enc_norm_w = (const float*)d_in[19];
    const float* enc_norm_b = (const float*)d_in[20];
    const float* ds_qw = (const float*)d_in[21];
    const float* ds_qb = (const float*)d_in[22];
    const float* ds_ow = (const float*)d_in[27];
    const float* ds_ob = (const float*)d_in[28];
    const float* ds_fw = (const float*)d_in[29];
    const float* dc_qw = (const float*)d_in[30];
    const float* dc_qb = (const float*)d_in[31];
    const float* dc_kw = (const float*)d_in[32];
    const float* dc_kb = (const float*)d_in[33];
    const float* dc_ow = (const float*)d_in[36];
    const float* dc_ob = (const float*)d_in[37];
    const float* dc_fw = (const float*)d_in[38];
    const float* dec_c1 = (const float*)d_in[39];
    const float* dec_c2 = (const float*)d_in[40];
    const float* dec_trend_w = (const float*)d_in[41];
    const float* dec_norm_w = (const float*)d_in[42];
    const float* dec_norm_b = (const float*)d_in[43];
    const float* proj_w = (const float*)d_in[44];
    const float* proj_b = (const float*)d_in[45];

    float* ws = (float*)d_ws;
    // persistents
    float* XD = ws;                       // 9,437,184
    float* TS = ws + 9437184;             // 9,437,184
    float* XE = ws + 18874368;            // 6,291,456
    float* SI = ws + 25165824;            // 129,024
    float* TI = ws + 25294848;            // 129,024
    float* SC = ws + 25423872;            // scratch: 28,311,552 floats
    // bf16 twiddle tables at scratch tail
    unsigned short* TdbE = (unsigned short*)(SC + 28246016);          // 128*96
    unsigned short* TdbD = (unsigned short*)(SC + 28246016 + 6144);   // 128*160
    unsigned short* TibE = (unsigned short*)(SC + 28246016 + 16384);  // 96*96
    unsigned short* TibD = (unsigned short*)(SC + 28246016 + 20992);  // 144*128

    const size_t need_bytes = (size_t)53735424 * sizeof(float);
    if (ws_size < need_bytes) {
        zero_out_kernel<<<cdiv(out_size, 256), 256, 0, stream>>>((float*)d_out, out_size);
        return;
    }

    auto gemm = [&](const float* A, const float* W, const float* bias, float* Cout,
                    int rows, int N, int K, int lda, int ldw, int gelu, int accum) {
        dim3 g(N / 128, rows / 128);
        gemm_bf16_nt<<<g, 256, 0, stream>>>(A, W, bias, Cout, N, K, lda, ldw, gelu, accum);
    };
    auto ffn = [&](const float* X, const float* c1, const float* c2, int rows,
                   float* hid, float* fout) {
        for (int j0 = 0; j0 < 2048; j0 += 512) {
            gemm(X, c1 + (size_t)j0 * 512, nullptr, hid, rows, 512, 512, 512, 512, 1, 0);
            gemm(hid, c2 + j0, nullptr, fout, rows, 512, 512, 512, 2048, 0, j0 > 0);
        }
    };

    // ---- twiddle tables (constant per call)
    dtab_kernel<<<cdiv(128 * 96, 256), 256, 0, stream>>>(TdbE, 48, 96, 96);
    dtab_kernel<<<cdiv(128 * 160, 256), 256, 0, stream>>>(TdbD, 64, 144, 160);
    itab_kernel<<<cdiv(96 * 96, 256), 256, 0, stream>>>(TibE, 48, 96, 96);
    itab_kernel<<<cdiv(144 * 128, 256), 256, 0, stream>>>(TibD, 64, 144, 128);

    // ---- preprocess + encoder embed
    preprocess_kernel<<<cdiv(128 * 144 * 7, 256), 256, 0, stream>>>(x_enc, SI, TI);
    embed_kernel<<<cdiv(128 * 96 * 512, 256), 256, 0, stream>>>(
        x_enc, x_mark_enc, enc_emb_conv_w, enc_emb_time_w, XE, 96);

    // ---- encoder layers
    for (int l = 0; l < 2; l++) {
        const float* qw = enc_qw + (size_t)l * 512 * 512;
        const float* qb = enc_qb + (size_t)l * 512;
        const float* ow = enc_ow + (size_t)l * 512 * 512;
        const float* ob = enc_ob + (size_t)l * 512;
        const float* fw = enc_fw + (size_t)l * 8 * 64 * 64 * 48 * 2;
        const float* c1 = enc_c1 + (size_t)l * 2048 * 512;
        const float* c2 = enc_c2 + (size_t)l * 512 * 2048;
        float* Pq = SC;                  // 6,291,456
        float* Xf = SC + 6291456;        // 8,388,608
        unsigned short* WBe = (unsigned short*)(SC + 14680064);  // 3,145,728 fl
        float* Yf = SC + 17825792;       // 8,388,608
        float* Tid = SC;                 // 6,291,456 (Pq dead)
        float* To  = SC + 6291456;       // 6,291,456 (Xf dead)

        gemm(XE, qw, qb, Pq, 12288, 512, 512, 512, 512, 0, 0);
        dft_mfma<<<dim3(1, 512), 256, 0, stream>>>(Pq, TdbE, Xf, 96, 96);
        wtrans2_kernel<<<cdiv(384 * 16384, 256), 256, 0, stream>>>(fw, WBe, 48);
        mix_mfma<<<dim3(48, 8), 256, 0, stream>>>(Xf, WBe, Yf, 48);
        idft_mfma<<<dim3(1, 512), 256, 0, stream>>>(Yf, TibE, Tid, 96, 96, 1.f / 96.f);
        gemm(Tid, ow, ob, To, 12288, 512, 512, 512, 512, 0, 0);
        decomp_kernel<<<dim3(128, 8), 256, 0, stream>>>(XE, To, XE, nullptr, 96, 0);
        ffn(XE, c1, c2, 12288, SC, SC + 6291456);
        decomp_kernel<<<dim3(128, 8), 256, 0, stream>>>(XE, SC + 6291456, XE, nullptr, 96, 0);
    }
    ln_rows_kernel<<<12288, 256, 0, stream>>>(XE, enc_norm_w, enc_norm_b, XE);
    timesub_kernel<<<dim3(128, 8), 256, 0, stream>>>(XE, 96);  // XE = enc_out

    // ---- decoder embed
    embed_kernel<<<cdiv(128 * 144 * 512, 256), 256, 0, stream>>>(
        SI, x_mark_dec, dec_emb_conv_w, dec_emb_time_w, XD, 144);

    // ---- decoder self fourier block
    {
        float* Pq = SC;                  // 9,437,184
        float* Xf = SC + 9437184;        // 8,388,608
        unsigned short* WBd = (unsigned short*)(SC + 17825792);  // 4,194,304 fl
        float* Yf = SC;                  // 8,388,608 (Pq dead)
        float* Tid = SC + 8388608;       // 9,437,184 (Xf dead)
        float* To  = SC + 17825792;      // 9,437,184 (WBd dead)

        gemm(XD, ds_qw, ds_qb, Pq, 18432, 512, 512, 512, 512, 0, 0);
        dft_mfma<<<dim3(1, 512), 256, 0, stream>>>(Pq, TdbD, Xf, 144, 160);
        wtrans2_kernel<<<cdiv(512 * 16384, 256), 256, 0, stream>>>(ds_fw, WBd, 64);
        mix_mfma<<<dim3(64, 8), 256, 0, stream>>>(Xf, WBd, Yf, 64);
        idft_mfma<<<dim3(2, 512), 256, 0, stream>>>(Yf, TibD, Tid, 144, 128, 1.f / 144.f);
        gemm(Tid, ds_ow, ds_ob, To, 18432, 512, 512, 512, 512, 0, 0);
        decomp_kernel<<<dim3(128, 8), 256, 0, stream>>>(XD, To, XD, TS, 144, 1);
    }

    // ---- cross attention
    {
        float* Pq = SC;                  // 9,437,184
        float* XQ = SC + 9437184;        // 8,388,608
        float* Pk = SC + 17825792;       // 6,291,456
        float* XK = SC;                  // 8,388,608 (Pq dead)
        float* G  = SC + 17825792;       // 6,291,456 (Pk dead)
        float* V  = SC + 9437184;        // 8,388,608 (XQ dead)
        unsigned short* WBc = (unsigned short*)(SC + 17825792);  // (G dead)
        float* Yf = SC;                  // 8,388,608 (XK dead)
        float* Tid = SC + 8388608;       // 9,437,184 (V dead)
        float* To  = SC + 17825792;      // 9,437,184 (WBc dead)

        gemm(XD, dc_qw, dc_qb, Pq, 18432, 512, 512, 512, 512, 0, 0);
        dft_mfma<<<dim3(1, 512), 256, 0, stream>>>(Pq, TdbD, XQ, 144, 160);
        gemm(XE, dc_kw, dc_kb, Pk, 12288, 512, 512, 512, 512, 0, 0);
        dft_mfma<<<dim3(1, 512), 256, 0, stream>>>(Pk, TdbE, XK, 96, 96);
        xqk_kernel<<<dim3(128, 8), 256, 0, stream>>>((float2*)XQ, (float2*)XK, (float2*)G);
        xqkv_kernel<<<dim3(128, 8), 256, 0, stream>>>((float2*)G, (float2*)XK, (float2*)V);
        wtrans2_kernel<<<cdiv(512 * 16384, 256), 256, 0, stream>>>(dc_fw, WBc, 64);
        mix_mfma<<<dim3(64, 8), 256, 0, stream>>>(V, WBc, Yf, 64);
        idft_mfma<<<dim3(2, 512), 256, 0, stream>>>(Yf, TibD, Tid, 144, 128,
                                                    1.f / (144.f * 262144.f));
        gemm(Tid, dc_ow, dc_ob, To, 18432, 512, 512, 512, 512, 0, 0);
        decomp_kernel<<<dim3(128, 8), 256, 0, stream>>>(XD, To, XD, TS, 144, 2);
    }

    // ---- decoder FFN
    ffn(XD, dec_c1, dec_c2, 18432, SC, SC + 9437184);
    decomp_kernel<<<dim3(128, 8), 256, 0, stream>>>(XD, SC + 9437184, XD, TS, 144, 2);

    // ---- final norm + trend conv + projection
    ln_rows_kernel<<<18432, 256, 0, stream>>>(XD, dec_norm_w, dec_norm_b, XD);
    timesub_kernel<<<dim3(128, 8), 256, 0, stream>>>(XD, 144);
    final_kernel<<<cdiv(128 * 96 * 7, 256), 256, 0, stream>>>(
        XD, TS, TI, dec_trend_w, proj_w, proj_b, (float*)d_out);
}

// Round 5
// 2587.849 us; speedup vs baseline: 2.7182x; 1.1547x over previous
//
#include <hip/hip_runtime.h>
#include <hip/hip_bf16.h>
#include <math.h>

// Model_45904610459674: FEDformer-style forecaster.
// Round 5: final_kernel -> block-per-(b,l) reduction; FFN un-chunked
//          (enc whole, dec 2x1024); wtrans2 fused into mix_mfma (direct
//          float2 gather of fourier weights). Fourier path stays MFMA.
// Workspace: 53,768,192 floats = 215.07 MB, liveness-aliased per phase.

#define PI_F 3.14159265358979323846f

typedef short bf16x8 __attribute__((ext_vector_type(8)));
typedef float f32x4 __attribute__((ext_vector_type(4)));

static __device__ __forceinline__ int iclamp(int v, int lo, int hi) {
    return v < lo ? lo : (v > hi ? hi : v);
}

static __device__ __forceinline__ unsigned pack2(float x, float y) {
    unsigned xu = __float_as_uint(x) + 0x8000u;
    unsigned yu = __float_as_uint(y) + 0x8000u;
    return (xu >> 16) | (yu & 0xFFFF0000u);
}
static __device__ __forceinline__ unsigned short bfr(float x) {
    return (unsigned short)((__float_as_uint(x) + 0x8000u) >> 16);
}

__global__ void zero_out_kernel(float* __restrict__ out, int n) {
    int i = blockIdx.x * 256 + threadIdx.x;
    if (i < n) out[i] = 0.f;
}

// ---------------------------------------------------------------------------
__global__ void preprocess_kernel(const float* __restrict__ xe,
                                  float* __restrict__ SI, float* __restrict__ TI) {
    int idx = blockIdx.x * 256 + threadIdx.x;
    if (idx >= 128 * 144 * 7) return;
    int c = idx % 7;
    int l = (idx / 7) % 144;
    int b = idx / (7 * 144);
    const float* xb = xe + (size_t)b * 96 * 7;
    if (l < 48) {
        int p = 48 + l;
        float sum = 0.f;
        for (int j = -12; j <= 12; j++) sum += xb[iclamp(p + j, 0, 95) * 7 + c];
        float ma = sum * (1.0f / 25.0f);
        SI[idx] = xb[p * 7 + c] - ma;
        TI[idx] = ma;
    } else {
        SI[idx] = 0.f;
        float m = 0.f;
        for (int l2 = 0; l2 < 96; l2++) m += xb[l2 * 7 + c];
        TI[idx] = m * (1.0f / 96.0f);
    }
}

// ---------------------------------------------------------------------------
__global__ void embed_kernel(const float* __restrict__ x, const float* __restrict__ mark,
                             const float* __restrict__ cw, const float* __restrict__ tw,
                             float* __restrict__ out, int L) {
    size_t idx = (size_t)blockIdx.x * 256 + threadIdx.x;
    if (idx >= (size_t)128 * L * 512) return;
    int o = idx & 511;
    int l = (int)((idx >> 9) % L);
    int b = (int)(idx / ((size_t)512 * L));
    int lm = (l == 0) ? L - 1 : l - 1;
    int lp = (l == L - 1) ? 0 : l + 1;
    const float* x0 = x + (size_t)b * L * 7;
    float v = 0.f;
#pragma unroll
    for (int c = 0; c < 7; c++) {
        const float* w = cw + (o * 7 + c) * 3;
        v += x0[lm * 7 + c] * w[0] + x0[l * 7 + c] * w[1] + x0[lp * 7 + c] * w[2];
    }
    const float* mk = mark + ((size_t)b * L + l) * 4;
#pragma unroll
    for (int f = 0; f < 4; f++) v += mk[f] * tw[o * 4 + f];
    out[idx] = v;
}

// ---------------------------------------------------------------------------
// bf16 MFMA GEMM: C = [accum?C:0] + A@W.T (+bias)(+GELU). fp32 in, fp32 out.
__global__ __launch_bounds__(256) void gemm_bf16_nt(
    const float* __restrict__ A, const float* __restrict__ W,
    const float* __restrict__ bias, float* __restrict__ C,
    int N, int K, int lda, int ldw, int gelu, int accum) {
    __shared__ unsigned short As[128 * 72];
    __shared__ unsigned short Ws[128 * 72];
    const int tid = threadIdx.x;
    const int lane = tid & 63, wv = tid >> 6;
    const int wm = (wv & 1) * 64, wn = (wv >> 1) * 64;
    const int q = lane >> 4, ln = lane & 15;
    const size_t bm = (size_t)blockIdx.y * 128;
    const size_t bn = (size_t)blockIdx.x * 128;

    f32x4 acc[4][4];
#pragma unroll
    for (int i = 0; i < 4; i++)
#pragma unroll
        for (int j = 0; j < 4; j++) acc[i][j] = (f32x4){0.f, 0.f, 0.f, 0.f};

    for (int k0 = 0; k0 < K; k0 += 64) {
#pragma unroll
        for (int i = 0; i < 8; i++) {
            int flat = i * 1024 + tid * 4;
            int row = flat >> 6, col = flat & 63;
            const float4 a = *(const float4*)(A + (bm + row) * lda + k0 + col);
            *(uint2*)(&As[row * 72 + col]) =
                make_uint2(pack2(a.x, a.y), pack2(a.z, a.w));
            const float4 b = *(const float4*)(W + (bn + row) * ldw + k0 + col);
            *(uint2*)(&Ws[row * 72 + col]) =
                make_uint2(pack2(b.x, b.y), pack2(b.z, b.w));
        }
        __syncthreads();
#pragma unroll
        for (int kk = 0; kk < 64; kk += 32) {
            bf16x8 af[4], bfr4[4];
            union U8 { bf16x8 v; uint2 u[2]; };
#pragma unroll
            for (int i = 0; i < 4; i++) {
                U8 ua, ub;
                const unsigned short* pa = &As[(wm + i * 16 + ln) * 72 + kk + q * 8];
                ua.u[0] = *(const uint2*)(pa);
                ua.u[1] = *(const uint2*)(pa + 4);
                af[i] = ua.v;
                const unsigned short* pb = &Ws[(wn + i * 16 + ln) * 72 + kk + q * 8];
                ub.u[0] = *(const uint2*)(pb);
                ub.u[1] = *(const uint2*)(pb + 4);
                bfr4[i] = ub.v;
            }
#pragma unroll
            for (int i = 0; i < 4; i++)
#pragma unroll
                for (int j = 0; j < 4; j++)
                    acc[i][j] = __builtin_amdgcn_mfma_f32_16x16x32_bf16(
                        af[i], bfr4[j], acc[i][j], 0, 0, 0);
        }
        __syncthreads();
    }
#pragma unroll
    for (int j = 0; j < 4; j++) {
        int col = (int)bn + wn + j * 16 + ln;
        float bv = bias ? bias[col] : 0.f;
#pragma unroll
        for (int i = 0; i < 4; i++) {
            size_t row0 = bm + wm + i * 16 + q * 4;
#pragma unroll
            for (int r = 0; r < 4; r++) {
                float v = acc[i][j][r] + bv;
                if (gelu) v = 0.5f * v * (1.f + erff(v * 0.70710678118654752f));
                float* p = C + (row0 + r) * N + col;
                if (accum) v += *p;
                *p = v;
            }
        }
    }
}

// ---------------------------------------------------------------------------
// twiddle tables (bf16). dtab: Td[n=2m+p][k=l], ld=ldk, 128 rows, zero pad.
__global__ void dtab_kernel(unsigned short* __restrict__ T, int M, int L, int ldk) {
    int i = blockIdx.x * 256 + threadIdx.x;
    if (i >= 128 * ldk) return;
    int n = i / ldk, k = i - n * ldk;
    float val = 0.f;
    if (n < 2 * M && k < L) {
        int m = n >> 1;
        int r = (m * k) % L;
        float ang = -2.f * PI_F * (float)r / (float)L;
        val = (n & 1) ? sinf(ang) : cosf(ang);
    }
    T[i] = bfr(val);
}
// itab: Ti[n=l][k=2m+p]: Ti[l,2m]=cm*cos, Ti[l,2m+1]=-cm*sin, cm=(m?2:1)
__global__ void itab_kernel(unsigned short* __restrict__ T, int M, int L, int K) {
    int i = blockIdx.x * 256 + threadIdx.x;
    if (i >= L * K) return;
    int n = i / K, k = i - n * K;
    int m = k >> 1;
    float c = (m == 0) ? 1.f : 2.f;
    int r = (m * n) % L;
    float ang = 2.f * PI_F * (float)r / (float)L;
    float val = (k & 1) ? -c * sinf(ang) : c * cosf(ang);
    T[i] = bfr(val);
}

// ---------------------------------------------------------------------------
// dft MFMA: X[(b*512+c)*128 + n] = sum_l P[(b*L+l)*512 + c] * Td[n][l]
__global__ __launch_bounds__(256) void dft_mfma(
    const float* __restrict__ P, const unsigned short* __restrict__ Tdb,
    float* __restrict__ X, int L, int ldk) {
    const int tid = threadIdx.x;
    const int lane = tid & 63, wv = tid >> 6;
    const int wm = (wv & 1) * 64, wn = (wv >> 1) * 64;
    const int q = lane >> 4, ln = lane & 15;
    const int bm = blockIdx.y * 128;
    const int b = bm >> 9, c0 = bm & 511;
    const float* Pb = P + (size_t)b * L * 512;

    f32x4 acc[4][4];
#pragma unroll
    for (int i = 0; i < 4; i++)
#pragma unroll
        for (int j = 0; j < 4; j++) acc[i][j] = (f32x4){0.f, 0.f, 0.f, 0.f};

    for (int k0 = 0; k0 < L; k0 += 32) {
        bf16x8 af[4], bf[4];
        union FR { bf16x8 v; unsigned short s[8]; };
#pragma unroll
        for (int i = 0; i < 4; i++) {
            int c = c0 + wm + i * 16 + ln;
            FR fr;
#pragma unroll
            for (int t = 0; t < 8; t++) {
                int l = k0 + q * 8 + t;
                fr.s[t] = bfr(l < L ? Pb[(size_t)l * 512 + c] : 0.f);
            }
            af[i] = fr.v;
        }
#pragma unroll
        for (int j = 0; j < 4; j++) {
            int n = wn + j * 16 + ln;
            bf[j] = *(const bf16x8*)(Tdb + (size_t)n * ldk + k0 + q * 8);
        }
#pragma unroll
        for (int i = 0; i < 4; i++)
#pragma unroll
            for (int j = 0; j < 4; j++)
                acc[i][j] = __builtin_amdgcn_mfma_f32_16x16x32_bf16(
                    af[i], bf[j], acc[i][j], 0, 0, 0);
    }
#pragma unroll
    for (int j = 0; j < 4; j++) {
        int col = wn + j * 16 + ln;
#pragma unroll
        for (int i = 0; i < 4; i++) {
            int row0 = bm + wm + i * 16 + q * 4;
#pragma unroll
            for (int r = 0; r < 4; r++)
                X[(size_t)(row0 + r) * 128 + col] = acc[i][j][r];
        }
    }
}

// ---------------------------------------------------------------------------
// mix MFMA with fused complex-weight gather: per (h,m):
// C[b][n=2o+q] = sum_k A[b][k=2e+p] * WB[n][k], WB built on the fly from
// w[h][e][o][m][2] via {re,-im;im,re}. A from X (fp32 spectrum), out Y fp32.
__global__ __launch_bounds__(256) void mix_mfma(
    const float* __restrict__ X, const float* __restrict__ w,
    float* __restrict__ Y, int M) {
    const int m = blockIdx.x, h = blockIdx.y;
    const int tid = threadIdx.x;
    const int lane = tid & 63, wv = tid >> 6;
    const int wm = (wv & 1) * 64, wn = (wv >> 1) * 64;
    const int q = lane >> 4, ln = lane & 15;
    const float2* X2 = (const float2*)X;
    const float* wh = w + (size_t)h * 64 * 64 * M * 2 + (size_t)m * 2;

    f32x4 acc[4][4];
#pragma unroll
    for (int i = 0; i < 4; i++)
#pragma unroll
        for (int j = 0; j < 4; j++) acc[i][j] = (f32x4){0.f, 0.f, 0.f, 0.f};

#pragma unroll
    for (int k0 = 0; k0 < 128; k0 += 32) {
        bf16x8 af[4], bf[4];
        union FR { bf16x8 v; unsigned short s[8]; };
        int e0 = (k0 >> 1) + q * 4;
#pragma unroll
        for (int i = 0; i < 4; i++) {
            int b = wm + i * 16 + ln;
            FR fr;
#pragma unroll
            for (int u = 0; u < 4; u++) {
                float2 xv = X2[((size_t)(b * 8 + h) * 64 + e0 + u) * 64 + m];
                fr.s[2 * u] = bfr(xv.x);
                fr.s[2 * u + 1] = bfr(xv.y);
            }
            af[i] = fr.v;
        }
#pragma unroll
        for (int j = 0; j < 4; j++) {
            int n = wn + j * 16 + ln;
            int o = n >> 1, qn = n & 1;
            FR fr;
#pragma unroll
            for (int u = 0; u < 4; u++) {
                int e = e0 + u;
                const float2 wv2 = *(const float2*)(wh + ((size_t)e * 64 + o) * M * 2);
                fr.s[2 * u] = bfr(qn ? wv2.y : wv2.x);
                fr.s[2 * u + 1] = bfr(qn ? wv2.x : -wv2.y);
            }
            bf[j] = fr.v;
        }
#pragma unroll
        for (int i = 0; i < 4; i++)
#pragma unroll
            for (int j = 0; j < 4; j++)
                acc[i][j] = __builtin_amdgcn_mfma_f32_16x16x32_bf16(
                    af[i], bf[j], acc[i][j], 0, 0, 0);
    }
#pragma unroll
    for (int j = 0; j < 4; j++) {
        int n = wn + j * 16 + ln;
        int o = n >> 1, qq = n & 1;
#pragma unroll
        for (int i = 0; i < 4; i++) {
            int b0 = wm + i * 16 + q * 4;
#pragma unroll
            for (int r = 0; r < 4; r++)
                Y[((size_t)((b0 + r) * 8 + h) * 64 + o) * 128 + 2 * m + qq] =
                    acc[i][j][r];
        }
    }
}

// ---------------------------------------------------------------------------
// idft MFMA: Out[(b,h,o)*L + l] = s * sum_k Y[row*128+k]*Ti[l][k], K=2M
__global__ __launch_bounds__(256) void idft_mfma(
    const float* __restrict__ Y, const unsigned short* __restrict__ Tib,
    float* __restrict__ Out, int L, int K, float s) {
    const int tid = threadIdx.x;
    const int lane = tid & 63, wv = tid >> 6;
    const int wm = (wv & 1) * 64, wn = (wv >> 1) * 64;
    const int q = lane >> 4, ln = lane & 15;
    const int bm = blockIdx.y * 128;
    const int bn = blockIdx.x * 128;

    f32x4 acc[4][4];
#pragma unroll
    for (int i = 0; i < 4; i++)
#pragma unroll
        for (int j = 0; j < 4; j++) acc[i][j] = (f32x4){0.f, 0.f, 0.f, 0.f};

    for (int k0 = 0; k0 < K; k0 += 32) {
        bf16x8 af[4], bf[4];
        union FR { bf16x8 v; unsigned short s[8]; };
#pragma unroll
        for (int i = 0; i < 4; i++) {
            const float* ar = Y + (size_t)(bm + wm + i * 16 + ln) * 128 + k0 + q * 8;
            FR fr;
#pragma unroll
            for (int t = 0; t < 8; t++) fr.s[t] = bfr(ar[t]);
            af[i] = fr.v;
        }
#pragma unroll
        for (int j = 0; j < 4; j++) {
            int n = bn + wn + j * 16 + ln;
            if (n < L) bf[j] = *(const bf16x8*)(Tib + (size_t)n * K + k0 + q * 8);
            else bf[j] = (bf16x8){0, 0, 0, 0, 0, 0, 0, 0};
        }
#pragma unroll
        for (int i = 0; i < 4; i++)
#pragma unroll
            for (int j = 0; j < 4; j++)
                acc[i][j] = __builtin_amdgcn_mfma_f32_16x16x32_bf16(
                    af[i], bf[j], acc[i][j], 0, 0, 0);
    }
#pragma unroll
    for (int j = 0; j < 4; j++) {
        int col = bn + wn + j * 16 + ln;
        if (col >= L) continue;
#pragma unroll
        for (int i = 0; i < 4; i++) {
            int row0 = bm + wm + i * 16 + q * 4;
#pragma unroll
            for (int r = 0; r < 4; r++)
                Out[(size_t)(row0 + r) * L + col] = acc[i][j][r] * s;
        }
    }
}

// ---------------------------------------------------------------------------
// cross-attn: G[b,h,x,y] = ctanh(sum_e Q[..e,x]*K[..e,y]); XQ/XK ld = 64 f2
__global__ void xqk_kernel(const float2* __restrict__ XQ, const float2* __restrict__ XK,
                           float2* __restrict__ G) {
    int b = blockIdx.x, h = blockIdx.y;
    __shared__ float2 Qs[4096];  // [e*64+x]
    __shared__ float2 Ks[3072];  // [e*48+y]
    const float2* qs = XQ + ((size_t)b * 8 + h) * 4096;
    const float2* ks = XK + ((size_t)b * 8 + h) * 4096;
    for (int i = threadIdx.x; i < 4096; i += 256) Qs[i] = qs[i];
    for (int i = threadIdx.x; i < 3072; i += 256) {
        int e = i / 48, y = i - e * 48;
        Ks[i] = ks[e * 64 + y];
    }
    __syncthreads();
    for (int i = threadIdx.x; i < 64 * 48; i += 256) {
        int x = i / 48, y = i - x * 48;
        float re = 0.f, im = 0.f;
#pragma unroll 8
        for (int e = 0; e < 64; e++) {
            float2 qv = Qs[e * 64 + x];
            float2 kv = Ks[e * 48 + y];
            re += qv.x * kv.x - qv.y * kv.y;
            im += qv.x * kv.y + qv.y * kv.x;
        }
        float a2 = 2.f * re, b2 = 2.f * im;
        a2 = fminf(fmaxf(a2, -80.f), 80.f);
        float denom = coshf(a2) + cosf(b2);
        G[((size_t)b * 8 + h) * 3072 + i] = make_float2(sinhf(a2) / denom, sinf(b2) / denom);
    }
}

// V[((b*8+h)*64+e)*64 + x] = sum_y G[b,h,x,y] * K[..e,y]
__global__ void xqkv_kernel(const float2* __restrict__ G, const float2* __restrict__ XK,
                            float2* __restrict__ V) {
    int b = blockIdx.x, h = blockIdx.y;
    __shared__ float2 Gs[3072];  // [x*48+y]
    __shared__ float2 Ks[3072];  // [e*48+y]
    const float2* gs = G + ((size_t)b * 8 + h) * 3072;
    const float2* ks = XK + ((size_t)b * 8 + h) * 4096;
    for (int i = threadIdx.x; i < 3072; i += 256) {
        Gs[i] = gs[i];
        int e = i / 48, y = i - e * 48;
        Ks[i] = ks[e * 64 + y];
    }
    __syncthreads();
    for (int i = threadIdx.x; i < 4096; i += 256) {
        int e = i >> 6, x = i & 63;
        float re = 0.f, im = 0.f;
#pragma unroll 8
        for (int y = 0; y < 48; y++) {
            float2 gv = Gs[x * 48 + y];
            float2 kv = Ks[e * 48 + y];
            re += gv.x * kv.x - gv.y * kv.y;
            im += gv.x * kv.y + gv.y * kv.x;
        }
        V[((size_t)b * 8 + h) * 4096 + i] = make_float2(re, im);
    }
}

// ---------------------------------------------------------------------------
// series_decomp: SO = (P[+Q]) - movavg25(P[+Q]); trend stored/added to TS
__global__ void decomp_kernel(const float* __restrict__ P, const float* __restrict__ Q,
                              float* __restrict__ SO, float* __restrict__ TS,
                              int L, int tmode) {
    int b = blockIdx.x, d0 = blockIdx.y * 64;
    __shared__ float s[144 * 64];
    for (int i = threadIdx.x; i < L * 64; i += 256) {
        int l = i >> 6, d = i & 63;
        size_t idx = ((size_t)b * L + l) * 512 + d0 + d;
        float v = P[idx];
        if (Q) v += Q[idx];
        s[i] = v;
    }
    __syncthreads();
    for (int i = threadIdx.x; i < L * 64; i += 256) {
        int l = i >> 6, d = i & 63;
        float sum = 0.f;
#pragma unroll
        for (int j = -12; j <= 12; j++) sum += s[iclamp(l + j, 0, L - 1) * 64 + d];
        float ma = sum * (1.0f / 25.0f);
        size_t idx = ((size_t)b * L + l) * 512 + d0 + d;
        SO[idx] = s[i] - ma;
        if (tmode == 1) TS[idx] = ma;
        else if (tmode == 2) TS[idx] += ma;
    }
}

// ---------------------------------------------------------------------------
__global__ __launch_bounds__(256) void ln_rows_kernel(const float* __restrict__ in,
                                                      const float* __restrict__ w,
                                                      const float* __restrict__ bvec,
                                                      float* __restrict__ out) {
    size_t row = blockIdx.x;
    const float* p = in + row * 512;
    int t = threadIdx.x;
    float v0 = p[t], v1 = p[t + 256];
    float s = v0 + v1, s2 = v0 * v0 + v1 * v1;
    for (int o = 32; o > 0; o >>= 1) {
        s += __shfl_xor(s, o, 64);
        s2 += __shfl_xor(s2, o, 64);
    }
    __shared__ float rs[4], rs2[4];
    int wid = t >> 6;
    if ((t & 63) == 0) { rs[wid] = s; rs2[wid] = s2; }
    __syncthreads();
    s = rs[0] + rs[1] + rs[2] + rs[3];
    s2 = rs2[0] + rs2[1] + rs2[2] + rs2[3];
    float mu = s * (1.0f / 512.0f);
    float var = s2 * (1.0f / 512.0f) - mu * mu;
    float r = rsqrtf(var + 1e-5f);
    out[row * 512 + t] = (v0 - mu) * r * w[t] + bvec[t];
    out[row * 512 + t + 256] = (v1 - mu) * r * w[t + 256] + bvec[t + 256];
}

__global__ void timesub_kernel(float* __restrict__ X, int L) {
    int b = blockIdx.x, d0 = blockIdx.y * 64;
    __shared__ float tile[144 * 64];
    __shared__ float mean[64];
    for (int i = threadIdx.x; i < L * 64; i += 256) {
        int l = i >> 6, d = i & 63;
        tile[i] = X[((size_t)b * L + l) * 512 + d0 + d];
    }
    __syncthreads();
    if (threadIdx.x < 64) {
        float sm = 0.f;
        for (int l = 0; l < L; l++) sm += tile[l * 64 + threadIdx.x];
        mean[threadIdx.x] = sm / (float)L;
    }
    __syncthreads();
    for (int i = threadIdx.x; i < L * 64; i += 256) {
        int l = i >> 6, d = i & 63;
        X[((size_t)b * L + l) * 512 + d0 + d] = tile[i] - mean[d];
    }
}

// ---------------------------------------------------------------------------
// final v2: one block per (b,lo). 256 threads strip-mine d; wave-shuffle +
// LDS reduce the 7 output channels.
__global__ __launch_bounds__(256) void final_v2(
    const float* __restrict__ XL, const float* __restrict__ TS,
    const float* __restrict__ TI, const float* __restrict__ trend_w,
    const float* __restrict__ proj_w, const float* __restrict__ proj_b,
    float* __restrict__ out) {
    int blk = blockIdx.x;          // b*96 + lo
    int b = blk / 96, lo = blk - b * 96;
    int l = lo + 48;
    int lm = l - 1;
    int lp = (l == 143) ? 0 : l + 1;
    const float* ts = TS + (size_t)b * 144 * 512;
    const float* r0 = ts + (size_t)lm * 512;
    const float* r1 = ts + (size_t)l * 512;
    const float* r2 = ts + (size_t)lp * 512;
    const float* xl = XL + ((size_t)b * 144 + l) * 512;
    int t = threadIdx.x;
    float p[7];
#pragma unroll
    for (int c = 0; c < 7; c++) p[c] = 0.f;
#pragma unroll
    for (int dd = 0; dd < 2; dd++) {
        int d = t + dd * 256;
        float a0 = r0[d], a1 = r1[d], a2 = r2[d], x = xl[d];
#pragma unroll
        for (int c = 0; c < 7; c++) {
            const float* tw = trend_w + ((size_t)c * 512 + d) * 3;
            float v = a0 * tw[0] + a1 * tw[1] + a2 * tw[2];
            v = fmaf(x, proj_w[c * 512 + d], v);
            p[c] += v;
        }
    }
#pragma unroll
    for (int o = 32; o > 0; o >>= 1)
#pragma unroll
        for (int c = 0; c < 7; c++) p[c] += __shfl_xor(p[c], o, 64);
    __shared__ float red[4][7];
    int wid = t >> 6;
    if ((t & 63) == 0)
#pragma unroll
        for (int c = 0; c < 7; c++) red[wid][c] = p[c];
    __syncthreads();
    if (t < 7) {
        float v = red[0][t] + red[1][t] + red[2][t] + red[3][t]
                + TI[((size_t)b * 144 + l) * 7 + t] + proj_b[t];
        out[(size_t)blk * 7 + t] = v;
    }
}

// ---------------------------------------------------------------------------
static inline int cdiv(int a, int b) { return (a + b - 1) / b; }

extern "C" void kernel_launch(void* const* d_in, const int* in_sizes, int n_in,
                              void* d_out, int out_size, void* d_ws, size_t ws_size,
                              hipStream_t stream) {
    const float* x_enc      = (const float*)d_in[0];
    const float* x_mark_enc = (const float*)d_in[1];
    const float* x_mark_dec = (const float*)d_in[3];
    const float* enc_emb_conv_w = (const float*)d_in[4];
    const float* enc_emb_time_w = (const float*)d_in[5];
    const float* dec_emb_conv_w = (const float*)d_in[6];
    const float* dec_emb_time_w = (const float*)d_in[7];
    const float* enc_qw = (const float*)d_in[8];
    const float* enc_qb = (const float*)d_in[9];
    const float* enc_ow = (const float*)d_in[14];
    const float* enc_ob = (const float*)d_in[15];
    const float* enc_fw = (const float*)d_in[16];
    const float* enc_c1 = (const float*)d_in[17];
    const float* enc_c2 = (const float*)d_in[18];
    const float* enc_norm_w = (const float*)d_in[19];
    const float* enc_norm_b = (const float*)d_in[20];
    const float* ds_qw = (const float*)d_in[21];
    const float* ds_qb = (const float*)d_in[22];
    const float* ds_ow = (const float*)d_in[27];
    const float* ds_ob = (const float*)d_in[28];
    const float* ds_fw = (const float*)d_in[29];
    const float* dc_qw = (const float*)d_in[30];
    const float* dc_qb = (const float*)d_in[31];
    const float* dc_kw = (const float*)d_in[32];
    const float* dc_kb = (const float*)d_in[33];
    const float* dc_ow = (const float*)d_in[36];
    const float* dc_ob = (const float*)d_in[37];
    const float* dc_fw = (const float*)d_in[38];
    const float* dec_c1 = (const float*)d_in[39];
    const float* dec_c2 = (const float*)d_in[40];
    const float* dec_trend_w = (const float*)d_in[41];
    const float* dec_norm_w = (const float*)d_in[42];
    const float* dec_norm_b = (const float*)d_in[43];
    const float* proj_w = (const float*)d_in[44];
    const float* proj_b = (const float*)d_in[45];

    float* ws = (float*)d_ws;
    // persistents
    float* XD  = ws;                      // 9,437,184
    float* TS  = ws + 9437184;            // 9,437,184 (enc-FFN fout before decoder)
    float* XE  = ws + 18874368;           // 6,291,456
    float* SI  = ws + 25165824;           // 129,024
    float* TI  = ws + 25294848;           // 129,024
    float* TAB = ws + 25423872;           // 32,768 (bf16 twiddle tables)
    float* SC  = ws + 25456640;           // scratch: 28,311,552 floats
    unsigned short* TdbE = (unsigned short*)(TAB);          // 128*96  bf16
    unsigned short* TdbD = (unsigned short*)(TAB + 6144);   // 128*160
    unsigned short* TibE = (unsigned short*)(TAB + 16384);  // 96*96
    unsigned short* TibD = (unsigned short*)(TAB + 20992);  // 144*128

    const size_t need_bytes = (size_t)53768192 * sizeof(float);
    if (ws_size < need_bytes) {
        zero_out_kernel<<<cdiv(out_size, 256), 256, 0, stream>>>((float*)d_out, out_size);
        return;
    }

    auto gemm = [&](const float* A, const float* W, const float* bias, float* Cout,
                    int rows, int N, int K, int lda, int ldw, int gelu, int accum) {
        dim3 g(N / 128, rows / 128);
        gemm_bf16_nt<<<g, 256, 0, stream>>>(A, W, bias, Cout, N, K, lda, ldw, gelu, accum);
    };

    // ---- twiddle tables (constant per call)
    dtab_kernel<<<cdiv(128 * 96, 256), 256, 0, stream>>>(TdbE, 48, 96, 96);
    dtab_kernel<<<cdiv(128 * 160, 256), 256, 0, stream>>>(TdbD, 64, 144, 160);
    itab_kernel<<<cdiv(96 * 96, 256), 256, 0, stream>>>(TibE, 48, 96, 96);
    itab_kernel<<<cdiv(144 * 128, 256), 256, 0, stream>>>(TibD, 64, 144, 128);

    // ---- preprocess + encoder embed
    preprocess_kernel<<<cdiv(128 * 144 * 7, 256), 256, 0, stream>>>(x_enc, SI, TI);
    embed_kernel<<<cdiv(128 * 96 * 512, 256), 256, 0, stream>>>(
        x_enc, x_mark_enc, enc_emb_conv_w, enc_emb_time_w, XE, 96);

    // ---- encoder layers
    for (int l = 0; l < 2; l++) {
        const float* qw = enc_qw + (size_t)l * 512 * 512;
        const float* qb = enc_qb + (size_t)l * 512;
        const float* ow = enc_ow + (size_t)l * 512 * 512;
        const float* ob = enc_ob + (size_t)l * 512;
        const float* fw = enc_fw + (size_t)l * 8 * 64 * 64 * 48 * 2;
        const float* c1 = enc_c1 + (size_t)l * 2048 * 512;
        const float* c2 = enc_c2 + (size_t)l * 512 * 2048;
        float* Pq  = SC;                 // 6,291,456
        float* Xf  = SC + 6291456;       // 8,388,608
        float* Yf  = SC + 14680064;      // 8,388,608
        float* Tid = SC;                 // (Pq dead after dft)
        float* To  = SC + 6291456;       // (Xf dead after mix)

        gemm(XE, qw, qb, Pq, 12288, 512, 512, 512, 512, 0, 0);
        dft_mfma<<<dim3(1, 512), 256, 0, stream>>>(Pq, TdbE, Xf, 96, 96);
        mix_mfma<<<dim3(48, 8), 256, 0, stream>>>(Xf, fw, Yf, 48);
        idft_mfma<<<dim3(1, 512), 256, 0, stream>>>(Yf, TibE, Tid, 96, 96, 1.f / 96.f);
        gemm(Tid, ow, ob, To, 12288, 512, 512, 512, 512, 0, 0);
        decomp_kernel<<<dim3(128, 8), 256, 0, stream>>>(XE, To, XE, nullptr, 96, 0);
        // FFN un-chunked: hidden = SC whole, fout = TS (dead until decoder)
        gemm(XE, c1, nullptr, SC, 12288, 2048, 512, 512, 512, 1, 0);
        gemm(SC, c2, nullptr, TS, 12288, 512, 2048, 2048, 2048, 0, 0);
        decomp_kernel<<<dim3(128, 8), 256, 0, stream>>>(XE, TS, XE, nullptr, 96, 0);
    }
    ln_rows_kernel<<<12288, 256, 0, stream>>>(XE, enc_norm_w, enc_norm_b, XE);
    timesub_kernel<<<dim3(128, 8), 256, 0, stream>>>(XE, 96);  // XE = enc_out

    // ---- decoder embed
    embed_kernel<<<cdiv(128 * 144 * 512, 256), 256, 0, stream>>>(
        SI, x_mark_dec, dec_emb_conv_w, dec_emb_time_w, XD, 144);

    // ---- decoder self fourier block
    {
        float* Pq  = SC;                 // 9,437,184
        float* Xf  = SC + 9437184;       // 8,388,608
        float* Yf  = SC;                 // (Pq dead)
        float* Tid = SC + 8388608;       // (Xf dead)
        float* To  = SC + 17825792;      // 9,437,184

        gemm(XD, ds_qw, ds_qb, Pq, 18432, 512, 512, 512, 512, 0, 0);
        dft_mfma<<<dim3(1, 512), 256, 0, stream>>>(Pq, TdbD, Xf, 144, 160);
        mix_mfma<<<dim3(64, 8), 256, 0, stream>>>(Xf, ds_fw, Yf, 64);
        idft_mfma<<<dim3(2, 512), 256, 0, stream>>>(Yf, TibD, Tid, 144, 128, 1.f / 144.f);
        gemm(Tid, ds_ow, ds_ob, To, 18432, 512, 512, 512, 512, 0, 0);
        decomp_kernel<<<dim3(128, 8), 256, 0, stream>>>(XD, To, XD, TS, 144, 1);
    }

    // ---- cross attention
    {
        float* Pq  = SC;                 // 9,437,184
        float* XQ  = SC + 9437184;       // 8,388,608
        float* Pk  = SC + 17825792;      // 6,291,456
        float* XK  = SC;                 // (Pq dead)
        float* G   = SC + 17825792;      // (Pk dead)
        float* V   = SC + 9437184;       // (XQ dead)
        float* Yf  = SC;                 // (XK dead)
        float* Tid = SC + 8388608;       // (V dead)
        float* To  = SC + 17825792;      // (G dead)

        gemm(XD, dc_qw, dc_qb, Pq, 18432, 512, 512, 512, 512, 0, 0);
        dft_mfma<<<dim3(1, 512), 256, 0, stream>>>(Pq, TdbD, XQ, 144, 160);
        gemm(XE, dc_kw, dc_kb, Pk, 12288, 512, 512, 512, 512, 0, 0);
        dft_mfma<<<dim3(1, 512), 256, 0, stream>>>(Pk, TdbE, XK, 96, 96);
        xqk_kernel<<<dim3(128, 8), 256, 0, stream>>>((float2*)XQ, (float2*)XK, (float2*)G);
        xqkv_kernel<<<dim3(128, 8), 256, 0, stream>>>((float2*)G, (float2*)XK, (float2*)V);
        mix_mfma<<<dim3(64, 8), 256, 0, stream>>>(V, dc_fw, Yf, 64);
        idft_mfma<<<dim3(2, 512), 256, 0, stream>>>(Yf, TibD, Tid, 144, 128,
                                                    1.f / (144.f * 262144.f));
        gemm(Tid, dc_ow, dc_ob, To, 18432, 512, 512, 512, 512, 0, 0);
        decomp_kernel<<<dim3(128, 8), 256, 0, stream>>>(XD, To, XD, TS, 144, 2);
    }

    // ---- decoder FFN: 2 chunks of 1024 (hid 18.9M + fout 9.4M = SC exactly)
    {
        float* hid  = SC;
        float* fout = SC + 18874368;
        for (int j0 = 0; j0 < 2048; j0 += 1024) {
            gemm(XD, dec_c1 + (size_t)j0 * 512, nullptr, hid,
                 18432, 1024, 512, 512, 512, 1, 0);
            gemm(hid, dec_c2 + j0, nullptr, fout,
                 18432, 512, 1024, 1024, 2048, 0, j0 > 0);
        }
        decomp_kernel<<<dim3(128, 8), 256, 0, stream>>>(XD, fout, XD, TS, 144, 2);
    }

    // ---- final norm + trend conv + projection
    ln_rows_kernel<<<18432, 256, 0, stream>>>(XD, dec_norm_w, dec_norm_b, XD);
    timesub_kernel<<<dim3(128, 8), 256, 0, stream>>>(XD, 144);
    final_v2<<<12288, 256, 0, stream>>>(
        XD, TS, TI, dec_trend_w, proj_w, proj_b, (float*)d_out);
}

// Round 6
// 2202.002 us; speedup vs baseline: 3.1945x; 1.1752x over previous
//
#include <hip/hip_runtime.h>
#include <hip/hip_bf16.h>
#include <math.h>

// Model_45904610459674: FEDformer-style forecaster.
// Round 6: layout-coherent Fourier pipeline.
//   dft_mfma2 -> XT[h][m][b][2e+p] bf16 (LDS-transposed epilogue, coalesced)
//   wtrans3   -> WB[hm][2o+q][2e+p] bf16 (LDS-tiled, coalesced both sides)
//   mix_v2    -> direct-b128 MFMA, Y'[hm][b][n] bf16 coalesced
//   idft_v2   -> LDS prologue transposes Y' m-major->k-inner, MFMA, fp32 out
//   xqk2/xqkv2 read XT / write VT in chunk layout.
// Workspace: 53,768,192 floats = 215.07 MB (same guard as R5).

#define PI_F 3.14159265358979323846f

typedef short bf16x8 __attribute__((ext_vector_type(8)));
typedef float f32x4 __attribute__((ext_vector_type(4)));

static __device__ __forceinline__ int iclamp(int v, int lo, int hi) {
    return v < lo ? lo : (v > hi ? hi : v);
}
static __device__ __forceinline__ unsigned pack2(float x, float y) {
    unsigned xu = __float_as_uint(x) + 0x8000u;
    unsigned yu = __float_as_uint(y) + 0x8000u;
    return (xu >> 16) | (yu & 0xFFFF0000u);
}
static __device__ __forceinline__ unsigned short bfr(float x) {
    return (unsigned short)((__float_as_uint(x) + 0x8000u) >> 16);
}
static __device__ __forceinline__ float bf2f(unsigned short s) {
    return __uint_as_float((unsigned)s << 16);
}

__global__ void zero_out_kernel(float* __restrict__ out, int n) {
    int i = blockIdx.x * 256 + threadIdx.x;
    if (i < n) out[i] = 0.f;
}

// ---------------------------------------------------------------------------
__global__ void preprocess_kernel(const float* __restrict__ xe,
                                  float* __restrict__ SI, float* __restrict__ TI) {
    int idx = blockIdx.x * 256 + threadIdx.x;
    if (idx >= 128 * 144 * 7) return;
    int c = idx % 7;
    int l = (idx / 7) % 144;
    int b = idx / (7 * 144);
    const float* xb = xe + (size_t)b * 96 * 7;
    if (l < 48) {
        int p = 48 + l;
        float sum = 0.f;
        for (int j = -12; j <= 12; j++) sum += xb[iclamp(p + j, 0, 95) * 7 + c];
        float ma = sum * (1.0f / 25.0f);
        SI[idx] = xb[p * 7 + c] - ma;
        TI[idx] = ma;
    } else {
        SI[idx] = 0.f;
        float m = 0.f;
        for (int l2 = 0; l2 < 96; l2++) m += xb[l2 * 7 + c];
        TI[idx] = m * (1.0f / 96.0f);
    }
}

// ---------------------------------------------------------------------------
__global__ void embed_kernel(const float* __restrict__ x, const float* __restrict__ mark,
                             const float* __restrict__ cw, const float* __restrict__ tw,
                             float* __restrict__ out, int L) {
    size_t idx = (size_t)blockIdx.x * 256 + threadIdx.x;
    if (idx >= (size_t)128 * L * 512) return;
    int o = idx & 511;
    int l = (int)((idx >> 9) % L);
    int b = (int)(idx / ((size_t)512 * L));
    int lm = (l == 0) ? L - 1 : l - 1;
    int lp = (l == L - 1) ? 0 : l + 1;
    const float* x0 = x + (size_t)b * L * 7;
    float v = 0.f;
#pragma unroll
    for (int c = 0; c < 7; c++) {
        const float* w = cw + (o * 7 + c) * 3;
        v += x0[lm * 7 + c] * w[0] + x0[l * 7 + c] * w[1] + x0[lp * 7 + c] * w[2];
    }
    const float* mk = mark + ((size_t)b * L + l) * 4;
#pragma unroll
    for (int f = 0; f < 4; f++) v += mk[f] * tw[o * 4 + f];
    out[idx] = v;
}

// ---------------------------------------------------------------------------
// bf16 MFMA GEMM: C = [accum?C:0] + A@W.T (+bias)(+GELU). fp32 in/out.
__global__ __launch_bounds__(256) void gemm_bf16_nt(
    const float* __restrict__ A, const float* __restrict__ W,
    const float* __restrict__ bias, float* __restrict__ C,
    int N, int K, int lda, int ldw, int gelu, int accum) {
    __shared__ unsigned short As[128 * 72];
    __shared__ unsigned short Ws[128 * 72];
    const int tid = threadIdx.x;
    const int lane = tid & 63, wv = tid >> 6;
    const int wm = (wv & 1) * 64, wn = (wv >> 1) * 64;
    const int q = lane >> 4, ln = lane & 15;
    const size_t bm = (size_t)blockIdx.y * 128;
    const size_t bn = (size_t)blockIdx.x * 128;

    f32x4 acc[4][4];
#pragma unroll
    for (int i = 0; i < 4; i++)
#pragma unroll
        for (int j = 0; j < 4; j++) acc[i][j] = (f32x4){0.f, 0.f, 0.f, 0.f};

    for (int k0 = 0; k0 < K; k0 += 64) {
#pragma unroll
        for (int i = 0; i < 8; i++) {
            int flat = i * 1024 + tid * 4;
            int row = flat >> 6, col = flat & 63;
            const float4 a = *(const float4*)(A + (bm + row) * lda + k0 + col);
            *(uint2*)(&As[row * 72 + col]) =
                make_uint2(pack2(a.x, a.y), pack2(a.z, a.w));
            const float4 b = *(const float4*)(W + (bn + row) * ldw + k0 + col);
            *(uint2*)(&Ws[row * 72 + col]) =
                make_uint2(pack2(b.x, b.y), pack2(b.z, b.w));
        }
        __syncthreads();
#pragma unroll
        for (int kk = 0; kk < 64; kk += 32) {
            bf16x8 af[4], bfr4[4];
            union U8 { bf16x8 v; uint2 u[2]; };
#pragma unroll
            for (int i = 0; i < 4; i++) {
                U8 ua, ub;
                const unsigned short* pa = &As[(wm + i * 16 + ln) * 72 + kk + q * 8];
                ua.u[0] = *(const uint2*)(pa);
                ua.u[1] = *(const uint2*)(pa + 4);
                af[i] = ua.v;
                const unsigned short* pb = &Ws[(wn + i * 16 + ln) * 72 + kk + q * 8];
                ub.u[0] = *(const uint2*)(pb);
                ub.u[1] = *(const uint2*)(pb + 4);
                bfr4[i] = ub.v;
            }
#pragma unroll
            for (int i = 0; i < 4; i++)
#pragma unroll
                for (int j = 0; j < 4; j++)
                    acc[i][j] = __builtin_amdgcn_mfma_f32_16x16x32_bf16(
                        af[i], bfr4[j], acc[i][j], 0, 0, 0);
        }
        __syncthreads();
    }
#pragma unroll
    for (int j = 0; j < 4; j++) {
        int col = (int)bn + wn + j * 16 + ln;
        float bv = bias ? bias[col] : 0.f;
#pragma unroll
        for (int i = 0; i < 4; i++) {
            size_t row0 = bm + wm + i * 16 + q * 4;
#pragma unroll
            for (int r = 0; r < 4; r++) {
                float v = acc[i][j][r] + bv;
                if (gelu) v = 0.5f * v * (1.f + erff(v * 0.70710678118654752f));
                float* p = C + (row0 + r) * N + col;
                if (accum) v += *p;
                *p = v;
            }
        }
    }
}

// ---------------------------------------------------------------------------
// twiddle tables (bf16). dtab: Td[n=2m+p][k=l], ld=ldk, 128 rows, zero pad.
__global__ void dtab_kernel(unsigned short* __restrict__ T, int M, int L, int ldk) {
    int i = blockIdx.x * 256 + threadIdx.x;
    if (i >= 128 * ldk) return;
    int n = i / ldk, k = i - n * ldk;
    float val = 0.f;
    if (n < 2 * M && k < L) {
        int m = n >> 1;
        int r = (m * k) % L;
        float ang = -2.f * PI_F * (float)r / (float)L;
        val = (n & 1) ? sinf(ang) : cosf(ang);
    }
    T[i] = bfr(val);
}
// itab: Ti[n=l][k=2m+p]: Ti[l,2m]=cm*cos, Ti[l,2m+1]=-cm*sin, cm=(m?2:1)
__global__ void itab_kernel(unsigned short* __restrict__ T, int M, int L, int K) {
    int i = blockIdx.x * 256 + threadIdx.x;
    if (i >= L * K) return;
    int n = i / K, k = i - n * K;
    int m = k >> 1;
    float c = (m == 0) ? 1.f : 2.f;
    int r = (m * n) % L;
    float ang = 2.f * PI_F * (float)r / (float)L;
    float val = (k & 1) ? -c * sinf(ang) : c * cosf(ang);
    T[i] = bfr(val);
}

// ---------------------------------------------------------------------------
// dft MFMA v2: spectrum -> XT[h][m][b][2e+p] bf16 (chunk = 128 b-rows of
// 128 shorts). grid (1,512): block bm: b=bm>>2, c0=(bm&3)*128 (= h-pair).
__global__ __launch_bounds__(256) void dft_mfma2(
    const float* __restrict__ P, const unsigned short* __restrict__ Tdb,
    unsigned short* __restrict__ XT, int L, int ldk, int M) {
    __shared__ unsigned short tile[128 * 130];
    const int tid = threadIdx.x;
    const int lane = tid & 63, wv = tid >> 6;
    const int wm = (wv & 1) * 64, wn = (wv >> 1) * 64;
    const int q = lane >> 4, ln = lane & 15;
    const int bm = blockIdx.y;
    const int b = bm >> 2, c0 = (bm & 3) * 128;
    const int h0 = c0 >> 6;
    const float* Pb = P + (size_t)b * L * 512;

    f32x4 acc[4][4];
#pragma unroll
    for (int i = 0; i < 4; i++)
#pragma unroll
        for (int j = 0; j < 4; j++) acc[i][j] = (f32x4){0.f, 0.f, 0.f, 0.f};

    for (int k0 = 0; k0 < L; k0 += 32) {
        bf16x8 af[4], bf[4];
        union FR { bf16x8 v; unsigned short s[8]; };
#pragma unroll
        for (int i = 0; i < 4; i++) {
            int c = c0 + wm + i * 16 + ln;
            FR fr;
#pragma unroll
            for (int t = 0; t < 8; t++) {
                int l = k0 + q * 8 + t;
                fr.s[t] = bfr(l < L ? Pb[(size_t)l * 512 + c] : 0.f);
            }
            af[i] = fr.v;
        }
#pragma unroll
        for (int j = 0; j < 4; j++) {
            int n = wn + j * 16 + ln;
            bf[j] = *(const bf16x8*)(Tdb + (size_t)n * ldk + k0 + q * 8);
        }
#pragma unroll
        for (int i = 0; i < 4; i++)
#pragma unroll
            for (int j = 0; j < 4; j++)
                acc[i][j] = __builtin_amdgcn_mfma_f32_16x16x32_bf16(
                    af[i], bf[j], acc[i][j], 0, 0, 0);
    }
    // stage into LDS [c_local][n]
#pragma unroll
    for (int j = 0; j < 4; j++) {
        int col = wn + j * 16 + ln;
#pragma unroll
        for (int i = 0; i < 4; i++) {
            int r0 = wm + i * 16 + q * 4;
#pragma unroll
            for (int r = 0; r < 4; r++)
                tile[(r0 + r) * 130 + col] = bfr(acc[i][j][r]);
        }
    }
    __syncthreads();
    // transposed write: chunk (h0+h2, m), dword e
    unsigned* XTu = (unsigned*)XT;
    for (int idx = tid; idx < 2 * M * 64; idx += 256) {
        int chunk = idx >> 6, e = idx & 63;
        int h2 = chunk / M, m = chunk - h2 * M;
        unsigned v = *(const unsigned*)&tile[(h2 * 64 + e) * 130 + 2 * m];
        XTu[((size_t)((h0 + h2) * M + m) * 128 + b) * 64 + e] = v;
    }
}

// ---------------------------------------------------------------------------
// wtrans3: w[h][e][o][m][2] fp32 -> WB[(h*M+m)][n=2o+q][k=2e+p] bf16.
// grid (16, 8): blockIdx.x = ot*2+et (o-tile 8, e-tile 32), blockIdx.y = h.
__global__ __launch_bounds__(256) void wtrans3(
    const float* __restrict__ w, unsigned short* __restrict__ WB, int M) {
    __shared__ float Lre[16 * 289], Lim[16 * 289];  // [mm][e*9+o]
    const int h = blockIdx.y;
    const int ot = blockIdx.x >> 1, et = blockIdx.x & 1;
    const int o0 = ot * 8, e0 = et * 32;
    const int tid = threadIdx.x;
    unsigned* WBu = (unsigned*)WB;
    for (int mc = 0; mc < M; mc += 16) {
        // load: (e 32, o 8, mm 16) float2, coalesced over mm
        for (int idx = tid; idx < 4096; idx += 256) {
            int e = idx >> 7, o = (idx >> 4) & 7, mm = idx & 15;
            const float2 v = *(const float2*)(
                w + ((((size_t)h * 64 + e0 + e) * 64 + o0 + o) * M + mc + mm) * 2);
            Lre[mm * 289 + e * 9 + o] = v.x;
            Lim[mm * 289 + e * 9 + o] = v.y;
        }
        __syncthreads();
        // write: per m: rows n=2(o0+ol)+qn, dwords e (k=2e+p)
        for (int widx = tid; widx < 8192; widx += 256) {
            int mm = widx >> 9, no = (widx >> 5) & 15, e = widx & 31;
            int ol = no >> 1, qn = no & 1;
            float re = Lre[mm * 289 + e * 9 + ol];
            float im = Lim[mm * 289 + e * 9 + ol];
            unsigned v = qn ? pack2(im, re) : pack2(re, -im);
            WBu[((size_t)(h * M + mc + mm) * 128 + 2 * (o0 + ol) + qn) * 64 + e0 + e] = v;
        }
        __syncthreads();
    }
}

// ---------------------------------------------------------------------------
// mix_v2: per (h,m): Y'[b][n] = sum_k XT[hm][b][k] * WB[hm][n][k] (128^3),
// direct b128 loads, Y' bf16 coalesced via LDS restage.
__global__ __launch_bounds__(256) void mix_v2(
    const unsigned short* __restrict__ XT, const unsigned short* __restrict__ WB,
    unsigned short* __restrict__ Yp, int M) {
    __shared__ unsigned short tile[128 * 130];
    const int m = blockIdx.x, h = blockIdx.y;
    const int tid = threadIdx.x;
    const int lane = tid & 63, wv = tid >> 6;
    const int wm = (wv & 1) * 64, wn = (wv >> 1) * 64;
    const int q = lane >> 4, ln = lane & 15;
    const size_t hm = (size_t)h * M + m;
    const unsigned short* Ab = XT + hm * 16384;
    const unsigned short* Bb = WB + hm * 16384;

    f32x4 acc[4][4];
#pragma unroll
    for (int i = 0; i < 4; i++)
#pragma unroll
        for (int j = 0; j < 4; j++) acc[i][j] = (f32x4){0.f, 0.f, 0.f, 0.f};

#pragma unroll
    for (int k0 = 0; k0 < 128; k0 += 32) {
        bf16x8 af[4], bf[4];
#pragma unroll
        for (int i = 0; i < 4; i++)
            af[i] = *(const bf16x8*)(Ab + (size_t)(wm + i * 16 + ln) * 128 + k0 + q * 8);
#pragma unroll
        for (int j = 0; j < 4; j++)
            bf[j] = *(const bf16x8*)(Bb + (size_t)(wn + j * 16 + ln) * 128 + k0 + q * 8);
#pragma unroll
        for (int i = 0; i < 4; i++)
#pragma unroll
            for (int j = 0; j < 4; j++)
                acc[i][j] = __builtin_amdgcn_mfma_f32_16x16x32_bf16(
                    af[i], bf[j], acc[i][j], 0, 0, 0);
    }
#pragma unroll
    for (int j = 0; j < 4; j++) {
        int col = wn + j * 16 + ln;
#pragma unroll
        for (int i = 0; i < 4; i++) {
            int r0 = wm + i * 16 + q * 4;
#pragma unroll
            for (int r = 0; r < 4; r++)
                tile[(r0 + r) * 130 + col] = bfr(acc[i][j][r]);
        }
    }
    __syncthreads();
    unsigned* Yu = (unsigned*)Yp;
    for (int idx = tid; idx < 128 * 64; idx += 256) {
        int b = idx >> 6, dw = idx & 63;
        unsigned v = *(const unsigned*)&tile[b * 130 + 2 * dw];
        Yu[(hm * 128 + b) * 64 + dw] = v;
    }
}

// ---------------------------------------------------------------------------
// idft_v2: Out[(b,h,o)*L + l] = s * sum_k Y[b,h,o][k=2m+q] * Ti[l][k].
// Y' bf16 m-major; LDS prologue transposes to k-inner. grid (cdiv(L,128), 512).
__global__ __launch_bounds__(256) void idft_v2(
    const unsigned short* __restrict__ Yp, const unsigned short* __restrict__ Tib,
    float* __restrict__ Out, int L, int K, int M, float s) {
    __shared__ unsigned short sh[2 * 64 * 132];  // [(h2*M+m)*132 + n]
    const int tid = threadIdx.x;
    const int lane = tid & 63, wv = tid >> 6;
    const int wm = (wv & 1) * 64, wn = (wv >> 1) * 64;
    const int q = lane >> 4, ln = lane & 15;
    const int bm = blockIdx.y;
    const int b = bm >> 2, h0 = (bm & 3) * 2;
    const int bn = blockIdx.x * 128;

    const unsigned* Yu = (const unsigned*)Yp;
    for (int idx = tid; idx < 2 * M * 64; idx += 256) {
        int chunk = idx >> 6, dw = idx & 63;
        int h2 = chunk / M, m = chunk - h2 * M;
        unsigned v = Yu[((size_t)((h0 + h2) * M + m) * 128 + b) * 64 + dw];
        *(unsigned*)&sh[chunk * 132 + 2 * dw] = v;
    }
    __syncthreads();

    f32x4 acc[4][4];
#pragma unroll
    for (int i = 0; i < 4; i++)
#pragma unroll
        for (int j = 0; j < 4; j++) acc[i][j] = (f32x4){0.f, 0.f, 0.f, 0.f};

    for (int k0 = 0; k0 < K; k0 += 32) {
        bf16x8 af[4], bf[4];
        union FR { bf16x8 v; unsigned u[4]; };
#pragma unroll
        for (int i = 0; i < 4; i++) {
            int lr = wm + i * 16 + ln;
            int h2 = lr >> 6, o = lr & 63;
            FR fr;
#pragma unroll
            for (int jj = 0; jj < 4; jj++) {
                int m = (k0 >> 1) + q * 4 + jj;
                fr.u[jj] = *(const unsigned*)&sh[(h2 * M + m) * 132 + 2 * o];
            }
            af[i] = fr.v;
        }
#pragma unroll
        for (int j = 0; j < 4; j++) {
            int n = bn + wn + j * 16 + ln;
            if (n < L) bf[j] = *(const bf16x8*)(Tib + (size_t)n * K + k0 + q * 8);
            else bf[j] = (bf16x8){0, 0, 0, 0, 0, 0, 0, 0};
        }
#pragma unroll
        for (int i = 0; i < 4; i++)
#pragma unroll
            for (int j = 0; j < 4; j++)
                acc[i][j] = __builtin_amdgcn_mfma_f32_16x16x32_bf16(
                    af[i], bf[j], acc[i][j], 0, 0, 0);
    }
#pragma unroll
    for (int j = 0; j < 4; j++) {
        int col = bn + wn + j * 16 + ln;
        if (col >= L) continue;
#pragma unroll
        for (int i = 0; i < 4; i++) {
            int row0 = bm * 128 + wm + i * 16 + q * 4;
#pragma unroll
            for (int r = 0; r < 4; r++)
                Out[(size_t)(row0 + r) * L + col] = acc[i][j][r] * s;
        }
    }
}

// ---------------------------------------------------------------------------
// xqk2: G[b,h,x,y] = ctanh(sum_e Q[e,x] conj-less K[e,y]) from XT chunks.
__global__ __launch_bounds__(256) void xqk2(
    const unsigned short* __restrict__ XTQ, const unsigned short* __restrict__ XTK,
    float2* __restrict__ G) {
    __shared__ float Qre[64 * 65], Qim[64 * 65];  // [e*65 + x]
    __shared__ float Kre[64 * 49], Kim[64 * 49];  // [e*49 + y]
    int b = blockIdx.x, h = blockIdx.y;
    const unsigned* Qu = (const unsigned*)XTQ;
    const unsigned* Ku = (const unsigned*)XTK;
    for (int idx = threadIdx.x; idx < 64 * 64; idx += 256) {
        int x = idx >> 6, e = idx & 63;
        unsigned v = Qu[((size_t)(h * 64 + x) * 128 + b) * 64 + e];
        Qre[e * 65 + x] = bf2f((unsigned short)(v & 0xFFFF));
        Qim[e * 65 + x] = bf2f((unsigned short)(v >> 16));
    }
    for (int idx = threadIdx.x; idx < 48 * 64; idx += 256) {
        int y = idx >> 6, e = idx & 63;
        unsigned v = Ku[((size_t)(h * 48 + y) * 128 + b) * 64 + e];
        Kre[e * 49 + y] = bf2f((unsigned short)(v & 0xFFFF));
        Kim[e * 49 + y] = bf2f((unsigned short)(v >> 16));
    }
    __syncthreads();
    for (int i = threadIdx.x; i < 64 * 48; i += 256) {
        int x = i / 48, y = i - x * 48;
        float re = 0.f, im = 0.f;
#pragma unroll 8
        for (int e = 0; e < 64; e++) {
            float qr = Qre[e * 65 + x], qi = Qim[e * 65 + x];
            float kr = Kre[e * 49 + y], ki = Kim[e * 49 + y];
            re += qr * kr - qi * ki;
            im += qr * ki + qi * kr;
        }
        float a2 = 2.f * re, b2 = 2.f * im;
        a2 = fminf(fmaxf(a2, -80.f), 80.f);
        float denom = coshf(a2) + cosf(b2);
        G[((size_t)b * 8 + h) * 3072 + i] = make_float2(sinhf(a2) / denom, sinf(b2) / denom);
    }
}

// xqkv2: VT[h][x][b][2e+p] bf16 = sum_y G[x,y] * K[e,y]
__global__ __launch_bounds__(256) void xqkv2(
    const float2* __restrict__ G, const unsigned short* __restrict__ XTK,
    unsigned short* __restrict__ VT) {
    __shared__ float Gre[64 * 49], Gim[64 * 49];  // [x*49 + y]
    __shared__ float Kre[64 * 49], Kim[64 * 49];  // [e*49 + y]
    int b = blockIdx.x, h = blockIdx.y;
    const unsigned* Ku = (const unsigned*)XTK;
    const float2* gs = G + ((size_t)b * 8 + h) * 3072;
    for (int idx = threadIdx.x; idx < 64 * 48; idx += 256) {
        int x = idx / 48, y = idx - x * 48;
        float2 g = gs[idx];
        Gre[x * 49 + y] = g.x;
        Gim[x * 49 + y] = g.y;
    }
    for (int idx = threadIdx.x; idx < 48 * 64; idx += 256) {
        int y = idx >> 6, e = idx & 63;
        unsigned v = Ku[((size_t)(h * 48 + y) * 128 + b) * 64 + e];
        Kre[e * 49 + y] = bf2f((unsigned short)(v & 0xFFFF));
        Kim[e * 49 + y] = bf2f((unsigned short)(v >> 16));
    }
    __syncthreads();
    unsigned* Vu = (unsigned*)VT;
    for (int idx = threadIdx.x; idx < 4096; idx += 256) {
        int x = idx >> 6, e = idx & 63;
        float re = 0.f, im = 0.f;
#pragma unroll 8
        for (int y = 0; y < 48; y++) {
            float gr = Gre[x * 49 + y], gi = Gim[x * 49 + y];
            float kr = Kre[e * 49 + y], ki = Kim[e * 49 + y];
            re += gr * kr - gi * ki;
            im += gr * ki + gi * kr;
        }
        Vu[((size_t)(h * 64 + x) * 128 + b) * 64 + e] = pack2(re, im);
    }
}

// ---------------------------------------------------------------------------
__global__ void decomp_kernel(const float* __restrict__ P, const float* __restrict__ Q,
                              float* __restrict__ SO, float* __restrict__ TS,
                              int L, int tmode) {
    int b = blockIdx.x, d0 = blockIdx.y * 64;
    __shared__ float s[144 * 64];
    for (int i = threadIdx.x; i < L * 64; i += 256) {
        int l = i >> 6, d = i & 63;
        size_t idx = ((size_t)b * L + l) * 512 + d0 + d;
        float v = P[idx];
        if (Q) v += Q[idx];
        s[i] = v;
    }
    __syncthreads();
    for (int i = threadIdx.x; i < L * 64; i += 256) {
        int l = i >> 6, d = i & 63;
        float sum = 0.f;
#pragma unroll
        for (int j = -12; j <= 12; j++) sum += s[iclamp(l + j, 0, L - 1) * 64 + d];
        float ma = sum * (1.0f / 25.0f);
        size_t idx = ((size_t)b * L + l) * 512 + d0 + d;
        SO[idx] = s[i] - ma;
        if (tmode == 1) TS[idx] = ma;
        else if (tmode == 2) TS[idx] += ma;
    }
}

// ---------------------------------------------------------------------------
__global__ __launch_bounds__(256) void ln_rows_kernel(const float* __restrict__ in,
                                                      const float* __restrict__ w,
                                                      const float* __restrict__ bvec,
                                                      float* __restrict__ out) {
    size_t row = blockIdx.x;
    const float* p = in + row * 512;
    int t = threadIdx.x;
    float v0 = p[t], v1 = p[t + 256];
    float s = v0 + v1, s2 = v0 * v0 + v1 * v1;
    for (int o = 32; o > 0; o >>= 1) {
        s += __shfl_xor(s, o, 64);
        s2 += __shfl_xor(s2, o, 64);
    }
    __shared__ float rs[4], rs2[4];
    int wid = t >> 6;
    if ((t & 63) == 0) { rs[wid] = s; rs2[wid] = s2; }
    __syncthreads();
    s = rs[0] + rs[1] + rs[2] + rs[3];
    s2 = rs2[0] + rs2[1] + rs2[2] + rs2[3];
    float mu = s * (1.0f / 512.0f);
    float var = s2 * (1.0f / 512.0f) - mu * mu;
    float r = rsqrtf(var + 1e-5f);
    out[row * 512 + t] = (v0 - mu) * r * w[t] + bvec[t];
    out[row * 512 + t + 256] = (v1 - mu) * r * w[t + 256] + bvec[t + 256];
}

__global__ void timesub_kernel(float* __restrict__ X, int L) {
    int b = blockIdx.x, d0 = blockIdx.y * 64;
    __shared__ float tile[144 * 64];
    __shared__ float mean[64];
    for (int i = threadIdx.x; i < L * 64; i += 256) {
        int l = i >> 6, d = i & 63;
        tile[i] = X[((size_t)b * L + l) * 512 + d0 + d];
    }
    __syncthreads();
    if (threadIdx.x < 64) {
        float sm = 0.f;
        for (int l = 0; l < L; l++) sm += tile[l * 64 + threadIdx.x];
        mean[threadIdx.x] = sm / (float)L;
    }
    __syncthreads();
    for (int i = threadIdx.x; i < L * 64; i += 256) {
        int l = i >> 6, d = i & 63;
        X[((size_t)b * L + l) * 512 + d0 + d] = tile[i] - mean[d];
    }
}

// ---------------------------------------------------------------------------
__global__ __launch_bounds__(256) void final_v2(
    const float* __restrict__ XL, const float* __restrict__ TS,
    const float* __restrict__ TI, const float* __restrict__ trend_w,
    const float* __restrict__ proj_w, const float* __restrict__ proj_b,
    float* __restrict__ out) {
    int blk = blockIdx.x;
    int b = blk / 96, lo = blk - b * 96;
    int l = lo + 48;
    int lm = l - 1;
    int lp = (l == 143) ? 0 : l + 1;
    const float* ts = TS + (size_t)b * 144 * 512;
    const float* r0 = ts + (size_t)lm * 512;
    const float* r1 = ts + (size_t)l * 512;
    const float* r2 = ts + (size_t)lp * 512;
    const float* xl = XL + ((size_t)b * 144 + l) * 512;
    int t = threadIdx.x;
    float p[7];
#pragma unroll
    for (int c = 0; c < 7; c++) p[c] = 0.f;
#pragma unroll
    for (int dd = 0; dd < 2; dd++) {
        int d = t + dd * 256;
        float a0 = r0[d], a1 = r1[d], a2 = r2[d], x = xl[d];
#pragma unroll
        for (int c = 0; c < 7; c++) {
            const float* tw = trend_w + ((size_t)c * 512 + d) * 3;
            float v = a0 * tw[0] + a1 * tw[1] + a2 * tw[2];
            v = fmaf(x, proj_w[c * 512 + d], v);
            p[c] += v;
        }
    }
#pragma unroll
    for (int o = 32; o > 0; o >>= 1)
#pragma unroll
        for (int c = 0; c < 7; c++) p[c] += __shfl_xor(p[c], o, 64);
    __shared__ float red[4][7];
    int wid = t >> 6;
    if ((t & 63) == 0)
#pragma unroll
        for (int c = 0; c < 7; c++) red[wid][c] = p[c];
    __syncthreads();
    if (t < 7) {
        float v = red[0][t] + red[1][t] + red[2][t] + red[3][t]
                + TI[((size_t)b * 144 + l) * 7 + t] + proj_b[t];
        out[(size_t)blk * 7 + t] = v;
    }
}

// ---------------------------------------------------------------------------
static inline int cdiv(int a, int b) { return (a + b - 1) / b; }

extern "C" void kernel_launch(void* const* d_in, const int* in_sizes, int n_in,
                              void* d_out, int out_size, void* d_ws, size_t ws_size,
                              hipStream_t stream) {
    const float* x_enc      = (const float*)d_in[0];
    const float* x_mark_enc = (const float*)d_in[1];
    const float* x_mark_dec = (const float*)d_in[3];
    const float* enc_emb_conv_w = (const float*)d_in[4];
    const float* enc_emb_time_w = (const float*)d_in[5];
    const float* dec_emb_conv_w = (const float*)d_in[6];
    const float* dec_emb_time_w = (const float*)d_in[7];
    const float* enc_qw = (const float*)d_in[8];
    const float* enc_qb = (const float*)d_in[9];
    const float* enc_ow = (const float*)d_in[14];
    const float* enc_ob = (const float*)d_in[15];
    const float* enc_fw = (const float*)d_in[16];
    const float* enc_c1 = (const float*)d_in[17];
    const float* enc_c2 = (const float*)d_in[18];
    const float* enc_norm_w = (const float*)d_in[19];
    const float* enc_norm_b = (const float*)d_in[20];
    const float* ds_qw = (const float*)d_in[21];
    const float* ds_qb = (const float*)d_in[22];
    const float* ds_ow = (const float*)d_in[27];
    const float* ds_ob = (const float*)d_in[28];
    const float* ds_fw = (const float*)d_in[29];
    const float* dc_qw = (const float*)d_in[30];
    const float* dc_qb = (const float*)d_in[31];
    const float* dc_kw = (const float*)d_in[32];
    const float* dc_kb = (const float*)d_in[33];
    const float* dc_ow = (const float*)d_in[36];
    const float* dc_ob = (const float*)d_in[37];
    const float* dc_fw = (const float*)d_in[38];
    const float* dec_c1 = (const float*)d_in[39];
    const float* dec_c2 = (const float*)d_in[40];
    const float* dec_trend_w = (const float*)d_in[41];
    const float* dec_norm_w = (const float*)d_in[42];
    const float* dec_norm_b = (const float*)d_in[43];
    const float* proj_w = (const float*)d_in[44];
    const float* proj_b = (const float*)d_in[45];

    float* ws = (float*)d_ws;
    float* XD  = ws;                      // 9,437,184
    float* TS  = ws + 9437184;            // 9,437,184
    float* XE  = ws + 18874368;           // 6,291,456
    float* SI  = ws + 25165824;           // 129,024
    float* TI  = ws + 25294848;           // 129,024
    float* TAB = ws + 25423872;           // 32,768
    float* SC  = ws + 25456640;           // scratch: 28,311,552 floats
    unsigned short* TdbE = (unsigned short*)(TAB);
    unsigned short* TdbD = (unsigned short*)(TAB + 6144);
    unsigned short* TibE = (unsigned short*)(TAB + 16384);
    unsigned short* TibD = (unsigned short*)(TAB + 20992);

    const size_t need_bytes = (size_t)53768192 * sizeof(float);
    if (ws_size < need_bytes) {
        zero_out_kernel<<<cdiv(out_size, 256), 256, 0, stream>>>((float*)d_out, out_size);
        return;
    }

    auto gemm = [&](const float* A, const float* W, const float* bias, float* Cout,
                    int rows, int N, int K, int lda, int ldw, int gelu, int accum) {
        dim3 g(N / 128, rows / 128);
        gemm_bf16_nt<<<g, 256, 0, stream>>>(A, W, bias, Cout, N, K, lda, ldw, gelu, accum);
    };

    // ---- twiddle tables
    dtab_kernel<<<cdiv(128 * 96, 256), 256, 0, stream>>>(TdbE, 48, 96, 96);
    dtab_kernel<<<cdiv(128 * 160, 256), 256, 0, stream>>>(TdbD, 64, 144, 160);
    itab_kernel<<<cdiv(96 * 96, 256), 256, 0, stream>>>(TibE, 48, 96, 96);
    itab_kernel<<<cdiv(144 * 128, 256), 256, 0, stream>>>(TibD, 64, 144, 128);

    // ---- preprocess + encoder embed
    preprocess_kernel<<<cdiv(128 * 144 * 7, 256), 256, 0, stream>>>(x_enc, SI, TI);
    embed_kernel<<<cdiv(128 * 96 * 512, 256), 256, 0, stream>>>(
        x_enc, x_mark_enc, enc_emb_conv_w, enc_emb_time_w, XE, 96);

    // ---- encoder layers (M=48)
    for (int l = 0; l < 2; l++) {
        const float* qw = enc_qw + (size_t)l * 512 * 512;
        const float* qb = enc_qb + (size_t)l * 512;
        const float* ow = enc_ow + (size_t)l * 512 * 512;
        const float* ob = enc_ob + (size_t)l * 512;
        const float* fw = enc_fw + (size_t)l * 8 * 64 * 64 * 48 * 2;
        const float* c1 = enc_c1 + (size_t)l * 2048 * 512;
        const float* c2 = enc_c2 + (size_t)l * 512 * 2048;
        float* Pq = SC;                                       // 6,291,456 fl
        unsigned short* XT = (unsigned short*)(SC + 6291456); // 3,145,728 fl
        unsigned short* WB = (unsigned short*)(SC + 9437184); // 3,145,728 fl
        unsigned short* Yp = (unsigned short*)(SC + 12582912);// 3,145,728 fl
        float* Tid = SC;                                      // Pq dead
        float* To  = SC + 6291456;                            // XT/WB dead

        gemm(XE, qw, qb, Pq, 12288, 512, 512, 512, 512, 0, 0);
        dft_mfma2<<<dim3(1, 512), 256, 0, stream>>>(Pq, TdbE, XT, 96, 96, 48);
        wtrans3<<<dim3(16, 8), 256, 0, stream>>>(fw, WB, 48);
        mix_v2<<<dim3(48, 8), 256, 0, stream>>>(XT, WB, Yp, 48);
        idft_v2<<<dim3(1, 512), 256, 0, stream>>>(Yp, TibE, Tid, 96, 96, 48, 1.f / 96.f);
        gemm(Tid, ow, ob, To, 12288, 512, 512, 512, 512, 0, 0);
        decomp_kernel<<<dim3(128, 8), 256, 0, stream>>>(XE, To, XE, nullptr, 96, 0);
        gemm(XE, c1, nullptr, SC, 12288, 2048, 512, 512, 512, 1, 0);
        gemm(SC, c2, nullptr, TS, 12288, 512, 2048, 2048, 2048, 0, 0);
        decomp_kernel<<<dim3(128, 8), 256, 0, stream>>>(XE, TS, XE, nullptr, 96, 0);
    }
    ln_rows_kernel<<<12288, 256, 0, stream>>>(XE, enc_norm_w, enc_norm_b, XE);
    timesub_kernel<<<dim3(128, 8), 256, 0, stream>>>(XE, 96);  // XE = enc_out

    // ---- decoder embed
    embed_kernel<<<cdiv(128 * 144 * 512, 256), 256, 0, stream>>>(
        SI, x_mark_dec, dec_emb_conv_w, dec_emb_time_w, XD, 144);

    // ---- decoder self fourier block (M=64)
    {
        float* Pq = SC;                                        // 9,437,184
        unsigned short* XT = (unsigned short*)(SC + 9437184);  // 4,194,304 fl
        unsigned short* WB = (unsigned short*)(SC + 13631488); // 4,194,304 fl
        unsigned short* Yp = (unsigned short*)(SC + 17825792); // 4,194,304 fl
        float* Tid = SC;                                       // Pq dead
        float* To  = SC + 9437184;                             // XT/WB dead

        gemm(XD, ds_qw, ds_qb, Pq, 18432, 512, 512, 512, 512, 0, 0);
        dft_mfma2<<<dim3(1, 512), 256, 0, stream>>>(Pq, TdbD, XT, 144, 160, 64);
        wtrans3<<<dim3(16, 8), 256, 0, stream>>>(ds_fw, WB, 64);
        mix_v2<<<dim3(64, 8), 256, 0, stream>>>(XT, WB, Yp, 64);
        idft_v2<<<dim3(2, 512), 256, 0, stream>>>(Yp, TibD, Tid, 144, 128, 64, 1.f / 144.f);
        gemm(Tid, ds_ow, ds_ob, To, 18432, 512, 512, 512, 512, 0, 0);
        decomp_kernel<<<dim3(128, 8), 256, 0, stream>>>(XD, To, XD, TS, 144, 1);
    }

    // ---- cross attention (K first for liveness)
    {
        float* Pk = SC;                                        // 6,291,456
        unsigned short* XTK = (unsigned short*)(SC + 6291456); // 3,145,728 fl
        float* Pq = SC + 9437184;                              // 9,437,184
        unsigned short* XTQ = (unsigned short*)(SC + 18874368);// 4,194,304 fl
        float* G = SC;                                         // 6,291,456 (Pk dead)
        unsigned short* VT = (unsigned short*)(SC + 9437184);  // 4,194,304 (Pq dead)
        unsigned short* WB = (unsigned short*)(SC + 13631488); // 4,194,304
        unsigned short* Yp = (unsigned short*)(SC);            // 4,194,304 (G dead)
        float* Tid = SC + 4194304;                             // 9,437,184
        float* To  = SC + 13631488;                            // 9,437,184 (WB dead)

        gemm(XE, dc_kw, dc_kb, Pk, 12288, 512, 512, 512, 512, 0, 0);
        dft_mfma2<<<dim3(1, 512), 256, 0, stream>>>(Pk, TdbE, XTK, 96, 96, 48);
        gemm(XD, dc_qw, dc_qb, Pq, 18432, 512, 512, 512, 512, 0, 0);
        dft_mfma2<<<dim3(1, 512), 256, 0, stream>>>(Pq, TdbD, XTQ, 144, 160, 64);
        xqk2<<<dim3(128, 8), 256, 0, stream>>>(XTQ, XTK, (float2*)G);
        xqkv2<<<dim3(128, 8), 256, 0, stream>>>((float2*)G, XTK, VT);
        wtrans3<<<dim3(16, 8), 256, 0, stream>>>(dc_fw, WB, 64);
        mix_v2<<<dim3(64, 8), 256, 0, stream>>>(VT, WB, Yp, 64);
        idft_v2<<<dim3(2, 512), 256, 0, stream>>>(Yp, TibD, Tid, 144, 128, 64,
                                                  1.f / (144.f * 262144.f));
        gemm(Tid, dc_ow, dc_ob, To, 18432, 512, 512, 512, 512, 0, 0);
        decomp_kernel<<<dim3(128, 8), 256, 0, stream>>>(XD, To, XD, TS, 144, 2);
    }

    // ---- decoder FFN: 2 chunks of 1024
    {
        float* hid  = SC;
        float* fout = SC + 18874368;
        for (int j0 = 0; j0 < 2048; j0 += 1024) {
            gemm(XD, dec_c1 + (size_t)j0 * 512, nullptr, hid,
                 18432, 1024, 512, 512, 512, 1, 0);
            gemm(hid, dec_c2 + j0, nullptr, fout,
                 18432, 512, 1024, 1024, 2048, 0, j0 > 0);
        }
        decomp_kernel<<<dim3(128, 8), 256, 0, stream>>>(XD, fout, XD, TS, 144, 2);
    }

    // ---- final norm + trend conv + projection
    ln_rows_kernel<<<18432, 256, 0, stream>>>(XD, dec_norm_w, dec_norm_b, XD);
    timesub_kernel<<<dim3(128, 8), 256, 0, stream>>>(XD, 144);
    final_v2<<<12288, 256, 0, stream>>>(
        XD, TS, TI, dec_trend_w, proj_w, proj_b, (float*)d_out);
}

// Round 7
// 1850.478 us; speedup vs baseline: 3.8013x; 1.1900x over previous
//
#include <hip/hip_runtime.h>
#include <hip/hip_bf16.h>
#include <math.h>

// Model_45904610459674: FEDformer-style forecaster.
// Round 7: bf16-resident GEMM operands.
//   f2b: weights -> bf16 arena once per call (16.5 MB).
//   gemm_bb: A,W bf16 in HBM; staging = uint4 load + uint4 LDS store (no
//            conversion VALU); out fp32 (residual) or bf16 (GEMM/DFT consumer).
//   Producers emit bf16 copies (embed/decomp/timesub); idft emits bf16;
//   G packed bf16. Same rounding points as R6 -> same numerics.
// Workspace: 53,768,192 floats = 215.07 MB (same guard).

#define PI_F 3.14159265358979323846f

typedef short bf16x8 __attribute__((ext_vector_type(8)));
typedef float f32x4 __attribute__((ext_vector_type(4)));

static __device__ __forceinline__ int iclamp(int v, int lo, int hi) {
    return v < lo ? lo : (v > hi ? hi : v);
}
static __device__ __forceinline__ unsigned pack2(float x, float y) {
    unsigned xu = __float_as_uint(x) + 0x8000u;
    unsigned yu = __float_as_uint(y) + 0x8000u;
    return (xu >> 16) | (yu & 0xFFFF0000u);
}
static __device__ __forceinline__ unsigned short bfr(float x) {
    return (unsigned short)((__float_as_uint(x) + 0x8000u) >> 16);
}
static __device__ __forceinline__ float bf2f(unsigned short s) {
    return __uint_as_float((unsigned)s << 16);
}

__global__ void zero_out_kernel(float* __restrict__ out, int n) {
    int i = blockIdx.x * 256 + threadIdx.x;
    if (i < n) out[i] = 0.f;
}

// f2b: fp32 -> bf16, 4 elems/thread
__global__ void f2b(const float* __restrict__ s, unsigned short* __restrict__ d, int n) {
    int i = (blockIdx.x * 256 + threadIdx.x) * 4;
    if (i >= n) return;
    const float4 v = *(const float4*)(s + i);
    *(uint2*)(d + i) = make_uint2(pack2(v.x, v.y), pack2(v.z, v.w));
}

// ---------------------------------------------------------------------------
__global__ void preprocess_kernel(const float* __restrict__ xe,
                                  float* __restrict__ SI, float* __restrict__ TI) {
    int idx = blockIdx.x * 256 + threadIdx.x;
    if (idx >= 128 * 144 * 7) return;
    int c = idx % 7;
    int l = (idx / 7) % 144;
    int b = idx / (7 * 144);
    const float* xb = xe + (size_t)b * 96 * 7;
    if (l < 48) {
        int p = 48 + l;
        float sum = 0.f;
        for (int j = -12; j <= 12; j++) sum += xb[iclamp(p + j, 0, 95) * 7 + c];
        float ma = sum * (1.0f / 25.0f);
        SI[idx] = xb[p * 7 + c] - ma;
        TI[idx] = ma;
    } else {
        SI[idx] = 0.f;
        float m = 0.f;
        for (int l2 = 0; l2 < 96; l2++) m += xb[l2 * 7 + c];
        TI[idx] = m * (1.0f / 96.0f);
    }
}

// ---------------------------------------------------------------------------
// embed + bf16 copy
__global__ void embed_kernel(const float* __restrict__ x, const float* __restrict__ mark,
                             const float* __restrict__ cw, const float* __restrict__ tw,
                             float* __restrict__ out, unsigned short* __restrict__ outb,
                             int L) {
    size_t idx = (size_t)blockIdx.x * 256 + threadIdx.x;
    if (idx >= (size_t)128 * L * 512) return;
    int o = idx & 511;
    int l = (int)((idx >> 9) % L);
    int b = (int)(idx / ((size_t)512 * L));
    int lm = (l == 0) ? L - 1 : l - 1;
    int lp = (l == L - 1) ? 0 : l + 1;
    const float* x0 = x + (size_t)b * L * 7;
    float v = 0.f;
#pragma unroll
    for (int c = 0; c < 7; c++) {
        const float* w = cw + (o * 7 + c) * 3;
        v += x0[lm * 7 + c] * w[0] + x0[l * 7 + c] * w[1] + x0[lp * 7 + c] * w[2];
    }
    const float* mk = mark + ((size_t)b * L + l) * 4;
#pragma unroll
    for (int f = 0; f < 4; f++) v += mk[f] * tw[o * 4 + f];
    out[idx] = v;
    outb[idx] = bfr(v);
}

// ---------------------------------------------------------------------------
// gemm_bb: A,W bf16. C = [accum?C:0] + A@W.T (+bias)(+GELU).
// Out fp32 (Cf) or bf16 (Cb). 128x128 tile, BK=64, 256 thr, 16x16x32 MFMA.
__global__ __launch_bounds__(256) void gemm_bb(
    const unsigned short* __restrict__ A, const unsigned short* __restrict__ W,
    const float* __restrict__ bias, float* __restrict__ Cf,
    unsigned short* __restrict__ Cb,
    int N, int K, int lda, int ldw, int gelu, int accum) {
    __shared__ unsigned short As[128 * 72];
    __shared__ unsigned short Ws[128 * 72];
    const int tid = threadIdx.x;
    const int lane = tid & 63, wv = tid >> 6;
    const int wm = (wv & 1) * 64, wn = (wv >> 1) * 64;
    const int q = lane >> 4, ln = lane & 15;
    const size_t bm = (size_t)blockIdx.y * 128;
    const size_t bn = (size_t)blockIdx.x * 128;

    f32x4 acc[4][4];
#pragma unroll
    for (int i = 0; i < 4; i++)
#pragma unroll
        for (int j = 0; j < 4; j++) acc[i][j] = (f32x4){0.f, 0.f, 0.f, 0.f};

    for (int k0 = 0; k0 < K; k0 += 64) {
#pragma unroll
        for (int p = 0; p < 4; p++) {
            int flat = p * 2048 + tid * 8;
            int row = flat >> 6, col = flat & 63;
            *(uint4*)&As[row * 72 + col] =
                *(const uint4*)(A + (bm + row) * lda + k0 + col);
            *(uint4*)&Ws[row * 72 + col] =
                *(const uint4*)(W + (bn + row) * ldw + k0 + col);
        }
        __syncthreads();
#pragma unroll
        for (int kk = 0; kk < 64; kk += 32) {
            bf16x8 af[4], bfr4[4];
            union U8 { bf16x8 v; uint2 u[2]; };
#pragma unroll
            for (int i = 0; i < 4; i++) {
                U8 ua, ub;
                const unsigned short* pa = &As[(wm + i * 16 + ln) * 72 + kk + q * 8];
                ua.u[0] = *(const uint2*)(pa);
                ua.u[1] = *(const uint2*)(pa + 4);
                af[i] = ua.v;
                const unsigned short* pb = &Ws[(wn + i * 16 + ln) * 72 + kk + q * 8];
                ub.u[0] = *(const uint2*)(pb);
                ub.u[1] = *(const uint2*)(pb + 4);
                bfr4[i] = ub.v;
            }
#pragma unroll
            for (int i = 0; i < 4; i++)
#pragma unroll
                for (int j = 0; j < 4; j++)
                    acc[i][j] = __builtin_amdgcn_mfma_f32_16x16x32_bf16(
                        af[i], bfr4[j], acc[i][j], 0, 0, 0);
        }
        __syncthreads();
    }
#pragma unroll
    for (int j = 0; j < 4; j++) {
        int col = (int)bn + wn + j * 16 + ln;
        float bv = bias ? bias[col] : 0.f;
#pragma unroll
        for (int i = 0; i < 4; i++) {
            size_t row0 = bm + wm + i * 16 + q * 4;
#pragma unroll
            for (int r = 0; r < 4; r++) {
                float v = acc[i][j][r] + bv;
                if (gelu) v = 0.5f * v * (1.f + erff(v * 0.70710678118654752f));
                if (Cb) {
                    Cb[(row0 + r) * N + col] = bfr(v);
                } else {
                    float* p = Cf + (row0 + r) * N + col;
                    if (accum) v += *p;
                    *p = v;
                }
            }
        }
    }
}

// ---------------------------------------------------------------------------
// twiddle tables (bf16)
__global__ void dtab_kernel(unsigned short* __restrict__ T, int M, int L, int ldk) {
    int i = blockIdx.x * 256 + threadIdx.x;
    if (i >= 128 * ldk) return;
    int n = i / ldk, k = i - n * ldk;
    float val = 0.f;
    if (n < 2 * M && k < L) {
        int m = n >> 1;
        int r = (m * k) % L;
        float ang = -2.f * PI_F * (float)r / (float)L;
        val = (n & 1) ? sinf(ang) : cosf(ang);
    }
    T[i] = bfr(val);
}
__global__ void itab_kernel(unsigned short* __restrict__ T, int M, int L, int K) {
    int i = blockIdx.x * 256 + threadIdx.x;
    if (i >= L * K) return;
    int n = i / K, k = i - n * K;
    int m = k >> 1;
    float c = (m == 0) ? 1.f : 2.f;
    int r = (m * n) % L;
    float ang = 2.f * PI_F * (float)r / (float)L;
    float val = (k & 1) ? -c * sinf(ang) : c * cosf(ang);
    T[i] = bfr(val);
}

// ---------------------------------------------------------------------------
// dft MFMA v2 (bf16 input): P bf16 [B*L,512] -> XT[h][m][b][2e+p] bf16
__global__ __launch_bounds__(256) void dft_mfma2(
    const unsigned short* __restrict__ P, const unsigned short* __restrict__ Tdb,
    unsigned short* __restrict__ XT, int L, int ldk, int M) {
    __shared__ unsigned short tile[128 * 130];
    const int tid = threadIdx.x;
    const int lane = tid & 63, wv = tid >> 6;
    const int wm = (wv & 1) * 64, wn = (wv >> 1) * 64;
    const int q = lane >> 4, ln = lane & 15;
    const int bm = blockIdx.y;
    const int b = bm >> 2, c0 = (bm & 3) * 128;
    const int h0 = c0 >> 6;
    const unsigned short* Pb = P + (size_t)b * L * 512;

    f32x4 acc[4][4];
#pragma unroll
    for (int i = 0; i < 4; i++)
#pragma unroll
        for (int j = 0; j < 4; j++) acc[i][j] = (f32x4){0.f, 0.f, 0.f, 0.f};

    for (int k0 = 0; k0 < L; k0 += 32) {
        bf16x8 af[4], bf[4];
        union FR { bf16x8 v; unsigned short s[8]; };
#pragma unroll
        for (int i = 0; i < 4; i++) {
            int c = c0 + wm + i * 16 + ln;
            FR fr;
#pragma unroll
            for (int t = 0; t < 8; t++) {
                int l = k0 + q * 8 + t;
                fr.s[t] = (l < L) ? Pb[(size_t)l * 512 + c] : (unsigned short)0;
            }
            af[i] = fr.v;
        }
#pragma unroll
        for (int j = 0; j < 4; j++) {
            int n = wn + j * 16 + ln;
            bf[j] = *(const bf16x8*)(Tdb + (size_t)n * ldk + k0 + q * 8);
        }
#pragma unroll
        for (int i = 0; i < 4; i++)
#pragma unroll
            for (int j = 0; j < 4; j++)
                acc[i][j] = __builtin_amdgcn_mfma_f32_16x16x32_bf16(
                    af[i], bf[j], acc[i][j], 0, 0, 0);
    }
#pragma unroll
    for (int j = 0; j < 4; j++) {
        int col = wn + j * 16 + ln;
#pragma unroll
        for (int i = 0; i < 4; i++) {
            int r0 = wm + i * 16 + q * 4;
#pragma unroll
            for (int r = 0; r < 4; r++)
                tile[(r0 + r) * 130 + col] = bfr(acc[i][j][r]);
        }
    }
    __syncthreads();
    unsigned* XTu = (unsigned*)XT;
    for (int idx = tid; idx < 2 * M * 64; idx += 256) {
        int chunk = idx >> 6, e = idx & 63;
        int h2 = chunk / M, m = chunk - h2 * M;
        unsigned v = *(const unsigned*)&tile[(h2 * 64 + e) * 130 + 2 * m];
        XTu[((size_t)((h0 + h2) * M + m) * 128 + b) * 64 + e] = v;
    }
}

// ---------------------------------------------------------------------------
// wtrans3: w[h][e][o][m][2] fp32 -> WB[(h*M+m)][n=2o+q][k=2e+p] bf16
__global__ __launch_bounds__(256) void wtrans3(
    const float* __restrict__ w, unsigned short* __restrict__ WB, int M) {
    __shared__ float Lre[16 * 289], Lim[16 * 289];
    const int h = blockIdx.y;
    const int ot = blockIdx.x >> 1, et = blockIdx.x & 1;
    const int o0 = ot * 8, e0 = et * 32;
    const int tid = threadIdx.x;
    unsigned* WBu = (unsigned*)WB;
    for (int mc = 0; mc < M; mc += 16) {
        for (int idx = tid; idx < 4096; idx += 256) {
            int e = idx >> 7, o = (idx >> 4) & 7, mm = idx & 15;
            const float2 v = *(const float2*)(
                w + ((((size_t)h * 64 + e0 + e) * 64 + o0 + o) * M + mc + mm) * 2);
            Lre[mm * 289 + e * 9 + o] = v.x;
            Lim[mm * 289 + e * 9 + o] = v.y;
        }
        __syncthreads();
        for (int widx = tid; widx < 8192; widx += 256) {
            int mm = widx >> 9, no = (widx >> 5) & 15, e = widx & 31;
            int ol = no >> 1, qn = no & 1;
            float re = Lre[mm * 289 + e * 9 + ol];
            float im = Lim[mm * 289 + e * 9 + ol];
            unsigned v = qn ? pack2(im, re) : pack2(re, -im);
            WBu[((size_t)(h * M + mc + mm) * 128 + 2 * (o0 + ol) + qn) * 64 + e0 + e] = v;
        }
        __syncthreads();
    }
}

// ---------------------------------------------------------------------------
// mix_v2: per (h,m): Y'[b][n] = sum_k XT[hm][b][k]*WB[hm][n][k], b128 loads
__global__ __launch_bounds__(256) void mix_v2(
    const unsigned short* __restrict__ XT, const unsigned short* __restrict__ WB,
    unsigned short* __restrict__ Yp, int M) {
    __shared__ unsigned short tile[128 * 130];
    const int m = blockIdx.x, h = blockIdx.y;
    const int tid = threadIdx.x;
    const int lane = tid & 63, wv = tid >> 6;
    const int wm = (wv & 1) * 64, wn = (wv >> 1) * 64;
    const int q = lane >> 4, ln = lane & 15;
    const size_t hm = (size_t)h * M + m;
    const unsigned short* Ab = XT + hm * 16384;
    const unsigned short* Bb = WB + hm * 16384;

    f32x4 acc[4][4];
#pragma unroll
    for (int i = 0; i < 4; i++)
#pragma unroll
        for (int j = 0; j < 4; j++) acc[i][j] = (f32x4){0.f, 0.f, 0.f, 0.f};

#pragma unroll
    for (int k0 = 0; k0 < 128; k0 += 32) {
        bf16x8 af[4], bf[4];
#pragma unroll
        for (int i = 0; i < 4; i++)
            af[i] = *(const bf16x8*)(Ab + (size_t)(wm + i * 16 + ln) * 128 + k0 + q * 8);
#pragma unroll
        for (int j = 0; j < 4; j++)
            bf[j] = *(const bf16x8*)(Bb + (size_t)(wn + j * 16 + ln) * 128 + k0 + q * 8);
#pragma unroll
        for (int i = 0; i < 4; i++)
#pragma unroll
            for (int j = 0; j < 4; j++)
                acc[i][j] = __builtin_amdgcn_mfma_f32_16x16x32_bf16(
                    af[i], bf[j], acc[i][j], 0, 0, 0);
    }
#pragma unroll
    for (int j = 0; j < 4; j++) {
        int col = wn + j * 16 + ln;
#pragma unroll
        for (int i = 0; i < 4; i++) {
            int r0 = wm + i * 16 + q * 4;
#pragma unroll
            for (int r = 0; r < 4; r++)
                tile[(r0 + r) * 130 + col] = bfr(acc[i][j][r]);
        }
    }
    __syncthreads();
    unsigned* Yu = (unsigned*)Yp;
    for (int idx = tid; idx < 128 * 64; idx += 256) {
        int b = idx >> 6, dw = idx & 63;
        unsigned v = *(const unsigned*)&tile[b * 130 + 2 * dw];
        Yu[(hm * 128 + b) * 64 + dw] = v;
    }
}

// ---------------------------------------------------------------------------
// idft_v2: Out bf16 [(b,h,o)*L + l] = bf16(s * sum_k Y'[..][k]*Ti[l][k])
__global__ __launch_bounds__(256) void idft_v2(
    const unsigned short* __restrict__ Yp, const unsigned short* __restrict__ Tib,
    unsigned short* __restrict__ Out, int L, int K, int M, float s) {
    __shared__ unsigned short sh[2 * 64 * 132];
    const int tid = threadIdx.x;
    const int lane = tid & 63, wv = tid >> 6;
    const int wm = (wv & 1) * 64, wn = (wv >> 1) * 64;
    const int q = lane >> 4, ln = lane & 15;
    const int bm = blockIdx.y;
    const int b = bm >> 2, h0 = (bm & 3) * 2;
    const int bn = blockIdx.x * 128;

    const unsigned* Yu = (const unsigned*)Yp;
    for (int idx = tid; idx < 2 * M * 64; idx += 256) {
        int chunk = idx >> 6, dw = idx & 63;
        int h2 = chunk / M, m = chunk - h2 * M;
        unsigned v = Yu[((size_t)((h0 + h2) * M + m) * 128 + b) * 64 + dw];
        *(unsigned*)&sh[chunk * 132 + 2 * dw] = v;
    }
    __syncthreads();

    f32x4 acc[4][4];
#pragma unroll
    for (int i = 0; i < 4; i++)
#pragma unroll
        for (int j = 0; j < 4; j++) acc[i][j] = (f32x4){0.f, 0.f, 0.f, 0.f};

    for (int k0 = 0; k0 < K; k0 += 32) {
        bf16x8 af[4], bf[4];
        union FR { bf16x8 v; unsigned u[4]; };
#pragma unroll
        for (int i = 0; i < 4; i++) {
            int lr = wm + i * 16 + ln;
            int h2 = lr >> 6, o = lr & 63;
            FR fr;
#pragma unroll
            for (int jj = 0; jj < 4; jj++) {
                int m = (k0 >> 1) + q * 4 + jj;
                fr.u[jj] = *(const unsigned*)&sh[(h2 * M + m) * 132 + 2 * o];
            }
            af[i] = fr.v;
        }
#pragma unroll
        for (int j = 0; j < 4; j++) {
            int n = bn + wn + j * 16 + ln;
            if (n < L) bf[j] = *(const bf16x8*)(Tib + (size_t)n * K + k0 + q * 8);
            else bf[j] = (bf16x8){0, 0, 0, 0, 0, 0, 0, 0};
        }
#pragma unroll
        for (int i = 0; i < 4; i++)
#pragma unroll
            for (int j = 0; j < 4; j++)
                acc[i][j] = __builtin_amdgcn_mfma_f32_16x16x32_bf16(
                    af[i], bf[j], acc[i][j], 0, 0, 0);
    }
#pragma unroll
    for (int j = 0; j < 4; j++) {
        int col = bn + wn + j * 16 + ln;
        if (col >= L) continue;
#pragma unroll
        for (int i = 0; i < 4; i++) {
            int row0 = bm * 128 + wm + i * 16 + q * 4;
#pragma unroll
            for (int r = 0; r < 4; r++)
                Out[(size_t)(row0 + r) * L + col] = bfr(acc[i][j][r] * s);
        }
    }
}

// ---------------------------------------------------------------------------
// xqk2: G (packed bf16 pairs) = ctanh(Q^T K) from XT chunks
__global__ __launch_bounds__(256) void xqk2(
    const unsigned short* __restrict__ XTQ, const unsigned short* __restrict__ XTK,
    unsigned* __restrict__ G) {
    __shared__ float Qre[64 * 65], Qim[64 * 65];
    __shared__ float Kre[64 * 49], Kim[64 * 49];
    int b = blockIdx.x, h = blockIdx.y;
    const unsigned* Qu = (const unsigned*)XTQ;
    const unsigned* Ku = (const unsigned*)XTK;
    for (int idx = threadIdx.x; idx < 64 * 64; idx += 256) {
        int x = idx >> 6, e = idx & 63;
        unsigned v = Qu[((size_t)(h * 64 + x) * 128 + b) * 64 + e];
        Qre[e * 65 + x] = bf2f((unsigned short)(v & 0xFFFF));
        Qim[e * 65 + x] = bf2f((unsigned short)(v >> 16));
    }
    for (int idx = threadIdx.x; idx < 48 * 64; idx += 256) {
        int y = idx >> 6, e = idx & 63;
        unsigned v = Ku[((size_t)(h * 48 + y) * 128 + b) * 64 + e];
        Kre[e * 49 + y] = bf2f((unsigned short)(v & 0xFFFF));
        Kim[e * 49 + y] = bf2f((unsigned short)(v >> 16));
    }
    __syncthreads();
    for (int i = threadIdx.x; i < 64 * 48; i += 256) {
        int x = i / 48, y = i - x * 48;
        float re = 0.f, im = 0.f;
#pragma unroll 8
        for (int e = 0; e < 64; e++) {
            float qr = Qre[e * 65 + x], qi = Qim[e * 65 + x];
            float kr = Kre[e * 49 + y], ki = Kim[e * 49 + y];
            re += qr * kr - qi * ki;
            im += qr * ki + qi * kr;
        }
        float a2 = 2.f * re, b2 = 2.f * im;
        a2 = fminf(fmaxf(a2, -80.f), 80.f);
        float denom = coshf(a2) + cosf(b2);
        G[((size_t)b * 8 + h) * 3072 + i] = pack2(sinhf(a2) / denom, sinf(b2) / denom);
    }
}

// xqkv2: VT[h][x][b][2e+p] bf16 = sum_y G[x,y] * K[e,y]
__global__ __launch_bounds__(256) void xqkv2(
    const unsigned* __restrict__ G, const unsigned short* __restrict__ XTK,
    unsigned short* __restrict__ VT) {
    __shared__ float Gre[64 * 49], Gim[64 * 49];
    __shared__ float Kre[64 * 49], Kim[64 * 49];
    int b = blockIdx.x, h = blockIdx.y;
    const unsigned* Ku = (const unsigned*)XTK;
    const unsigned* gs = G + ((size_t)b * 8 + h) * 3072;
    for (int idx = threadIdx.x; idx < 64 * 48; idx += 256) {
        int x = idx / 48, y = idx - x * 48;
        unsigned g = gs[idx];
        Gre[x * 49 + y] = bf2f((unsigned short)(g & 0xFFFF));
        Gim[x * 49 + y] = bf2f((unsigned short)(g >> 16));
    }
    for (int idx = threadIdx.x; idx < 48 * 64; idx += 256) {
        int y = idx >> 6, e = idx & 63;
        unsigned v = Ku[((size_t)(h * 48 + y) * 128 + b) * 64 + e];
        Kre[e * 49 + y] = bf2f((unsigned short)(v & 0xFFFF));
        Kim[e * 49 + y] = bf2f((unsigned short)(v >> 16));
    }
    __syncthreads();
    unsigned* Vu = (unsigned*)VT;
    for (int idx = threadIdx.x; idx < 4096; idx += 256) {
        int x = idx >> 6, e = idx & 63;
        float re = 0.f, im = 0.f;
#pragma unroll 8
        for (int y = 0; y < 48; y++) {
            float gr = Gre[x * 49 + y], gi = Gim[x * 49 + y];
            float kr = Kre[e * 49 + y], ki = Kim[e * 49 + y];
            re += gr * kr - gi * ki;
            im += gr * ki + gi * kr;
        }
        Vu[((size_t)(h * 64 + x) * 128 + b) * 64 + e] = pack2(re, im);
    }
}

// ---------------------------------------------------------------------------
// series_decomp (+ optional bf16 copy of seasonal out)
__global__ void decomp_kernel(const float* __restrict__ P, const float* __restrict__ Q,
                              float* __restrict__ SO, unsigned short* __restrict__ SOb,
                              float* __restrict__ TS, int L, int tmode) {
    int b = blockIdx.x, d0 = blockIdx.y * 64;
    __shared__ float s[144 * 64];
    for (int i = threadIdx.x; i < L * 64; i += 256) {
        int l = i >> 6, d = i & 63;
        size_t idx = ((size_t)b * L + l) * 512 + d0 + d;
        float v = P[idx];
        if (Q) v += Q[idx];
        s[i] = v;
    }
    __syncthreads();
    for (int i = threadIdx.x; i < L * 64; i += 256) {
        int l = i >> 6, d = i & 63;
        float sum = 0.f;
#pragma unroll
        for (int j = -12; j <= 12; j++) sum += s[iclamp(l + j, 0, L - 1) * 64 + d];
        float ma = sum * (1.0f / 25.0f);
        size_t idx = ((size_t)b * L + l) * 512 + d0 + d;
        float so = s[i] - ma;
        SO[idx] = so;
        if (SOb) SOb[idx] = bfr(so);
        if (tmode == 1) TS[idx] = ma;
        else if (tmode == 2) TS[idx] += ma;
    }
}

// ---------------------------------------------------------------------------
__global__ __launch_bounds__(256) void ln_rows_kernel(const float* __restrict__ in,
                                                      const float* __restrict__ w,
                                                      const float* __restrict__ bvec,
                                                      float* __restrict__ out) {
    size_t row = blockIdx.x;
    const float* p = in + row * 512;
    int t = threadIdx.x;
    float v0 = p[t], v1 = p[t + 256];
    float s = v0 + v1, s2 = v0 * v0 + v1 * v1;
    for (int o = 32; o > 0; o >>= 1) {
        s += __shfl_xor(s, o, 64);
        s2 += __shfl_xor(s2, o, 64);
    }
    __shared__ float rs[4], rs2[4];
    int wid = t >> 6;
    if ((t & 63) == 0) { rs[wid] = s; rs2[wid] = s2; }
    __syncthreads();
    s = rs[0] + rs[1] + rs[2] + rs[3];
    s2 = rs2[0] + rs2[1] + rs2[2] + rs2[3];
    float mu = s * (1.0f / 512.0f);
    float var = s2 * (1.0f / 512.0f) - mu * mu;
    float r = rsqrtf(var + 1e-5f);
    out[row * 512 + t] = (v0 - mu) * r * w[t] + bvec[t];
    out[row * 512 + t + 256] = (v1 - mu) * r * w[t + 256] + bvec[t + 256];
}

// timesub (+ optional bf16 copy)
__global__ void timesub_kernel(float* __restrict__ X, unsigned short* __restrict__ Xb,
                               int L) {
    int b = blockIdx.x, d0 = blockIdx.y * 64;
    __shared__ float tile[144 * 64];
    __shared__ float mean[64];
    for (int i = threadIdx.x; i < L * 64; i += 256) {
        int l = i >> 6, d = i & 63;
        tile[i] = X[((size_t)b * L + l) * 512 + d0 + d];
    }
    __syncthreads();
    if (threadIdx.x < 64) {
        float sm = 0.f;
        for (int l = 0; l < L; l++) sm += tile[l * 64 + threadIdx.x];
        mean[threadIdx.x] = sm / (float)L;
    }
    __syncthreads();
    for (int i = threadIdx.x; i < L * 64; i += 256) {
        int l = i >> 6, d = i & 63;
        size_t idx = ((size_t)b * L + l) * 512 + d0 + d;
        float v = tile[i] - mean[d];
        X[idx] = v;
        if (Xb) Xb[idx] = bfr(v);
    }
}

// ---------------------------------------------------------------------------
__global__ __launch_bounds__(256) void final_v2(
    const float* __restrict__ XL, const float* __restrict__ TS,
    const float* __restrict__ TI, const float* __restrict__ trend_w,
    const float* __restrict__ proj_w, const float* __restrict__ proj_b,
    float* __restrict__ out) {
    int blk = blockIdx.x;
    int b = blk / 96, lo = blk - b * 96;
    int l = lo + 48;
    int lm = l - 1;
    int lp = (l == 143) ? 0 : l + 1;
    const float* ts = TS + (size_t)b * 144 * 512;
    const float* r0 = ts + (size_t)lm * 512;
    const float* r1 = ts + (size_t)l * 512;
    const float* r2 = ts + (size_t)lp * 512;
    const float* xl = XL + ((size_t)b * 144 + l) * 512;
    int t = threadIdx.x;
    float p[7];
#pragma unroll
    for (int c = 0; c < 7; c++) p[c] = 0.f;
#pragma unroll
    for (int dd = 0; dd < 2; dd++) {
        int d = t + dd * 256;
        float a0 = r0[d], a1 = r1[d], a2 = r2[d], x = xl[d];
#pragma unroll
        for (int c = 0; c < 7; c++) {
            const float* tw = trend_w + ((size_t)c * 512 + d) * 3;
            float v = a0 * tw[0] + a1 * tw[1] + a2 * tw[2];
            v = fmaf(x, proj_w[c * 512 + d], v);
            p[c] += v;
        }
    }
#pragma unroll
    for (int o = 32; o > 0; o >>= 1)
#pragma unroll
        for (int c = 0; c < 7; c++) p[c] += __shfl_xor(p[c], o, 64);
    __shared__ float red[4][7];
    int wid = t >> 6;
    if ((t & 63) == 0)
#pragma unroll
        for (int c = 0; c < 7; c++) red[wid][c] = p[c];
    __syncthreads();
    if (t < 7) {
        float v = red[0][t] + red[1][t] + red[2][t] + red[3][t]
                + TI[((size_t)b * 144 + l) * 7 + t] + proj_b[t];
        out[(size_t)blk * 7 + t] = v;
    }
}

// ---------------------------------------------------------------------------
static inline int cdiv(int a, int b) { return (a + b - 1) / b; }

extern "C" void kernel_launch(void* const* d_in, const int* in_sizes, int n_in,
                              void* d_out, int out_size, void* d_ws, size_t ws_size,
                              hipStream_t stream) {
    const float* x_enc      = (const float*)d_in[0];
    const float* x_mark_enc = (const float*)d_in[1];
    const float* x_mark_dec = (const float*)d_in[3];
    const float* enc_emb_conv_w = (const float*)d_in[4];
    const float* enc_emb_time_w = (const float*)d_in[5];
    const float* dec_emb_conv_w = (const float*)d_in[6];
    const float* dec_emb_time_w = (const float*)d_in[7];
    const float* enc_qw = (const float*)d_in[8];
    const float* enc_qb = (const float*)d_in[9];
    const float* enc_ow = (const float*)d_in[14];
    const float* enc_ob = (const float*)d_in[15];
    const float* enc_fw = (const float*)d_in[16];
    const float* enc_c1 = (const float*)d_in[17];
    const float* enc_c2 = (const float*)d_in[18];
    const float* enc_norm_w = (const float*)d_in[19];
    const float* enc_norm_b = (const float*)d_in[20];
    const float* ds_qw = (const float*)d_in[21];
    const float* ds_qb = (const float*)d_in[22];
    const float* ds_ow = (const float*)d_in[27];
    const float* ds_ob = (const float*)d_in[28];
    const float* ds_fw = (const float*)d_in[29];
    const float* dc_qw = (const float*)d_in[30];
    const float* dc_qb = (const float*)d_in[31];
    const float* dc_kw = (const float*)d_in[32];
    const float* dc_kb = (const float*)d_in[33];
    const float* dc_ow = (const float*)d_in[36];
    const float* dc_ob = (const float*)d_in[37];
    const float* dc_fw = (const float*)d_in[38];
    const float* dec_c1 = (const float*)d_in[39];
    const float* dec_c2 = (const float*)d_in[40];
    const float* dec_trend_w = (const float*)d_in[41];
    const float* dec_norm_w = (const float*)d_in[42];
    const float* dec_norm_b = (const float*)d_in[43];
    const float* proj_w = (const float*)d_in[44];
    const float* proj_b = (const float*)d_in[45];

    float* ws = (float*)d_ws;
    float* XD   = ws;                        // 9,437,184
    float* TS   = ws + 9437184;              // 9,437,184
    float* XE   = ws + 18874368;             // 6,291,456 (fout aliases XE+XEb)
    unsigned short* XEb = (unsigned short*)(ws + 25165824);  // 3,145,728 fl
    unsigned short* XDb = (unsigned short*)(ws + 28311552);  // 4,718,592 fl
    float* SI   = ws + 33030144;             // 129,024
    float* TI   = ws + 33159168;             // 129,024
    float* TAB  = ws + 33288192;             // 32,768
    unsigned short* WF = (unsigned short*)(ws + 33320960);   // 4,325,376 fl
    float* SC   = ws + 37646336;             // 16,121,856 fl scratch
    unsigned short* TdbE = (unsigned short*)(TAB);
    unsigned short* TdbD = (unsigned short*)(TAB + 6144);
    unsigned short* TibE = (unsigned short*)(TAB + 16384);
    unsigned short* TibD = (unsigned short*)(TAB + 20992);

    // bf16 weight arena offsets (elements)
    unsigned short* enc_qw_b = WF;                 // 524288 (2 layers)
    unsigned short* enc_ow_b = WF + 524288;        // 524288
    unsigned short* enc_c1_b = WF + 1048576;       // 2097152
    unsigned short* enc_c2_b = WF + 3145728;       // 2097152
    unsigned short* ds_qw_b  = WF + 5242880;       // 262144
    unsigned short* ds_ow_b  = WF + 5505024;
    unsigned short* dc_qw_b  = WF + 5767168;
    unsigned short* dc_kw_b  = WF + 6029312;
    unsigned short* dc_ow_b  = WF + 6291456;
    unsigned short* dec_c1_b = WF + 6553600;       // 1048576
    unsigned short* dec_c2_b = WF + 7602176;       // 1048576

    const size_t need_bytes = (size_t)53768192 * sizeof(float);
    if (ws_size < need_bytes) {
        zero_out_kernel<<<cdiv(out_size, 256), 256, 0, stream>>>((float*)d_out, out_size);
        return;
    }

    auto conv = [&](const float* s, unsigned short* d, int n) {
        f2b<<<cdiv(n / 4, 256), 256, 0, stream>>>(s, d, n);
    };
    auto gemm = [&](const unsigned short* A, const unsigned short* W, const float* bias,
                    float* Cf, unsigned short* Cb, int rows, int N, int K,
                    int lda, int ldw, int gelu, int accum) {
        dim3 g(N / 128, rows / 128);
        gemm_bb<<<g, 256, 0, stream>>>(A, W, bias, Cf, Cb, N, K, lda, ldw, gelu, accum);
    };

    // ---- weight conversion (per call; harness re-poisons ws)
    conv(enc_qw, enc_qw_b, 524288);
    conv(enc_ow, enc_ow_b, 524288);
    conv(enc_c1, enc_c1_b, 2097152);
    conv(enc_c2, enc_c2_b, 2097152);
    conv(ds_qw, ds_qw_b, 262144);
    conv(ds_ow, ds_ow_b, 262144);
    conv(dc_qw, dc_qw_b, 262144);
    conv(dc_kw, dc_kw_b, 262144);
    conv(dc_ow, dc_ow_b, 262144);
    conv(dec_c1, dec_c1_b, 1048576);
    conv(dec_c2, dec_c2_b, 1048576);

    // ---- twiddle tables
    dtab_kernel<<<cdiv(128 * 96, 256), 256, 0, stream>>>(TdbE, 48, 96, 96);
    dtab_kernel<<<cdiv(128 * 160, 256), 256, 0, stream>>>(TdbD, 64, 144, 160);
    itab_kernel<<<cdiv(96 * 96, 256), 256, 0, stream>>>(TibE, 48, 96, 96);
    itab_kernel<<<cdiv(144 * 128, 256), 256, 0, stream>>>(TibD, 64, 144, 128);

    // ---- preprocess + encoder embed
    preprocess_kernel<<<cdiv(128 * 144 * 7, 256), 256, 0, stream>>>(x_enc, SI, TI);
    embed_kernel<<<cdiv(128 * 96 * 512, 256), 256, 0, stream>>>(
        x_enc, x_mark_enc, enc_emb_conv_w, enc_emb_time_w, XE, XEb, 96);

    // ---- encoder layers (M=48)
    for (int l = 0; l < 2; l++) {
        const unsigned short* qwb = enc_qw_b + (size_t)l * 262144;
        const float* qb = enc_qb + (size_t)l * 512;
        const unsigned short* owb = enc_ow_b + (size_t)l * 262144;
        const float* ob = enc_ob + (size_t)l * 512;
        const float* fw = enc_fw + (size_t)l * 8 * 64 * 64 * 48 * 2;
        const unsigned short* c1b = enc_c1_b + (size_t)l * 1048576;
        const unsigned short* c2b = enc_c2_b + (size_t)l * 1048576;
        unsigned short* Pq = (unsigned short*)(SC);             // 3.15M fl
        unsigned short* XT = (unsigned short*)(SC + 3145728);
        unsigned short* WB = (unsigned short*)(SC + 6291456);
        unsigned short* Yp = (unsigned short*)(SC + 9437184);
        unsigned short* Tidb = (unsigned short*)(SC);           // Pq dead
        float* To = SC + 3145728;                               // XT/WB dead, 6.29M

        gemm(XEb, qwb, qb, nullptr, Pq, 12288, 512, 512, 512, 512, 0, 0);
        dft_mfma2<<<dim3(1, 512), 256, 0, stream>>>(Pq, TdbE, XT, 96, 96, 48);
        wtrans3<<<dim3(16, 8), 256, 0, stream>>>(fw, WB, 48);
        mix_v2<<<dim3(48, 8), 256, 0, stream>>>(XT, WB, Yp, 48);
        idft_v2<<<dim3(1, 512), 256, 0, stream>>>(Yp, TibE, Tidb, 96, 96, 48, 1.f / 96.f);
        gemm(Tidb, owb, ob, To, nullptr, 12288, 512, 512, 512, 512, 0, 0);
        decomp_kernel<<<dim3(128, 8), 256, 0, stream>>>(XE, To, XE, XEb, nullptr, 96, 0);
        // FFN: hid bf16 in SC (12.58M fl), fout fp32 -> TS
        unsigned short* hid = (unsigned short*)(SC);
        gemm(XEb, c1b, nullptr, nullptr, hid, 12288, 2048, 512, 512, 512, 1, 0);
        gemm(hid, c2b, nullptr, TS, nullptr, 12288, 512, 2048, 2048, 2048, 0, 0);
        decomp_kernel<<<dim3(128, 8), 256, 0, stream>>>(XE, TS, XE, XEb, nullptr, 96, 0);
    }
    ln_rows_kernel<<<12288, 256, 0, stream>>>(XE, enc_norm_w, enc_norm_b, XE);
    timesub_kernel<<<dim3(128, 8), 256, 0, stream>>>(XE, XEb, 96);  // enc_out + bf16

    // ---- decoder embed
    embed_kernel<<<cdiv(128 * 144 * 512, 256), 256, 0, stream>>>(
        SI, x_mark_dec, dec_emb_conv_w, dec_emb_time_w, XD, XDb, 144);

    // ---- decoder self fourier block (M=64)
    {
        unsigned short* Pq = (unsigned short*)(SC);             // 4.72M fl
        unsigned short* XT = (unsigned short*)(SC + 4718592);   // 4.19M
        unsigned short* WB = (unsigned short*)(SC + 8912896);   // 4.19M
        unsigned short* Yp = (unsigned short*)(SC);             // Pq dead
        unsigned short* Tidb = (unsigned short*)(SC + 9437184); // 4.72M (WB tail ok)
        float* To = SC;                                         // 9.44M (all dead)

        gemm(XDb, ds_qw_b, ds_qb, nullptr, Pq, 18432, 512, 512, 512, 512, 0, 0);
        dft_mfma2<<<dim3(1, 512), 256, 0, stream>>>(Pq, TdbD, XT, 144, 160, 64);
        wtrans3<<<dim3(16, 8), 256, 0, stream>>>(ds_fw, WB, 64);
        mix_v2<<<dim3(64, 8), 256, 0, stream>>>(XT, WB, Yp, 64);
        idft_v2<<<dim3(2, 512), 256, 0, stream>>>(Yp, TibD, Tidb, 144, 128, 64, 1.f / 144.f);
        gemm(Tidb, ds_ow_b, ds_ob, To, nullptr, 18432, 512, 512, 512, 512, 0, 0);
        decomp_kernel<<<dim3(128, 8), 256, 0, stream>>>(XD, To, XD, XDb, TS, 144, 1);
    }

    // ---- cross attention
    {
        unsigned short* Pq  = (unsigned short*)(SC);             // 4.72M fl
        unsigned short* XTQ = (unsigned short*)(SC + 4718592);   // 4.19M
        unsigned short* Pk  = (unsigned short*)(SC);             // 3.15M (Pq dead)
        unsigned short* XTK = (unsigned short*)(SC + 8912896);   // 3.15M
        unsigned* G         = (unsigned*)(SC);                   // 3.15M (Pk dead)
        unsigned short* VT  = (unsigned short*)(SC + 3145728);   // 4.19M (XTQ dead)
        unsigned short* WB  = (unsigned short*)(SC + 7340032);   // 4.19M
        unsigned short* Yp  = (unsigned short*)(SC + 11534336);  // 4.19M (XTK dead)
        unsigned short* Tidb = (unsigned short*)(SC);            // 4.72M (G/VT dead)
        float* To = SC + 4718592;                                // 9.44M (WB/Yp dead)

        gemm(XDb, dc_qw_b, dc_qb, nullptr, Pq, 18432, 512, 512, 512, 512, 0, 0);
        dft_mfma2<<<dim3(1, 512), 256, 0, stream>>>(Pq, TdbD, XTQ, 144, 160, 64);
        gemm(XEb, dc_kw_b, dc_kb, nullptr, Pk, 12288, 512, 512, 512, 512, 0, 0);
        dft_mfma2<<<dim3(1, 512), 256, 0, stream>>>(Pk, TdbE, XTK, 96, 96, 48);
        xqk2<<<dim3(128, 8), 256, 0, stream>>>(XTQ, XTK, G);
        xqkv2<<<dim3(128, 8), 256, 0, stream>>>(G, XTK, VT);
        wtrans3<<<dim3(16, 8), 256, 0, stream>>>(dc_fw, WB, 64);
        mix_v2<<<dim3(64, 8), 256, 0, stream>>>(VT, WB, Yp, 64);
        idft_v2<<<dim3(2, 512), 256, 0, stream>>>(Yp, TibD, Tidb, 144, 128, 64,
                                                  1.f / (144.f * 262144.f));
        gemm(Tidb, dc_ow_b, dc_ob, To, nullptr, 18432, 512, 512, 512, 512, 0, 0);
        decomp_kernel<<<dim3(128, 8), 256, 0, stream>>>(XD, To, XD, XDb, TS, 144, 2);
    }

    // ---- decoder FFN: 2 chunks of N=1024; hid bf16 in SC, fout aliases XE+XEb
    {
        unsigned short* hid = (unsigned short*)(SC);   // 9.44M fl per chunk
        float* fout = XE;                              // 9.44M (XE+XEb dead)
        for (int j0 = 0; j0 < 2048; j0 += 1024) {
            gemm(XDb, dec_c1_b + (size_t)j0 * 512, nullptr, nullptr, hid,
                 18432, 1024, 512, 512, 512, 1, 0);
            gemm(hid, dec_c2_b + j0, nullptr, fout, nullptr,
                 18432, 512, 1024, 1024, 2048, 0, j0 > 0);
        }
        decomp_kernel<<<dim3(128, 8), 256, 0, stream>>>(XD, fout, XD, nullptr, TS, 144, 2);
    }

    // ---- final norm + trend conv + projection
    ln_rows_kernel<<<18432, 256, 0, stream>>>(XD, dec_norm_w, dec_norm_b, XD);
    timesub_kernel<<<dim3(128, 8), 256, 0, stream>>>(XD, nullptr, 144);
    final_v2<<<12288, 256, 0, stream>>>(
        XD, TS, TI, dec_trend_w, proj_w, proj_b, (float*)d_out);
}

// Round 8
// 1716.733 us; speedup vs baseline: 4.0974x; 1.0779x over previous
//
#include <hip/hip_runtime.h>
#include <hip/hip_bf16.h>
#include <math.h>

// Model_45904610459674: FEDformer-style forecaster.
// Round 8: gemm_bb staging via __builtin_amdgcn_global_load_lds (16B DMA,
// no VGPR round-trip) with XOR-swizzled LDS chunks (c_phys = c_log ^ (row&7),
// permuted on the *global* side so DMA lane layout stays contiguous).
// Fragment reads: bank start 4*(c_log^(ln&7)) -> uniform 2-way = free.
// Everything else identical to R7 (passing, absmax 7.8e-3).
// Workspace: 53,768,192 floats = 215.07 MB (same guard).

#define PI_F 3.14159265358979323846f

typedef short bf16x8 __attribute__((ext_vector_type(8)));
typedef float f32x4 __attribute__((ext_vector_type(4)));

static __device__ __forceinline__ int iclamp(int v, int lo, int hi) {
    return v < lo ? lo : (v > hi ? hi : v);
}
static __device__ __forceinline__ unsigned pack2(float x, float y) {
    unsigned xu = __float_as_uint(x) + 0x8000u;
    unsigned yu = __float_as_uint(y) + 0x8000u;
    return (xu >> 16) | (yu & 0xFFFF0000u);
}
static __device__ __forceinline__ unsigned short bfr(float x) {
    return (unsigned short)((__float_as_uint(x) + 0x8000u) >> 16);
}
static __device__ __forceinline__ float bf2f(unsigned short s) {
    return __uint_as_float((unsigned)s << 16);
}

__global__ void zero_out_kernel(float* __restrict__ out, int n) {
    int i = blockIdx.x * 256 + threadIdx.x;
    if (i < n) out[i] = 0.f;
}

// f2b: fp32 -> bf16, 4 elems/thread
__global__ void f2b(const float* __restrict__ s, unsigned short* __restrict__ d, int n) {
    int i = (blockIdx.x * 256 + threadIdx.x) * 4;
    if (i >= n) return;
    const float4 v = *(const float4*)(s + i);
    *(uint2*)(d + i) = make_uint2(pack2(v.x, v.y), pack2(v.z, v.w));
}

// ---------------------------------------------------------------------------
__global__ void preprocess_kernel(const float* __restrict__ xe,
                                  float* __restrict__ SI, float* __restrict__ TI) {
    int idx = blockIdx.x * 256 + threadIdx.x;
    if (idx >= 128 * 144 * 7) return;
    int c = idx % 7;
    int l = (idx / 7) % 144;
    int b = idx / (7 * 144);
    const float* xb = xe + (size_t)b * 96 * 7;
    if (l < 48) {
        int p = 48 + l;
        float sum = 0.f;
        for (int j = -12; j <= 12; j++) sum += xb[iclamp(p + j, 0, 95) * 7 + c];
        float ma = sum * (1.0f / 25.0f);
        SI[idx] = xb[p * 7 + c] - ma;
        TI[idx] = ma;
    } else {
        SI[idx] = 0.f;
        float m = 0.f;
        for (int l2 = 0; l2 < 96; l2++) m += xb[l2 * 7 + c];
        TI[idx] = m * (1.0f / 96.0f);
    }
}

// ---------------------------------------------------------------------------
// embed + bf16 copy
__global__ void embed_kernel(const float* __restrict__ x, const float* __restrict__ mark,
                             const float* __restrict__ cw, const float* __restrict__ tw,
                             float* __restrict__ out, unsigned short* __restrict__ outb,
                             int L) {
    size_t idx = (size_t)blockIdx.x * 256 + threadIdx.x;
    if (idx >= (size_t)128 * L * 512) return;
    int o = idx & 511;
    int l = (int)((idx >> 9) % L);
    int b = (int)(idx / ((size_t)512 * L));
    int lm = (l == 0) ? L - 1 : l - 1;
    int lp = (l == L - 1) ? 0 : l + 1;
    const float* x0 = x + (size_t)b * L * 7;
    float v = 0.f;
#pragma unroll
    for (int c = 0; c < 7; c++) {
        const float* w = cw + (o * 7 + c) * 3;
        v += x0[lm * 7 + c] * w[0] + x0[l * 7 + c] * w[1] + x0[lp * 7 + c] * w[2];
    }
    const float* mk = mark + ((size_t)b * L + l) * 4;
#pragma unroll
    for (int f = 0; f < 4; f++) v += mk[f] * tw[o * 4 + f];
    out[idx] = v;
    outb[idx] = bfr(v);
}

// ---------------------------------------------------------------------------
// gemm_bb: A,W bf16. C = [accum?C:0] + A@W.T (+bias)(+GELU).
// Staging: global_load_lds 16B DMA, XOR-swizzled chunks. Out fp32 or bf16.
__global__ __launch_bounds__(256, 4) void gemm_bb(
    const unsigned short* __restrict__ A, const unsigned short* __restrict__ W,
    const float* __restrict__ bias, float* __restrict__ Cf,
    unsigned short* __restrict__ Cb,
    int N, int K, int lda, int ldw, int gelu, int accum) {
    __shared__ unsigned short As[128 * 64];
    __shared__ unsigned short Ws[128 * 64];
    const int tid = threadIdx.x;
    const int lane = tid & 63, wv = tid >> 6;
    const int wm = (wv & 1) * 64, wn = (wv >> 1) * 64;
    const int q = lane >> 4, ln = lane & 15;
    const size_t bm = (size_t)blockIdx.y * 128;
    const size_t bn = (size_t)blockIdx.x * 128;

    // staging map: flat chunk idx = (wv*4+t)*64 + lane; row = idx>>3,
    // c_phys = idx&7, c_log = c_phys ^ (row&7); lane fetches global chunk
    // c_log so DMA (base + lane*16B) lands it at c_phys. Same 128B segment.
    f32x4 acc[4][4];
#pragma unroll
    for (int i = 0; i < 4; i++)
#pragma unroll
        for (int j = 0; j < 4; j++) acc[i][j] = (f32x4){0.f, 0.f, 0.f, 0.f};

    for (int k0 = 0; k0 < K; k0 += 64) {
#pragma unroll
        for (int t = 0; t < 4; t++) {
            int idx = (wv * 4 + t) * 64 + lane;
            int row = idx >> 3, cp = idx & 7;
            int cl = cp ^ (row & 7);
            __builtin_amdgcn_global_load_lds(
                (const __attribute__((address_space(1))) void*)(A + (bm + row) * lda + k0 + cl * 8),
                (__attribute__((address_space(3))) void*)(As + (size_t)(wv * 4 + t) * 512),
                16, 0, 0);
            __builtin_amdgcn_global_load_lds(
                (const __attribute__((address_space(1))) void*)(W + (bn + row) * ldw + k0 + cl * 8),
                (__attribute__((address_space(3))) void*)(Ws + (size_t)(wv * 4 + t) * 512),
                16, 0, 0);
        }
        __syncthreads();
#pragma unroll
        for (int kk = 0; kk < 64; kk += 32) {
            bf16x8 af[4], bfr4[4];
            const int cq = (kk >> 3) + q;   // logical chunk index
#pragma unroll
            for (int i = 0; i < 4; i++) {
                int r = wm + i * 16 + ln;
                af[i] = *(const bf16x8*)(As + r * 64 + ((cq ^ (r & 7)) * 8));
                int rw = wn + i * 16 + ln;
                bfr4[i] = *(const bf16x8*)(Ws + rw * 64 + ((cq ^ (rw & 7)) * 8));
            }
#pragma unroll
            for (int i = 0; i < 4; i++)
#pragma unroll
                for (int j = 0; j < 4; j++)
                    acc[i][j] = __builtin_amdgcn_mfma_f32_16x16x32_bf16(
                        af[i], bfr4[j], acc[i][j], 0, 0, 0);
        }
        __syncthreads();
    }
#pragma unroll
    for (int j = 0; j < 4; j++) {
        int col = (int)bn + wn + j * 16 + ln;
        float bv = bias ? bias[col] : 0.f;
#pragma unroll
        for (int i = 0; i < 4; i++) {
            size_t row0 = bm + wm + i * 16 + q * 4;
#pragma unroll
            for (int r = 0; r < 4; r++) {
                float v = acc[i][j][r] + bv;
                if (gelu) v = 0.5f * v * (1.f + erff(v * 0.70710678118654752f));
                if (Cb) {
                    Cb[(row0 + r) * N + col] = bfr(v);
                } else {
                    float* p = Cf + (row0 + r) * N + col;
                    if (accum) v += *p;
                    *p = v;
                }
            }
        }
    }
}

// ---------------------------------------------------------------------------
// twiddle tables (bf16)
__global__ void dtab_kernel(unsigned short* __restrict__ T, int M, int L, int ldk) {
    int i = blockIdx.x * 256 + threadIdx.x;
    if (i >= 128 * ldk) return;
    int n = i / ldk, k = i - n * ldk;
    float val = 0.f;
    if (n < 2 * M && k < L) {
        int m = n >> 1;
        int r = (m * k) % L;
        float ang = -2.f * PI_F * (float)r / (float)L;
        val = (n & 1) ? sinf(ang) : cosf(ang);
    }
    T[i] = bfr(val);
}
__global__ void itab_kernel(unsigned short* __restrict__ T, int M, int L, int K) {
    int i = blockIdx.x * 256 + threadIdx.x;
    if (i >= L * K) return;
    int n = i / K, k = i - n * K;
    int m = k >> 1;
    float c = (m == 0) ? 1.f : 2.f;
    int r = (m * n) % L;
    float ang = 2.f * PI_F * (float)r / (float)L;
    float val = (k & 1) ? -c * sinf(ang) : c * cosf(ang);
    T[i] = bfr(val);
}

// ---------------------------------------------------------------------------
// dft MFMA v2 (bf16 input): P bf16 [B*L,512] -> XT[h][m][b][2e+p] bf16
__global__ __launch_bounds__(256) void dft_mfma2(
    const unsigned short* __restrict__ P, const unsigned short* __restrict__ Tdb,
    unsigned short* __restrict__ XT, int L, int ldk, int M) {
    __shared__ unsigned short tile[128 * 130];
    const int tid = threadIdx.x;
    const int lane = tid & 63, wv = tid >> 6;
    const int wm = (wv & 1) * 64, wn = (wv >> 1) * 64;
    const int q = lane >> 4, ln = lane & 15;
    const int bm = blockIdx.y;
    const int b = bm >> 2, c0 = (bm & 3) * 128;
    const int h0 = c0 >> 6;
    const unsigned short* Pb = P + (size_t)b * L * 512;

    f32x4 acc[4][4];
#pragma unroll
    for (int i = 0; i < 4; i++)
#pragma unroll
        for (int j = 0; j < 4; j++) acc[i][j] = (f32x4){0.f, 0.f, 0.f, 0.f};

    for (int k0 = 0; k0 < L; k0 += 32) {
        bf16x8 af[4], bf[4];
        union FR { bf16x8 v; unsigned short s[8]; };
#pragma unroll
        for (int i = 0; i < 4; i++) {
            int c = c0 + wm + i * 16 + ln;
            FR fr;
#pragma unroll
            for (int t = 0; t < 8; t++) {
                int l = k0 + q * 8 + t;
                fr.s[t] = (l < L) ? Pb[(size_t)l * 512 + c] : (unsigned short)0;
            }
            af[i] = fr.v;
        }
#pragma unroll
        for (int j = 0; j < 4; j++) {
            int n = wn + j * 16 + ln;
            bf[j] = *(const bf16x8*)(Tdb + (size_t)n * ldk + k0 + q * 8);
        }
#pragma unroll
        for (int i = 0; i < 4; i++)
#pragma unroll
            for (int j = 0; j < 4; j++)
                acc[i][j] = __builtin_amdgcn_mfma_f32_16x16x32_bf16(
                    af[i], bf[j], acc[i][j], 0, 0, 0);
    }
#pragma unroll
    for (int j = 0; j < 4; j++) {
        int col = wn + j * 16 + ln;
#pragma unroll
        for (int i = 0; i < 4; i++) {
            int r0 = wm + i * 16 + q * 4;
#pragma unroll
            for (int r = 0; r < 4; r++)
                tile[(r0 + r) * 130 + col] = bfr(acc[i][j][r]);
        }
    }
    __syncthreads();
    unsigned* XTu = (unsigned*)XT;
    for (int idx = tid; idx < 2 * M * 64; idx += 256) {
        int chunk = idx >> 6, e = idx & 63;
        int h2 = chunk / M, m = chunk - h2 * M;
        unsigned v = *(const unsigned*)&tile[(h2 * 64 + e) * 130 + 2 * m];
        XTu[((size_t)((h0 + h2) * M + m) * 128 + b) * 64 + e] = v;
    }
}

// ---------------------------------------------------------------------------
// wtrans3: w[h][e][o][m][2] fp32 -> WB[(h*M+m)][n=2o+q][k=2e+p] bf16
__global__ __launch_bounds__(256) void wtrans3(
    const float* __restrict__ w, unsigned short* __restrict__ WB, int M) {
    __shared__ float Lre[16 * 289], Lim[16 * 289];
    const int h = blockIdx.y;
    const int ot = blockIdx.x >> 1, et = blockIdx.x & 1;
    const int o0 = ot * 8, e0 = et * 32;
    const int tid = threadIdx.x;
    unsigned* WBu = (unsigned*)WB;
    for (int mc = 0; mc < M; mc += 16) {
        for (int idx = tid; idx < 4096; idx += 256) {
            int e = idx >> 7, o = (idx >> 4) & 7, mm = idx & 15;
            const float2 v = *(const float2*)(
                w + ((((size_t)h * 64 + e0 + e) * 64 + o0 + o) * M + mc + mm) * 2);
            Lre[mm * 289 + e * 9 + o] = v.x;
            Lim[mm * 289 + e * 9 + o] = v.y;
        }
        __syncthreads();
        for (int widx = tid; widx < 8192; widx += 256) {
            int mm = widx >> 9, no = (widx >> 5) & 15, e = widx & 31;
            int ol = no >> 1, qn = no & 1;
            float re = Lre[mm * 289 + e * 9 + ol];
            float im = Lim[mm * 289 + e * 9 + ol];
            unsigned v = qn ? pack2(im, re) : pack2(re, -im);
            WBu[((size_t)(h * M + mc + mm) * 128 + 2 * (o0 + ol) + qn) * 64 + e0 + e] = v;
        }
        __syncthreads();
    }
}

// ---------------------------------------------------------------------------
// mix_v2: per (h,m): Y'[b][n] = sum_k XT[hm][b][k]*WB[hm][n][k], b128 loads
__global__ __launch_bounds__(256) void mix_v2(
    const unsigned short* __restrict__ XT, const unsigned short* __restrict__ WB,
    unsigned short* __restrict__ Yp, int M) {
    __shared__ unsigned short tile[128 * 130];
    const int m = blockIdx.x, h = blockIdx.y;
    const int tid = threadIdx.x;
    const int lane = tid & 63, wv = tid >> 6;
    const int wm = (wv & 1) * 64, wn = (wv >> 1) * 64;
    const int q = lane >> 4, ln = lane & 15;
    const size_t hm = (size_t)h * M + m;
    const unsigned short* Ab = XT + hm * 16384;
    const unsigned short* Bb = WB + hm * 16384;

    f32x4 acc[4][4];
#pragma unroll
    for (int i = 0; i < 4; i++)
#pragma unroll
        for (int j = 0; j < 4; j++) acc[i][j] = (f32x4){0.f, 0.f, 0.f, 0.f};

#pragma unroll
    for (int k0 = 0; k0 < 128; k0 += 32) {
        bf16x8 af[4], bf[4];
#pragma unroll
        for (int i = 0; i < 4; i++)
            af[i] = *(const bf16x8*)(Ab + (size_t)(wm + i * 16 + ln) * 128 + k0 + q * 8);
#pragma unroll
        for (int j = 0; j < 4; j++)
            bf[j] = *(const bf16x8*)(Bb + (size_t)(wn + j * 16 + ln) * 128 + k0 + q * 8);
#pragma unroll
        for (int i = 0; i < 4; i++)
#pragma unroll
            for (int j = 0; j < 4; j++)
                acc[i][j] = __builtin_amdgcn_mfma_f32_16x16x32_bf16(
                    af[i], bf[j], acc[i][j], 0, 0, 0);
    }
#pragma unroll
    for (int j = 0; j < 4; j++) {
        int col = wn + j * 16 + ln;
#pragma unroll
        for (int i = 0; i < 4; i++) {
            int r0 = wm + i * 16 + q * 4;
#pragma unroll
            for (int r = 0; r < 4; r++)
                tile[(r0 + r) * 130 + col] = bfr(acc[i][j][r]);
        }
    }
    __syncthreads();
    unsigned* Yu = (unsigned*)Yp;
    for (int idx = tid; idx < 128 * 64; idx += 256) {
        int b = idx >> 6, dw = idx & 63;
        unsigned v = *(const unsigned*)&tile[b * 130 + 2 * dw];
        Yu[(hm * 128 + b) * 64 + dw] = v;
    }
}

// ---------------------------------------------------------------------------
// idft_v2: Out bf16 [(b,h,o)*L + l] = bf16(s * sum_k Y'[..][k]*Ti[l][k])
__global__ __launch_bounds__(256) void idft_v2(
    const unsigned short* __restrict__ Yp, const unsigned short* __restrict__ Tib,
    unsigned short* __restrict__ Out, int L, int K, int M, float s) {
    __shared__ unsigned short sh[2 * 64 * 132];
    const int tid = threadIdx.x;
    const int lane = tid & 63, wv = tid >> 6;
    const int wm = (wv & 1) * 64, wn = (wv >> 1) * 64;
    const int q = lane >> 4, ln = lane & 15;
    const int bm = blockIdx.y;
    const int b = bm >> 2, h0 = (bm & 3) * 2;
    const int bn = blockIdx.x * 128;

    const unsigned* Yu = (const unsigned*)Yp;
    for (int idx = tid; idx < 2 * M * 64; idx += 256) {
        int chunk = idx >> 6, dw = idx & 63;
        int h2 = chunk / M, m = chunk - h2 * M;
        unsigned v = Yu[((size_t)((h0 + h2) * M + m) * 128 + b) * 64 + dw];
        *(unsigned*)&sh[chunk * 132 + 2 * dw] = v;
    }
    __syncthreads();

    f32x4 acc[4][4];
#pragma unroll
    for (int i = 0; i < 4; i++)
#pragma unroll
        for (int j = 0; j < 4; j++) acc[i][j] = (f32x4){0.f, 0.f, 0.f, 0.f};

    for (int k0 = 0; k0 < K; k0 += 32) {
        bf16x8 af[4], bf[4];
        union FR { bf16x8 v; unsigned u[4]; };
#pragma unroll
        for (int i = 0; i < 4; i++) {
            int lr = wm + i * 16 + ln;
            int h2 = lr >> 6, o = lr & 63;
            FR fr;
#pragma unroll
            for (int jj = 0; jj < 4; jj++) {
                int m = (k0 >> 1) + q * 4 + jj;
                fr.u[jj] = *(const unsigned*)&sh[(h2 * M + m) * 132 + 2 * o];
            }
            af[i] = fr.v;
        }
#pragma unroll
        for (int j = 0; j < 4; j++) {
            int n = bn + wn + j * 16 + ln;
            if (n < L) bf[j] = *(const bf16x8*)(Tib + (size_t)n * K + k0 + q * 8);
            else bf[j] = (bf16x8){0, 0, 0, 0, 0, 0, 0, 0};
        }
#pragma unroll
        for (int i = 0; i < 4; i++)
#pragma unroll
            for (int j = 0; j < 4; j++)
                acc[i][j] = __builtin_amdgcn_mfma_f32_16x16x32_bf16(
                    af[i], bf[j], acc[i][j], 0, 0, 0);
    }
#pragma unroll
    for (int j = 0; j < 4; j++) {
        int col = bn + wn + j * 16 + ln;
        if (col >= L) continue;
#pragma unroll
        for (int i = 0; i < 4; i++) {
            int row0 = bm * 128 + wm + i * 16 + q * 4;
#pragma unroll
            for (int r = 0; r < 4; r++)
                Out[(size_t)(row0 + r) * L + col] = bfr(acc[i][j][r] * s);
        }
    }
}

// ---------------------------------------------------------------------------
// xqk2: G (packed bf16 pairs) = ctanh(Q^T K) from XT chunks
__global__ __launch_bounds__(256) void xqk2(
    const unsigned short* __restrict__ XTQ, const unsigned short* __restrict__ XTK,
    unsigned* __restrict__ G) {
    __shared__ float Qre[64 * 65], Qim[64 * 65];
    __shared__ float Kre[64 * 49], Kim[64 * 49];
    int b = blockIdx.x, h = blockIdx.y;
    const unsigned* Qu = (const unsigned*)XTQ;
    const unsigned* Ku = (const unsigned*)XTK;
    for (int idx = threadIdx.x; idx < 64 * 64; idx += 256) {
        int x = idx >> 6, e = idx & 63;
        unsigned v = Qu[((size_t)(h * 64 + x) * 128 + b) * 64 + e];
        Qre[e * 65 + x] = bf2f((unsigned short)(v & 0xFFFF));
        Qim[e * 65 + x] = bf2f((unsigned short)(v >> 16));
    }
    for (int idx = threadIdx.x; idx < 48 * 64; idx += 256) {
        int y = idx >> 6, e = idx & 63;
        unsigned v = Ku[((size_t)(h * 48 + y) * 128 + b) * 64 + e];
        Kre[e * 49 + y] = bf2f((unsigned short)(v & 0xFFFF));
        Kim[e * 49 + y] = bf2f((unsigned short)(v >> 16));
    }
    __syncthreads();
    for (int i = threadIdx.x; i < 64 * 48; i += 256) {
        int x = i / 48, y = i - x * 48;
        float re = 0.f, im = 0.f;
#pragma unroll 8
        for (int e = 0; e < 64; e++) {
            float qr = Qre[e * 65 + x], qi = Qim[e * 65 + x];
            float kr = Kre[e * 49 + y], ki = Kim[e * 49 + y];
            re += qr * kr - qi * ki;
            im += qr * ki + qi * kr;
        }
        float a2 = 2.f * re, b2 = 2.f * im;
        a2 = fminf(fmaxf(a2, -80.f), 80.f);
        float denom = coshf(a2) + cosf(b2);
        G[((size_t)b * 8 + h) * 3072 + i] = pack2(sinhf(a2) / denom, sinf(b2) / denom);
    }
}

// xqkv2: VT[h][x][b][2e+p] bf16 = sum_y G[x,y] * K[e,y]
__global__ __launch_bounds__(256) void xqkv2(
    const unsigned* __restrict__ G, const unsigned short* __restrict__ XTK,
    unsigned short* __restrict__ VT) {
    __shared__ float Gre[64 * 49], Gim[64 * 49];
    __shared__ float Kre[64 * 49], Kim[64 * 49];
    int b = blockIdx.x, h = blockIdx.y;
    const unsigned* Ku = (const unsigned*)XTK;
    const unsigned* gs = G + ((size_t)b * 8 + h) * 3072;
    for (int idx = threadIdx.x; idx < 64 * 48; idx += 256) {
        int x = idx / 48, y = idx - x * 48;
        unsigned g = gs[idx];
        Gre[x * 49 + y] = bf2f((unsigned short)(g & 0xFFFF));
        Gim[x * 49 + y] = bf2f((unsigned short)(g >> 16));
    }
    for (int idx = threadIdx.x; idx < 48 * 64; idx += 256) {
        int y = idx >> 6, e = idx & 63;
        unsigned v = Ku[((size_t)(h * 48 + y) * 128 + b) * 64 + e];
        Kre[e * 49 + y] = bf2f((unsigned short)(v & 0xFFFF));
        Kim[e * 49 + y] = bf2f((unsigned short)(v >> 16));
    }
    __syncthreads();
    unsigned* Vu = (unsigned*)VT;
    for (int idx = threadIdx.x; idx < 4096; idx += 256) {
        int x = idx >> 6, e = idx & 63;
        float re = 0.f, im = 0.f;
#pragma unroll 8
        for (int y = 0; y < 48; y++) {
            float gr = Gre[x * 49 + y], gi = Gim[x * 49 + y];
            float kr = Kre[e * 49 + y], ki = Kim[e * 49 + y];
            re += gr * kr - gi * ki;
            im += gr * ki + gi * kr;
        }
        Vu[((size_t)(h * 64 + x) * 128 + b) * 64 + e] = pack2(re, im);
    }
}

// ---------------------------------------------------------------------------
// series_decomp (+ optional bf16 copy of seasonal out)
__global__ void decomp_kernel(const float* __restrict__ P, const float* __restrict__ Q,
                              float* __restrict__ SO, unsigned short* __restrict__ SOb,
                              float* __restrict__ TS, int L, int tmode) {
    int b = blockIdx.x, d0 = blockIdx.y * 64;
    __shared__ float s[144 * 64];
    for (int i = threadIdx.x; i < L * 64; i += 256) {
        int l = i >> 6, d = i & 63;
        size_t idx = ((size_t)b * L + l) * 512 + d0 + d;
        float v = P[idx];
        if (Q) v += Q[idx];
        s[i] = v;
    }
    __syncthreads();
    for (int i = threadIdx.x; i < L * 64; i += 256) {
        int l = i >> 6, d = i & 63;
        float sum = 0.f;
#pragma unroll
        for (int j = -12; j <= 12; j++) sum += s[iclamp(l + j, 0, L - 1) * 64 + d];
        float ma = sum * (1.0f / 25.0f);
        size_t idx = ((size_t)b * L + l) * 512 + d0 + d;
        float so = s[i] - ma;
        SO[idx] = so;
        if (SOb) SOb[idx] = bfr(so);
        if (tmode == 1) TS[idx] = ma;
        else if (tmode == 2) TS[idx] += ma;
    }
}

// ---------------------------------------------------------------------------
__global__ __launch_bounds__(256) void ln_rows_kernel(const float* __restrict__ in,
                                                      const float* __restrict__ w,
                                                      const float* __restrict__ bvec,
                                                      float* __restrict__ out) {
    size_t row = blockIdx.x;
    const float* p = in + row * 512;
    int t = threadIdx.x;
    float v0 = p[t], v1 = p[t + 256];
    float s = v0 + v1, s2 = v0 * v0 + v1 * v1;
    for (int o = 32; o > 0; o >>= 1) {
        s += __shfl_xor(s, o, 64);
        s2 += __shfl_xor(s2, o, 64);
    }
    __shared__ float rs[4], rs2[4];
    int wid = t >> 6;
    if ((t & 63) == 0) { rs[wid] = s; rs2[wid] = s2; }
    __syncthreads();
    s = rs[0] + rs[1] + rs[2] + rs[3];
    s2 = rs2[0] + rs2[1] + rs2[2] + rs2[3];
    float mu = s * (1.0f / 512.0f);
    float var = s2 * (1.0f / 512.0f) - mu * mu;
    float r = rsqrtf(var + 1e-5f);
    out[row * 512 + t] = (v0 - mu) * r * w[t] + bvec[t];
    out[row * 512 + t + 256] = (v1 - mu) * r * w[t + 256] + bvec[t + 256];
}

// timesub (+ optional bf16 copy)
__global__ void timesub_kernel(float* __restrict__ X, unsigned short* __restrict__ Xb,
                               int L) {
    int b = blockIdx.x, d0 = blockIdx.y * 64;
    __shared__ float tile[144 * 64];
    __shared__ float mean[64];
    for (int i = threadIdx.x; i < L * 64; i += 256) {
        int l = i >> 6, d = i & 63;
        tile[i] = X[((size_t)b * L + l) * 512 + d0 + d];
    }
    __syncthreads();
    if (threadIdx.x < 64) {
        float sm = 0.f;
        for (int l = 0; l < L; l++) sm += tile[l * 64 + threadIdx.x];
        mean[threadIdx.x] = sm / (float)L;
    }
    __syncthreads();
    for (int i = threadIdx.x; i < L * 64; i += 256) {
        int l = i >> 6, d = i & 63;
        size_t idx = ((size_t)b * L + l) * 512 + d0 + d;
        float v = tile[i] - mean[d];
        X[idx] = v;
        if (Xb) Xb[idx] = bfr(v);
    }
}

// ---------------------------------------------------------------------------
__global__ __launch_bounds__(256) void final_v2(
    const float* __restrict__ XL, const float* __restrict__ TS,
    const float* __restrict__ TI, const float* __restrict__ trend_w,
    const float* __restrict__ proj_w, const float* __restrict__ proj_b,
    float* __restrict__ out) {
    int blk = blockIdx.x;
    int b = blk / 96, lo = blk - b * 96;
    int l = lo + 48;
    int lm = l - 1;
    int lp = (l == 143) ? 0 : l + 1;
    const float* ts = TS + (size_t)b * 144 * 512;
    const float* r0 = ts + (size_t)lm * 512;
    const float* r1 = ts + (size_t)l * 512;
    const float* r2 = ts + (size_t)lp * 512;
    const float* xl = XL + ((size_t)b * 144 + l) * 512;
    int t = threadIdx.x;
    float p[7];
#pragma unroll
    for (int c = 0; c < 7; c++) p[c] = 0.f;
#pragma unroll
    for (int dd = 0; dd < 2; dd++) {
        int d = t + dd * 256;
        float a0 = r0[d], a1 = r1[d], a2 = r2[d], x = xl[d];
#pragma unroll
        for (int c = 0; c < 7; c++) {
            const float* tw = trend_w + ((size_t)c * 512 + d) * 3;
            float v = a0 * tw[0] + a1 * tw[1] + a2 * tw[2];
            v = fmaf(x, proj_w[c * 512 + d], v);
            p[c] += v;
        }
    }
#pragma unroll
    for (int o = 32; o > 0; o >>= 1)
#pragma unroll
        for (int c = 0; c < 7; c++) p[c] += __shfl_xor(p[c], o, 64);
    __shared__ float red[4][7];
    int wid = t >> 6;
    if ((t & 63) == 0)
#pragma unroll
        for (int c = 0; c < 7; c++) red[wid][c] = p[c];
    __syncthreads();
    if (t < 7) {
        float v = red[0][t] + red[1][t] + red[2][t] + red[3][t]
                + TI[((size_t)b * 144 + l) * 7 + t] + proj_b[t];
        out[(size_t)blk * 7 + t] = v;
    }
}

// ---------------------------------------------------------------------------
static inline int cdiv(int a, int b) { return (a + b - 1) / b; }

extern "C" void kernel_launch(void* const* d_in, const int* in_sizes, int n_in,
                              void* d_out, int out_size, void* d_ws, size_t ws_size,
                              hipStream_t stream) {
    const float* x_enc      = (const float*)d_in[0];
    const float* x_mark_enc = (const float*)d_in[1];
    const float* x_mark_dec = (const float*)d_in[3];
    const float* enc_emb_conv_w = (const float*)d_in[4];
    const float* enc_emb_time_w = (const float*)d_in[5];
    const float* dec_emb_conv_w = (const float*)d_in[6];
    const float* dec_emb_time_w = (const float*)d_in[7];
    const float* enc_qw = (const float*)d_in[8];
    const float* enc_qb = (const float*)d_in[9];
    const float* enc_ow = (const float*)d_in[14];
    const float* enc_ob = (const float*)d_in[15];
    const float* enc_fw = (const float*)d_in[16];
    const float* enc_c1 = (const float*)d_in[17];
    const float* enc_c2 = (const float*)d_in[18];
    const float* enc_norm_w = (const float*)d_in[19];
    const float* enc_norm_b = (const float*)d_in[20];
    const float* ds_qw = (const float*)d_in[21];
    const float* ds_qb = (const float*)d_in[22];
    const float* ds_ow = (const float*)d_in[27];
    const float* ds_ob = (const float*)d_in[28];
    const float* ds_fw = (const float*)d_in[29];
    const float* dc_qw = (const float*)d_in[30];
    const float* dc_qb = (const float*)d_in[31];
    const float* dc_kw = (const float*)d_in[32];
    const float* dc_kb = (const float*)d_in[33];
    const float* dc_ow = (const float*)d_in[36];
    const float* dc_ob = (const float*)d_in[37];
    const float* dc_fw = (const float*)d_in[38];
    const float* dec_c1 = (const float*)d_in[39];
    const float* dec_c2 = (const float*)d_in[40];
    const float* dec_trend_w = (const float*)d_in[41];
    const float* dec_norm_w = (const float*)d_in[42];
    const float* dec_norm_b = (const float*)d_in[43];
    const float* proj_w = (const float*)d_in[44];
    const float* proj_b = (const float*)d_in[45];

    float* ws = (float*)d_ws;
    float* XD   = ws;                        // 9,437,184
    float* TS   = ws + 9437184;              // 9,437,184
    float* XE   = ws + 18874368;             // 6,291,456 (fout aliases XE+XEb)
    unsigned short* XEb = (unsigned short*)(ws + 25165824);  // 3,145,728 fl
    unsigned short* XDb = (unsigned short*)(ws + 28311552);  // 4,718,592 fl
    float* SI   = ws + 33030144;             // 129,024
    float* TI   = ws + 33159168;             // 129,024
    float* TAB  = ws + 33288192;             // 32,768
    unsigned short* WF = (unsigned short*)(ws + 33320960);   // 4,325,376 fl
    float* SC   = ws + 37646336;             // 16,121,856 fl scratch
    unsigned short* TdbE = (unsigned short*)(TAB);
    unsigned short* TdbD = (unsigned short*)(TAB + 6144);
    unsigned short* TibE = (unsigned short*)(TAB + 16384);
    unsigned short* TibD = (unsigned short*)(TAB + 20992);

    unsigned short* enc_qw_b = WF;
    unsigned short* enc_ow_b = WF + 524288;
    unsigned short* enc_c1_b = WF + 1048576;
    unsigned short* enc_c2_b = WF + 3145728;
    unsigned short* ds_qw_b  = WF + 5242880;
    unsigned short* ds_ow_b  = WF + 5505024;
    unsigned short* dc_qw_b  = WF + 5767168;
    unsigned short* dc_kw_b  = WF + 6029312;
    unsigned short* dc_ow_b  = WF + 6291456;
    unsigned short* dec_c1_b = WF + 6553600;
    unsigned short* dec_c2_b = WF + 7602176;

    const size_t need_bytes = (size_t)53768192 * sizeof(float);
    if (ws_size < need_bytes) {
        zero_out_kernel<<<cdiv(out_size, 256), 256, 0, stream>>>((float*)d_out, out_size);
        return;
    }

    auto conv = [&](const float* s, unsigned short* d, int n) {
        f2b<<<cdiv(n / 4, 256), 256, 0, stream>>>(s, d, n);
    };
    auto gemm = [&](const unsigned short* A, const unsigned short* W, const float* bias,
                    float* Cf, unsigned short* Cb, int rows, int N, int K,
                    int lda, int ldw, int gelu, int accum) {
        dim3 g(N / 128, rows / 128);
        gemm_bb<<<g, 256, 0, stream>>>(A, W, bias, Cf, Cb, N, K, lda, ldw, gelu, accum);
    };

    // ---- weight conversion
    conv(enc_qw, enc_qw_b, 524288);
    conv(enc_ow, enc_ow_b, 524288);
    conv(enc_c1, enc_c1_b, 2097152);
    conv(enc_c2, enc_c2_b, 2097152);
    conv(ds_qw, ds_qw_b, 262144);
    conv(ds_ow, ds_ow_b, 262144);
    conv(dc_qw, dc_qw_b, 262144);
    conv(dc_kw, dc_kw_b, 262144);
    conv(dc_ow, dc_ow_b, 262144);
    conv(dec_c1, dec_c1_b, 1048576);
    conv(dec_c2, dec_c2_b, 1048576);

    // ---- twiddle tables
    dtab_kernel<<<cdiv(128 * 96, 256), 256, 0, stream>>>(TdbE, 48, 96, 96);
    dtab_kernel<<<cdiv(128 * 160, 256), 256, 0, stream>>>(TdbD, 64, 144, 160);
    itab_kernel<<<cdiv(96 * 96, 256), 256, 0, stream>>>(TibE, 48, 96, 96);
    itab_kernel<<<cdiv(144 * 128, 256), 256, 0, stream>>>(TibD, 64, 144, 128);

    // ---- preprocess + encoder embed
    preprocess_kernel<<<cdiv(128 * 144 * 7, 256), 256, 0, stream>>>(x_enc, SI, TI);
    embed_kernel<<<cdiv(128 * 96 * 512, 256), 256, 0, stream>>>(
        x_enc, x_mark_enc, enc_emb_conv_w, enc_emb_time_w, XE, XEb, 96);

    // ---- encoder layers (M=48)
    for (int l = 0; l < 2; l++) {
        const unsigned short* qwb = enc_qw_b + (size_t)l * 262144;
        const float* qb = enc_qb + (size_t)l * 512;
        const unsigned short* owb = enc_ow_b + (size_t)l * 262144;
        const float* ob = enc_ob + (size_t)l * 512;
        const float* fw = enc_fw + (size_t)l * 8 * 64 * 64 * 48 * 2;
        const unsigned short* c1b = enc_c1_b + (size_t)l * 1048576;
        const unsigned short* c2b = enc_c2_b + (size_t)l * 1048576;
        unsigned short* Pq = (unsigned short*)(SC);
        unsigned short* XT = (unsigned short*)(SC + 3145728);
        unsigned short* WB = (unsigned short*)(SC + 6291456);
        unsigned short* Yp = (unsigned short*)(SC + 9437184);
        unsigned short* Tidb = (unsigned short*)(SC);
        float* To = SC + 3145728;

        gemm(XEb, qwb, qb, nullptr, Pq, 12288, 512, 512, 512, 512, 0, 0);
        dft_mfma2<<<dim3(1, 512), 256, 0, stream>>>(Pq, TdbE, XT, 96, 96, 48);
        wtrans3<<<dim3(16, 8), 256, 0, stream>>>(fw, WB, 48);
        mix_v2<<<dim3(48, 8), 256, 0, stream>>>(XT, WB, Yp, 48);
        idft_v2<<<dim3(1, 512), 256, 0, stream>>>(Yp, TibE, Tidb, 96, 96, 48, 1.f / 96.f);
        gemm(Tidb, owb, ob, To, nullptr, 12288, 512, 512, 512, 512, 0, 0);
        decomp_kernel<<<dim3(128, 8), 256, 0, stream>>>(XE, To, XE, XEb, nullptr, 96, 0);
        unsigned short* hid = (unsigned short*)(SC);
        gemm(XEb, c1b, nullptr, nullptr, hid, 12288, 2048, 512, 512, 512, 1, 0);
        gemm(hid, c2b, nullptr, TS, nullptr, 12288, 512, 2048, 2048, 2048, 0, 0);
        decomp_kernel<<<dim3(128, 8), 256, 0, stream>>>(XE, TS, XE, XEb, nullptr, 96, 0);
    }
    ln_rows_kernel<<<12288, 256, 0, stream>>>(XE, enc_norm_w, enc_norm_b, XE);
    timesub_kernel<<<dim3(128, 8), 256, 0, stream>>>(XE, XEb, 96);

    // ---- decoder embed
    embed_kernel<<<cdiv(128 * 144 * 512, 256), 256, 0, stream>>>(
        SI, x_mark_dec, dec_emb_conv_w, dec_emb_time_w, XD, XDb, 144);

    // ---- decoder self fourier block (M=64)
    {
        unsigned short* Pq = (unsigned short*)(SC);
        unsigned short* XT = (unsigned short*)(SC + 4718592);
        unsigned short* WB = (unsigned short*)(SC + 8912896);
        unsigned short* Yp = (unsigned short*)(SC);
        unsigned short* Tidb = (unsigned short*)(SC + 9437184);
        float* To = SC;

        gemm(XDb, ds_qw_b, ds_qb, nullptr, Pq, 18432, 512, 512, 512, 512, 0, 0);
        dft_mfma2<<<dim3(1, 512), 256, 0, stream>>>(Pq, TdbD, XT, 144, 160, 64);
        wtrans3<<<dim3(16, 8), 256, 0, stream>>>(ds_fw, WB, 64);
        mix_v2<<<dim3(64, 8), 256, 0, stream>>>(XT, WB, Yp, 64);
        idft_v2<<<dim3(2, 512), 256, 0, stream>>>(Yp, TibD, Tidb, 144, 128, 64, 1.f / 144.f);
        gemm(Tidb, ds_ow_b, ds_ob, To, nullptr, 18432, 512, 512, 512, 512, 0, 0);
        decomp_kernel<<<dim3(128, 8), 256, 0, stream>>>(XD, To, XD, XDb, TS, 144, 1);
    }

    // ---- cross attention
    {
        unsigned short* Pq  = (unsigned short*)(SC);
        unsigned short* XTQ = (unsigned short*)(SC + 4718592);
        unsigned short* Pk  = (unsigned short*)(SC);
        unsigned short* XTK = (unsigned short*)(SC + 8912896);
        unsigned* G         = (unsigned*)(SC);
        unsigned short* VT  = (unsigned short*)(SC + 3145728);
        unsigned short* WB  = (unsigned short*)(SC + 7340032);
        unsigned short* Yp  = (unsigned short*)(SC + 11534336);
        unsigned short* Tidb = (unsigned short*)(SC);
        float* To = SC + 4718592;

        gemm(XDb, dc_qw_b, dc_qb, nullptr, Pq, 18432, 512, 512, 512, 512, 0, 0);
        dft_mfma2<<<dim3(1, 512), 256, 0, stream>>>(Pq, TdbD, XTQ, 144, 160, 64);
        gemm(XEb, dc_kw_b, dc_kb, nullptr, Pk, 12288, 512, 512, 512, 512, 0, 0);
        dft_mfma2<<<dim3(1, 512), 256, 0, stream>>>(Pk, TdbE, XTK, 96, 96, 48);
        xqk2<<<dim3(128, 8), 256, 0, stream>>>(XTQ, XTK, G);
        xqkv2<<<dim3(128, 8), 256, 0, stream>>>(G, XTK, VT);
        wtrans3<<<dim3(16, 8), 256, 0, stream>>>(dc_fw, WB, 64);
        mix_v2<<<dim3(64, 8), 256, 0, stream>>>(VT, WB, Yp, 64);
        idft_v2<<<dim3(2, 512), 256, 0, stream>>>(Yp, TibD, Tidb, 144, 128, 64,
                                                  1.f / (144.f * 262144.f));
        gemm(Tidb, dc_ow_b, dc_ob, To, nullptr, 18432, 512, 512, 512, 512, 0, 0);
        decomp_kernel<<<dim3(128, 8), 256, 0, stream>>>(XD, To, XD, XDb, TS, 144, 2);
    }

    // ---- decoder FFN: 2 chunks of N=1024; hid bf16 in SC, fout aliases XE+XEb
    {
        unsigned short* hid = (unsigned short*)(SC);
        float* fout = XE;
        for (int j0 = 0; j0 < 2048; j0 += 1024) {
            gemm(XDb, dec_c1_b + (size_t)j0 * 512, nullptr, nullptr, hid,
                 18432, 1024, 512, 512, 512, 1, 0);
            gemm(hid, dec_c2_b + j0, nullptr, fout, nullptr,
                 18432, 512, 1024, 1024, 2048, 0, j0 > 0);
        }
        decomp_kernel<<<dim3(128, 8), 256, 0, stream>>>(XD, fout, XD, nullptr, TS, 144, 2);
    }

    // ---- final norm + trend conv + projection
    ln_rows_kernel<<<18432, 256, 0, stream>>>(XD, dec_norm_w, dec_norm_b, XD);
    timesub_kernel<<<dim3(128, 8), 256, 0, stream>>>(XD, nullptr, 144);
    final_v2<<<12288, 256, 0, stream>>>(
        XD, TS, TI, dec_trend_w, proj_w, proj_b, (float*)d_out);
}

// Round 9
// 1646.679 us; speedup vs baseline: 4.2717x; 1.0425x over previous
//
#include <hip/hip_runtime.h>
#include <hip/hip_bf16.h>
#include <math.h>

// Model_45904610459674: FEDformer-style forecaster.
// Round 9: cross-attention xqk/xqkv as bf16 MFMA GEMMs (real-embedded
// complex). xqk3: S=Q^T·[Kre|Kim] 64x96x128 + tanh epilogue; xqkv3:
// V=G·B2 64x128x96, B2 built in LDS from K with sign/rotate int ops.
// Everything else identical to R8 (passing, absmax 7.8e-3, 1717 us).
// Workspace: 53,768,192 floats = 215.07 MB (same guard).

#define PI_F 3.14159265358979323846f

typedef short bf16x8 __attribute__((ext_vector_type(8)));
typedef float f32x4 __attribute__((ext_vector_type(4)));

static __device__ __forceinline__ int iclamp(int v, int lo, int hi) {
    return v < lo ? lo : (v > hi ? hi : v);
}
static __device__ __forceinline__ unsigned pack2(float x, float y) {
    unsigned xu = __float_as_uint(x) + 0x8000u;
    unsigned yu = __float_as_uint(y) + 0x8000u;
    return (xu >> 16) | (yu & 0xFFFF0000u);
}
static __device__ __forceinline__ unsigned short bfr(float x) {
    return (unsigned short)((__float_as_uint(x) + 0x8000u) >> 16);
}
static __device__ __forceinline__ float bf2f(unsigned short s) {
    return __uint_as_float((unsigned)s << 16);
}

__global__ void zero_out_kernel(float* __restrict__ out, int n) {
    int i = blockIdx.x * 256 + threadIdx.x;
    if (i < n) out[i] = 0.f;
}

// f2b: fp32 -> bf16, 4 elems/thread
__global__ void f2b(const float* __restrict__ s, unsigned short* __restrict__ d, int n) {
    int i = (blockIdx.x * 256 + threadIdx.x) * 4;
    if (i >= n) return;
    const float4 v = *(const float4*)(s + i);
    *(uint2*)(d + i) = make_uint2(pack2(v.x, v.y), pack2(v.z, v.w));
}

// ---------------------------------------------------------------------------
__global__ void preprocess_kernel(const float* __restrict__ xe,
                                  float* __restrict__ SI, float* __restrict__ TI) {
    int idx = blockIdx.x * 256 + threadIdx.x;
    if (idx >= 128 * 144 * 7) return;
    int c = idx % 7;
    int l = (idx / 7) % 144;
    int b = idx / (7 * 144);
    const float* xb = xe + (size_t)b * 96 * 7;
    if (l < 48) {
        int p = 48 + l;
        float sum = 0.f;
        for (int j = -12; j <= 12; j++) sum += xb[iclamp(p + j, 0, 95) * 7 + c];
        float ma = sum * (1.0f / 25.0f);
        SI[idx] = xb[p * 7 + c] - ma;
        TI[idx] = ma;
    } else {
        SI[idx] = 0.f;
        float m = 0.f;
        for (int l2 = 0; l2 < 96; l2++) m += xb[l2 * 7 + c];
        TI[idx] = m * (1.0f / 96.0f);
    }
}

// ---------------------------------------------------------------------------
// embed + bf16 copy
__global__ void embed_kernel(const float* __restrict__ x, const float* __restrict__ mark,
                             const float* __restrict__ cw, const float* __restrict__ tw,
                             float* __restrict__ out, unsigned short* __restrict__ outb,
                             int L) {
    size_t idx = (size_t)blockIdx.x * 256 + threadIdx.x;
    if (idx >= (size_t)128 * L * 512) return;
    int o = idx & 511;
    int l = (int)((idx >> 9) % L);
    int b = (int)(idx / ((size_t)512 * L));
    int lm = (l == 0) ? L - 1 : l - 1;
    int lp = (l == L - 1) ? 0 : l + 1;
    const float* x0 = x + (size_t)b * L * 7;
    float v = 0.f;
#pragma unroll
    for (int c = 0; c < 7; c++) {
        const float* w = cw + (o * 7 + c) * 3;
        v += x0[lm * 7 + c] * w[0] + x0[l * 7 + c] * w[1] + x0[lp * 7 + c] * w[2];
    }
    const float* mk = mark + ((size_t)b * L + l) * 4;
#pragma unroll
    for (int f = 0; f < 4; f++) v += mk[f] * tw[o * 4 + f];
    out[idx] = v;
    outb[idx] = bfr(v);
}

// ---------------------------------------------------------------------------
// gemm_bb: A,W bf16. Staging: global_load_lds 16B DMA, XOR-swizzled chunks.
__global__ __launch_bounds__(256, 4) void gemm_bb(
    const unsigned short* __restrict__ A, const unsigned short* __restrict__ W,
    const float* __restrict__ bias, float* __restrict__ Cf,
    unsigned short* __restrict__ Cb,
    int N, int K, int lda, int ldw, int gelu, int accum) {
    __shared__ unsigned short As[128 * 64];
    __shared__ unsigned short Ws[128 * 64];
    const int tid = threadIdx.x;
    const int lane = tid & 63, wv = tid >> 6;
    const int wm = (wv & 1) * 64, wn = (wv >> 1) * 64;
    const int q = lane >> 4, ln = lane & 15;
    const size_t bm = (size_t)blockIdx.y * 128;
    const size_t bn = (size_t)blockIdx.x * 128;

    f32x4 acc[4][4];
#pragma unroll
    for (int i = 0; i < 4; i++)
#pragma unroll
        for (int j = 0; j < 4; j++) acc[i][j] = (f32x4){0.f, 0.f, 0.f, 0.f};

    for (int k0 = 0; k0 < K; k0 += 64) {
#pragma unroll
        for (int t = 0; t < 4; t++) {
            int idx = (wv * 4 + t) * 64 + lane;
            int row = idx >> 3, cp = idx & 7;
            int cl = cp ^ (row & 7);
            __builtin_amdgcn_global_load_lds(
                (const __attribute__((address_space(1))) void*)(A + (bm + row) * lda + k0 + cl * 8),
                (__attribute__((address_space(3))) void*)(As + (size_t)(wv * 4 + t) * 512),
                16, 0, 0);
            __builtin_amdgcn_global_load_lds(
                (const __attribute__((address_space(1))) void*)(W + (bn + row) * ldw + k0 + cl * 8),
                (__attribute__((address_space(3))) void*)(Ws + (size_t)(wv * 4 + t) * 512),
                16, 0, 0);
        }
        __syncthreads();
#pragma unroll
        for (int kk = 0; kk < 64; kk += 32) {
            bf16x8 af[4], bfr4[4];
            const int cq = (kk >> 3) + q;
#pragma unroll
            for (int i = 0; i < 4; i++) {
                int r = wm + i * 16 + ln;
                af[i] = *(const bf16x8*)(As + r * 64 + ((cq ^ (r & 7)) * 8));
                int rw = wn + i * 16 + ln;
                bfr4[i] = *(const bf16x8*)(Ws + rw * 64 + ((cq ^ (rw & 7)) * 8));
            }
#pragma unroll
            for (int i = 0; i < 4; i++)
#pragma unroll
                for (int j = 0; j < 4; j++)
                    acc[i][j] = __builtin_amdgcn_mfma_f32_16x16x32_bf16(
                        af[i], bfr4[j], acc[i][j], 0, 0, 0);
        }
        __syncthreads();
    }
#pragma unroll
    for (int j = 0; j < 4; j++) {
        int col = (int)bn + wn + j * 16 + ln;
        float bv = bias ? bias[col] : 0.f;
#pragma unroll
        for (int i = 0; i < 4; i++) {
            size_t row0 = bm + wm + i * 16 + q * 4;
#pragma unroll
            for (int r = 0; r < 4; r++) {
                float v = acc[i][j][r] + bv;
                if (gelu) v = 0.5f * v * (1.f + erff(v * 0.70710678118654752f));
                if (Cb) {
                    Cb[(row0 + r) * N + col] = bfr(v);
                } else {
                    float* p = Cf + (row0 + r) * N + col;
                    if (accum) v += *p;
                    *p = v;
                }
            }
        }
    }
}

// ---------------------------------------------------------------------------
// twiddle tables (bf16)
__global__ void dtab_kernel(unsigned short* __restrict__ T, int M, int L, int ldk) {
    int i = blockIdx.x * 256 + threadIdx.x;
    if (i >= 128 * ldk) return;
    int n = i / ldk, k = i - n * ldk;
    float val = 0.f;
    if (n < 2 * M && k < L) {
        int m = n >> 1;
        int r = (m * k) % L;
        float ang = -2.f * PI_F * (float)r / (float)L;
        val = (n & 1) ? sinf(ang) : cosf(ang);
    }
    T[i] = bfr(val);
}
__global__ void itab_kernel(unsigned short* __restrict__ T, int M, int L, int K) {
    int i = blockIdx.x * 256 + threadIdx.x;
    if (i >= L * K) return;
    int n = i / K, k = i - n * K;
    int m = k >> 1;
    float c = (m == 0) ? 1.f : 2.f;
    int r = (m * n) % L;
    float ang = 2.f * PI_F * (float)r / (float)L;
    float val = (k & 1) ? -c * sinf(ang) : c * cosf(ang);
    T[i] = bfr(val);
}

// ---------------------------------------------------------------------------
// dft MFMA v2 (bf16 input): P bf16 [B*L,512] -> XT[h][m][b][2e+p] bf16
__global__ __launch_bounds__(256) void dft_mfma2(
    const unsigned short* __restrict__ P, const unsigned short* __restrict__ Tdb,
    unsigned short* __restrict__ XT, int L, int ldk, int M) {
    __shared__ unsigned short tile[128 * 130];
    const int tid = threadIdx.x;
    const int lane = tid & 63, wv = tid >> 6;
    const int wm = (wv & 1) * 64, wn = (wv >> 1) * 64;
    const int q = lane >> 4, ln = lane & 15;
    const int bm = blockIdx.y;
    const int b = bm >> 2, c0 = (bm & 3) * 128;
    const int h0 = c0 >> 6;
    const unsigned short* Pb = P + (size_t)b * L * 512;

    f32x4 acc[4][4];
#pragma unroll
    for (int i = 0; i < 4; i++)
#pragma unroll
        for (int j = 0; j < 4; j++) acc[i][j] = (f32x4){0.f, 0.f, 0.f, 0.f};

    for (int k0 = 0; k0 < L; k0 += 32) {
        bf16x8 af[4], bf[4];
        union FR { bf16x8 v; unsigned short s[8]; };
#pragma unroll
        for (int i = 0; i < 4; i++) {
            int c = c0 + wm + i * 16 + ln;
            FR fr;
#pragma unroll
            for (int t = 0; t < 8; t++) {
                int l = k0 + q * 8 + t;
                fr.s[t] = (l < L) ? Pb[(size_t)l * 512 + c] : (unsigned short)0;
            }
            af[i] = fr.v;
        }
#pragma unroll
        for (int j = 0; j < 4; j++) {
            int n = wn + j * 16 + ln;
            bf[j] = *(const bf16x8*)(Tdb + (size_t)n * ldk + k0 + q * 8);
        }
#pragma unroll
        for (int i = 0; i < 4; i++)
#pragma unroll
            for (int j = 0; j < 4; j++)
                acc[i][j] = __builtin_amdgcn_mfma_f32_16x16x32_bf16(
                    af[i], bf[j], acc[i][j], 0, 0, 0);
    }
#pragma unroll
    for (int j = 0; j < 4; j++) {
        int col = wn + j * 16 + ln;
#pragma unroll
        for (int i = 0; i < 4; i++) {
            int r0 = wm + i * 16 + q * 4;
#pragma unroll
            for (int r = 0; r < 4; r++)
                tile[(r0 + r) * 130 + col] = bfr(acc[i][j][r]);
        }
    }
    __syncthreads();
    unsigned* XTu = (unsigned*)XT;
    for (int idx = tid; idx < 2 * M * 64; idx += 256) {
        int chunk = idx >> 6, e = idx & 63;
        int h2 = chunk / M, m = chunk - h2 * M;
        unsigned v = *(const unsigned*)&tile[(h2 * 64 + e) * 130 + 2 * m];
        XTu[((size_t)((h0 + h2) * M + m) * 128 + b) * 64 + e] = v;
    }
}

// ---------------------------------------------------------------------------
// wtrans3: w[h][e][o][m][2] fp32 -> WB[(h*M+m)][n=2o+q][k=2e+p] bf16
__global__ __launch_bounds__(256) void wtrans3(
    const float* __restrict__ w, unsigned short* __restrict__ WB, int M) {
    __shared__ float Lre[16 * 289], Lim[16 * 289];
    const int h = blockIdx.y;
    const int ot = blockIdx.x >> 1, et = blockIdx.x & 1;
    const int o0 = ot * 8, e0 = et * 32;
    const int tid = threadIdx.x;
    unsigned* WBu = (unsigned*)WB;
    for (int mc = 0; mc < M; mc += 16) {
        for (int idx = tid; idx < 4096; idx += 256) {
            int e = idx >> 7, o = (idx >> 4) & 7, mm = idx & 15;
            const float2 v = *(const float2*)(
                w + ((((size_t)h * 64 + e0 + e) * 64 + o0 + o) * M + mc + mm) * 2);
            Lre[mm * 289 + e * 9 + o] = v.x;
            Lim[mm * 289 + e * 9 + o] = v.y;
        }
        __syncthreads();
        for (int widx = tid; widx < 8192; widx += 256) {
            int mm = widx >> 9, no = (widx >> 5) & 15, e = widx & 31;
            int ol = no >> 1, qn = no & 1;
            float re = Lre[mm * 289 + e * 9 + ol];
            float im = Lim[mm * 289 + e * 9 + ol];
            unsigned v = qn ? pack2(im, re) : pack2(re, -im);
            WBu[((size_t)(h * M + mc + mm) * 128 + 2 * (o0 + ol) + qn) * 64 + e0 + e] = v;
        }
        __syncthreads();
    }
}

// ---------------------------------------------------------------------------
// mix_v2: per (h,m): Y'[b][n] = sum_k XT[hm][b][k]*WB[hm][n][k], b128 loads
__global__ __launch_bounds__(256) void mix_v2(
    const unsigned short* __restrict__ XT, const unsigned short* __restrict__ WB,
    unsigned short* __restrict__ Yp, int M) {
    __shared__ unsigned short tile[128 * 130];
    const int m = blockIdx.x, h = blockIdx.y;
    const int tid = threadIdx.x;
    const int lane = tid & 63, wv = tid >> 6;
    const int wm = (wv & 1) * 64, wn = (wv >> 1) * 64;
    const int q = lane >> 4, ln = lane & 15;
    const size_t hm = (size_t)h * M + m;
    const unsigned short* Ab = XT + hm * 16384;
    const unsigned short* Bb = WB + hm * 16384;

    f32x4 acc[4][4];
#pragma unroll
    for (int i = 0; i < 4; i++)
#pragma unroll
        for (int j = 0; j < 4; j++) acc[i][j] = (f32x4){0.f, 0.f, 0.f, 0.f};

#pragma unroll
    for (int k0 = 0; k0 < 128; k0 += 32) {
        bf16x8 af[4], bf[4];
#pragma unroll
        for (int i = 0; i < 4; i++)
            af[i] = *(const bf16x8*)(Ab + (size_t)(wm + i * 16 + ln) * 128 + k0 + q * 8);
#pragma unroll
        for (int j = 0; j < 4; j++)
            bf[j] = *(const bf16x8*)(Bb + (size_t)(wn + j * 16 + ln) * 128 + k0 + q * 8);
#pragma unroll
        for (int i = 0; i < 4; i++)
#pragma unroll
            for (int j = 0; j < 4; j++)
                acc[i][j] = __builtin_amdgcn_mfma_f32_16x16x32_bf16(
                    af[i], bf[j], acc[i][j], 0, 0, 0);
    }
#pragma unroll
    for (int j = 0; j < 4; j++) {
        int col = wn + j * 16 + ln;
#pragma unroll
        for (int i = 0; i < 4; i++) {
            int r0 = wm + i * 16 + q * 4;
#pragma unroll
            for (int r = 0; r < 4; r++)
                tile[(r0 + r) * 130 + col] = bfr(acc[i][j][r]);
        }
    }
    __syncthreads();
    unsigned* Yu = (unsigned*)Yp;
    for (int idx = tid; idx < 128 * 64; idx += 256) {
        int b = idx >> 6, dw = idx & 63;
        unsigned v = *(const unsigned*)&tile[b * 130 + 2 * dw];
        Yu[(hm * 128 + b) * 64 + dw] = v;
    }
}

// ---------------------------------------------------------------------------
// idft_v2: Out bf16 [(b,h,o)*L + l] = bf16(s * sum_k Y'[..][k]*Ti[l][k])
__global__ __launch_bounds__(256) void idft_v2(
    const unsigned short* __restrict__ Yp, const unsigned short* __restrict__ Tib,
    unsigned short* __restrict__ Out, int L, int K, int M, float s) {
    __shared__ unsigned short sh[2 * 64 * 132];
    const int tid = threadIdx.x;
    const int lane = tid & 63, wv = tid >> 6;
    const int wm = (wv & 1) * 64, wn = (wv >> 1) * 64;
    const int q = lane >> 4, ln = lane & 15;
    const int bm = blockIdx.y;
    const int b = bm >> 2, h0 = (bm & 3) * 2;
    const int bn = blockIdx.x * 128;

    const unsigned* Yu = (const unsigned*)Yp;
    for (int idx = tid; idx < 2 * M * 64; idx += 256) {
        int chunk = idx >> 6, dw = idx & 63;
        int h2 = chunk / M, m = chunk - h2 * M;
        unsigned v = Yu[((size_t)((h0 + h2) * M + m) * 128 + b) * 64 + dw];
        *(unsigned*)&sh[chunk * 132 + 2 * dw] = v;
    }
    __syncthreads();

    f32x4 acc[4][4];
#pragma unroll
    for (int i = 0; i < 4; i++)
#pragma unroll
        for (int j = 0; j < 4; j++) acc[i][j] = (f32x4){0.f, 0.f, 0.f, 0.f};

    for (int k0 = 0; k0 < K; k0 += 32) {
        bf16x8 af[4], bf[4];
        union FR { bf16x8 v; unsigned u[4]; };
#pragma unroll
        for (int i = 0; i < 4; i++) {
            int lr = wm + i * 16 + ln;
            int h2 = lr >> 6, o = lr & 63;
            FR fr;
#pragma unroll
            for (int jj = 0; jj < 4; jj++) {
                int m = (k0 >> 1) + q * 4 + jj;
                fr.u[jj] = *(const unsigned*)&sh[(h2 * M + m) * 132 + 2 * o];
            }
            af[i] = fr.v;
        }
#pragma unroll
        for (int j = 0; j < 4; j++) {
            int n = bn + wn + j * 16 + ln;
            if (n < L) bf[j] = *(const bf16x8*)(Tib + (size_t)n * K + k0 + q * 8);
            else bf[j] = (bf16x8){0, 0, 0, 0, 0, 0, 0, 0};
        }
#pragma unroll
        for (int i = 0; i < 4; i++)
#pragma unroll
            for (int j = 0; j < 4; j++)
                acc[i][j] = __builtin_amdgcn_mfma_f32_16x16x32_bf16(
                    af[i], bf[j], acc[i][j], 0, 0, 0);
    }
#pragma unroll
    for (int j = 0; j < 4; j++) {
        int col = bn + wn + j * 16 + ln;
        if (col >= L) continue;
#pragma unroll
        for (int i = 0; i < 4; i++) {
            int row0 = bm * 128 + wm + i * 16 + q * 4;
#pragma unroll
            for (int r = 0; r < 4; r++)
                Out[(size_t)(row0 + r) * L + col] = bfr(acc[i][j][r] * s);
        }
    }
}

// ---------------------------------------------------------------------------
// xqk3: per (b,h): S = Q^T [Kre|Kim] via 64x96x128 bf16 MFMA, tanh -> G.
// Qs pitch 136 (16B-aligned rows, 2-way bank alias), Bs stacked re/im.
__global__ __launch_bounds__(256) void xqk3(
    const unsigned short* __restrict__ XTQ, const unsigned short* __restrict__ XTK,
    unsigned* __restrict__ G) {
    __shared__ __align__(16) unsigned char sm[43520];
    unsigned short* Qs = (unsigned short*)sm;            // [64][136]
    unsigned short* Bs = (unsigned short*)(sm + 17408);  // [96][136]
    float* Ss = (float*)sm;                              // [64][100] alias
    const int b = blockIdx.x, h = blockIdx.y;
    const int tid = threadIdx.x;
    const int lane = tid & 63, wv = tid >> 6;
    const int wm = (wv & 1) * 32, wn = (wv >> 1) * 48;
    const int q = lane >> 4, ln = lane & 15;

    // stage Q rows (64 x 256B, contiguous per row)
    const uint4* Qg = (const uint4*)XTQ;
    for (int i = tid; i < 64 * 16; i += 256) {
        int x = i >> 4, c = i & 15;
        *(uint4*)(Qs + x * 136 + c * 8) = Qg[((size_t)(h * 64 + x) * 128 + b) * 16 + c];
    }
    // stage K -> stacked B: row y = (kr,-ki); row 48+y = (ki,kr)
    const unsigned* Ku = (const unsigned*)XTK;
    unsigned* Bu = (unsigned*)Bs;
    for (int i = tid; i < 48 * 64; i += 256) {
        int y = i >> 6, e = i & 63;
        unsigned v = Ku[((size_t)(h * 48 + y) * 128 + b) * 64 + e];
        Bu[y * 68 + e] = v ^ 0x80000000u;
        Bu[(48 + y) * 68 + e] = (v >> 16) | (v << 16);
    }
    __syncthreads();

    f32x4 acc[2][3];
#pragma unroll
    for (int i = 0; i < 2; i++)
#pragma unroll
        for (int j = 0; j < 3; j++) acc[i][j] = (f32x4){0.f, 0.f, 0.f, 0.f};

#pragma unroll
    for (int k0 = 0; k0 < 128; k0 += 32) {
        bf16x8 af[2], bf[3];
#pragma unroll
        for (int i = 0; i < 2; i++)
            af[i] = *(const bf16x8*)(Qs + (wm + i * 16 + ln) * 136 + k0 + q * 8);
#pragma unroll
        for (int j = 0; j < 3; j++)
            bf[j] = *(const bf16x8*)(Bs + (wn + j * 16 + ln) * 136 + k0 + q * 8);
#pragma unroll
        for (int i = 0; i < 2; i++)
#pragma unroll
            for (int j = 0; j < 3; j++)
                acc[i][j] = __builtin_amdgcn_mfma_f32_16x16x32_bf16(
                    af[i], bf[j], acc[i][j], 0, 0, 0);
    }
    __syncthreads();   // safe to alias Ss over Qs/Bs
#pragma unroll
    for (int j = 0; j < 3; j++) {
        int col = wn + j * 16 + ln;
#pragma unroll
        for (int i = 0; i < 2; i++) {
            int r0 = wm + i * 16 + q * 4;
#pragma unroll
            for (int r = 0; r < 4; r++)
                Ss[(r0 + r) * 100 + col] = acc[i][j][r];
        }
    }
    __syncthreads();
    for (int i = tid; i < 3072; i += 256) {
        int x = i / 48, y = i - x * 48;
        float re = Ss[x * 100 + y], im = Ss[x * 100 + 48 + y];
        float a2 = 2.f * re, b2 = 2.f * im;
        a2 = fminf(fmaxf(a2, -80.f), 80.f);
        float denom = coshf(a2) + cosf(b2);
        G[((size_t)(b * 8 + h) * 64 + x) * 48 + y] =
            pack2(sinhf(a2) / denom, sinf(b2) / denom);
    }
}

// ---------------------------------------------------------------------------
// xqkv3: per (b,h): V = G · B2 via 64x128x96 bf16 MFMA.
// A = G rows (bf16 pairs, direct global, 192B rows). B2[2e+q][2y+p] in LDS
// (pitch 104, 16B-aligned rows). Out VT[h][x][b][2e+p] via LDS restage.
__global__ __launch_bounds__(256) void xqkv3(
    const unsigned* __restrict__ G, const unsigned short* __restrict__ XTK,
    unsigned short* __restrict__ VT) {
    __shared__ __align__(16) unsigned char sm[26624];
    unsigned short* Bs = (unsigned short*)sm;   // [128][104]
    unsigned short* Vs = (unsigned short*)sm;   // [64][132] alias after MFMA
    const int b = blockIdx.x, h = blockIdx.y;
    const int tid = threadIdx.x;
    const int lane = tid & 63, wv = tid >> 6;
    const int wm = (wv & 1) * 32, wn = (wv >> 1) * 64;
    const int q = lane >> 4, ln = lane & 15;

    const unsigned* Ku = (const unsigned*)XTK;
    unsigned* Bu = (unsigned*)Bs;
    for (int i = tid; i < 48 * 64; i += 256) {
        int y = i >> 6, e = i & 63;
        unsigned v = Ku[((size_t)(h * 48 + y) * 128 + b) * 64 + e];
        Bu[(2 * e) * 52 + y] = v ^ 0x80000000u;          // (kr,-ki)
        Bu[(2 * e + 1) * 52 + y] = (v >> 16) | (v << 16); // (ki,kr)
    }
    __syncthreads();

    const unsigned short* Ag = (const unsigned short*)G + (size_t)(b * 8 + h) * 6144;
    f32x4 acc[2][4];
#pragma unroll
    for (int i = 0; i < 2; i++)
#pragma unroll
        for (int j = 0; j < 4; j++) acc[i][j] = (f32x4){0.f, 0.f, 0.f, 0.f};

#pragma unroll
    for (int k0 = 0; k0 < 96; k0 += 32) {
        bf16x8 af[2], bf[4];
#pragma unroll
        for (int i = 0; i < 2; i++)
            af[i] = *(const bf16x8*)(Ag + (wm + i * 16 + ln) * 96 + k0 + q * 8);
#pragma unroll
        for (int j = 0; j < 4; j++)
            bf[j] = *(const bf16x8*)(Bs + (wn + j * 16 + ln) * 104 + k0 + q * 8);
#pragma unroll
        for (int i = 0; i < 2; i++)
#pragma unroll
            for (int j = 0; j < 4; j++)
                acc[i][j] = __builtin_amdgcn_mfma_f32_16x16x32_bf16(
                    af[i], bf[j], acc[i][j], 0, 0, 0);
    }
    __syncthreads();   // alias Vs over Bs
#pragma unroll
    for (int j = 0; j < 4; j++) {
        int col = wn + j * 16 + ln;
#pragma unroll
        for (int i = 0; i < 2; i++) {
            int r0 = wm + i * 16 + q * 4;
#pragma unroll
            for (int r = 0; r < 4; r++)
                Vs[(r0 + r) * 132 + col] = bfr(acc[i][j][r]);
        }
    }
    __syncthreads();
    unsigned* Vu = (unsigned*)VT;
    for (int i = tid; i < 64 * 64; i += 256) {
        int x = i >> 6, dw = i & 63;
        Vu[((size_t)(h * 64 + x) * 128 + b) * 64 + dw] = *(unsigned*)&Vs[x * 132 + 2 * dw];
    }
}

// ---------------------------------------------------------------------------
// series_decomp (+ optional bf16 copy of seasonal out)
__global__ void decomp_kernel(const float* __restrict__ P, const float* __restrict__ Q,
                              float* __restrict__ SO, unsigned short* __restrict__ SOb,
                              float* __restrict__ TS, int L, int tmode) {
    int b = blockIdx.x, d0 = blockIdx.y * 64;
    __shared__ float s[144 * 64];
    for (int i = threadIdx.x; i < L * 64; i += 256) {
        int l = i >> 6, d = i & 63;
        size_t idx = ((size_t)b * L + l) * 512 + d0 + d;
        float v = P[idx];
        if (Q) v += Q[idx];
        s[i] = v;
    }
    __syncthreads();
    for (int i = threadIdx.x; i < L * 64; i += 256) {
        int l = i >> 6, d = i & 63;
        float sum = 0.f;
#pragma unroll
        for (int j = -12; j <= 12; j++) sum += s[iclamp(l + j, 0, L - 1) * 64 + d];
        float ma = sum * (1.0f / 25.0f);
        size_t idx = ((size_t)b * L + l) * 512 + d0 + d;
        float so = s[i] - ma;
        SO[idx] = so;
        if (SOb) SOb[idx] = bfr(so);
        if (tmode == 1) TS[idx] = ma;
        else if (tmode == 2) TS[idx] += ma;
    }
}

// ---------------------------------------------------------------------------
__global__ __launch_bounds__(256) void ln_rows_kernel(const float* __restrict__ in,
                                                      const float* __restrict__ w,
                                                      const float* __restrict__ bvec,
                                                      float* __restrict__ out) {
    size_t row = blockIdx.x;
    const float* p = in + row * 512;
    int t = threadIdx.x;
    float v0 = p[t], v1 = p[t + 256];
    float s = v0 + v1, s2 = v0 * v0 + v1 * v1;
    for (int o = 32; o > 0; o >>= 1) {
        s += __shfl_xor(s, o, 64);
        s2 += __shfl_xor(s2, o, 64);
    }
    __shared__ float rs[4], rs2[4];
    int wid = t >> 6;
    if ((t & 63) == 0) { rs[wid] = s; rs2[wid] = s2; }
    __syncthreads();
    s = rs[0] + rs[1] + rs[2] + rs[3];
    s2 = rs2[0] + rs2[1] + rs2[2] + rs2[3];
    float mu = s * (1.0f / 512.0f);
    float var = s2 * (1.0f / 512.0f) - mu * mu;
    float r = rsqrtf(var + 1e-5f);
    out[row * 512 + t] = (v0 - mu) * r * w[t] + bvec[t];
    out[row * 512 + t + 256] = (v1 - mu) * r * w[t + 256] + bvec[t + 256];
}

// timesub (+ optional bf16 copy)
__global__ void timesub_kernel(float* __restrict__ X, unsigned short* __restrict__ Xb,
                               int L) {
    int b = blockIdx.x, d0 = blockIdx.y * 64;
    __shared__ float tile[144 * 64];
    __shared__ float mean[64];
    for (int i = threadIdx.x; i < L * 64; i += 256) {
        int l = i >> 6, d = i & 63;
        tile[i] = X[((size_t)b * L + l) * 512 + d0 + d];
    }
    __syncthreads();
    if (threadIdx.x < 64) {
        float sm = 0.f;
        for (int l = 0; l < L; l++) sm += tile[l * 64 + threadIdx.x];
        mean[threadIdx.x] = sm / (float)L;
    }
    __syncthreads();
    for (int i = threadIdx.x; i < L * 64; i += 256) {
        int l = i >> 6, d = i & 63;
        size_t idx = ((size_t)b * L + l) * 512 + d0 + d;
        float v = tile[i] - mean[d];
        X[idx] = v;
        if (Xb) Xb[idx] = bfr(v);
    }
}

// ---------------------------------------------------------------------------
__global__ __launch_bounds__(256) void final_v2(
    const float* __restrict__ XL, const float* __restrict__ TS,
    const float* __restrict__ TI, const float* __restrict__ trend_w,
    const float* __restrict__ proj_w, const float* __restrict__ proj_b,
    float* __restrict__ out) {
    int blk = blockIdx.x;
    int b = blk / 96, lo = blk - b * 96;
    int l = lo + 48;
    int lm = l - 1;
    int lp = (l == 143) ? 0 : l + 1;
    const float* ts = TS + (size_t)b * 144 * 512;
    const float* r0 = ts + (size_t)lm * 512;
    const float* r1 = ts + (size_t)l * 512;
    const float* r2 = ts + (size_t)lp * 512;
    const float* xl = XL + ((size_t)b * 144 + l) * 512;
    int t = threadIdx.x;
    float p[7];
#pragma unroll
    for (int c = 0; c < 7; c++) p[c] = 0.f;
#pragma unroll
    for (int dd = 0; dd < 2; dd++) {
        int d = t + dd * 256;
        float a0 = r0[d], a1 = r1[d], a2 = r2[d], x = xl[d];
#pragma unroll
        for (int c = 0; c < 7; c++) {
            const float* tw = trend_w + ((size_t)c * 512 + d) * 3;
            float v = a0 * tw[0] + a1 * tw[1] + a2 * tw[2];
            v = fmaf(x, proj_w[c * 512 + d], v);
            p[c] += v;
        }
    }
#pragma unroll
    for (int o = 32; o > 0; o >>= 1)
#pragma unroll
        for (int c = 0; c < 7; c++) p[c] += __shfl_xor(p[c], o, 64);
    __shared__ float red[4][7];
    int wid = t >> 6;
    if ((t & 63) == 0)
#pragma unroll
        for (int c = 0; c < 7; c++) red[wid][c] = p[c];
    __syncthreads();
    if (t < 7) {
        float v = red[0][t] + red[1][t] + red[2][t] + red[3][t]
                + TI[((size_t)b * 144 + l) * 7 + t] + proj_b[t];
        out[(size_t)blk * 7 + t] = v;
    }
}

// ---------------------------------------------------------------------------
static inline int cdiv(int a, int b) { return (a + b - 1) / b; }

extern "C" void kernel_launch(void* const* d_in, const int* in_sizes, int n_in,
                              void* d_out, int out_size, void* d_ws, size_t ws_size,
                              hipStream_t stream) {
    const float* x_enc      = (const float*)d_in[0];
    const float* x_mark_enc = (const float*)d_in[1];
    const float* x_mark_dec = (const float*)d_in[3];
    const float* enc_emb_conv_w = (const float*)d_in[4];
    const float* enc_emb_time_w = (const float*)d_in[5];
    const float* dec_emb_conv_w = (const float*)d_in[6];
    const float* dec_emb_time_w = (const float*)d_in[7];
    const float* enc_qw = (const float*)d_in[8];
    const float* enc_qb = (const float*)d_in[9];
    const float* enc_ow = (const float*)d_in[14];
    const float* enc_ob = (const float*)d_in[15];
    const float* enc_fw = (const float*)d_in[16];
    const float* enc_c1 = (const float*)d_in[17];
    const float* enc_c2 = (const float*)d_in[18];
    const float* enc_norm_w = (const float*)d_in[19];
    const float* enc_norm_b = (const float*)d_in[20];
    const float* ds_qw = (const float*)d_in[21];
    const float* ds_qb = (const float*)d_in[22];
    const float* ds_ow = (const float*)d_in[27];
    const float* ds_ob = (const float*)d_in[28];
    const float* ds_fw = (const float*)d_in[29];
    const float* dc_qw = (const float*)d_in[30];
    const float* dc_qb = (const float*)d_in[31];
    const float* dc_kw = (const float*)d_in[32];
    const float* dc_kb = (const float*)d_in[33];
    const float* dc_ow = (const float*)d_in[36];
    const float* dc_ob = (const float*)d_in[37];
    const float* dc_fw = (const float*)d_in[38];
    const float* dec_c1 = (const float*)d_in[39];
    const float* dec_c2 = (const float*)d_in[40];
    const float* dec_trend_w = (const float*)d_in[41];
    const float* dec_norm_w = (const float*)d_in[42];
    const float* dec_norm_b = (const float*)d_in[43];
    const float* proj_w = (const float*)d_in[44];
    const float* proj_b = (const float*)d_in[45];

    float* ws = (float*)d_ws;
    float* XD   = ws;
    float* TS   = ws + 9437184;
    float* XE   = ws + 18874368;
    unsigned short* XEb = (unsigned short*)(ws + 25165824);
    unsigned short* XDb = (unsigned short*)(ws + 28311552);
    float* SI   = ws + 33030144;
    float* TI   = ws + 33159168;
    float* TAB  = ws + 33288192;
    unsigned short* WF = (unsigned short*)(ws + 33320960);
    float* SC   = ws + 37646336;
    unsigned short* TdbE = (unsigned short*)(TAB);
    unsigned short* TdbD = (unsigned short*)(TAB + 6144);
    unsigned short* TibE = (unsigned short*)(TAB + 16384);
    unsigned short* TibD = (unsigned short*)(TAB + 20992);

    unsigned short* enc_qw_b = WF;
    unsigned short* enc_ow_b = WF + 524288;
    unsigned short* enc_c1_b = WF + 1048576;
    unsigned short* enc_c2_b = WF + 3145728;
    unsigned short* ds_qw_b  = WF + 5242880;
    unsigned short* ds_ow_b  = WF + 5505024;
    unsigned short* dc_qw_b  = WF + 5767168;
    unsigned short* dc_kw_b  = WF + 6029312;
    unsigned short* dc_ow_b  = WF + 6291456;
    unsigned short* dec_c1_b = WF + 6553600;
    unsigned short* dec_c2_b = WF + 7602176;

    const size_t need_bytes = (size_t)53768192 * sizeof(float);
    if (ws_size < need_bytes) {
        zero_out_kernel<<<cdiv(out_size, 256), 256, 0, stream>>>((float*)d_out, out_size);
        return;
    }

    auto conv = [&](const float* s, unsigned short* d, int n) {
        f2b<<<cdiv(n / 4, 256), 256, 0, stream>>>(s, d, n);
    };
    auto gemm = [&](const unsigned short* A, const unsigned short* W, const float* bias,
                    float* Cf, unsigned short* Cb, int rows, int N, int K,
                    int lda, int ldw, int gelu, int accum) {
        dim3 g(N / 128, rows / 128);
        gemm_bb<<<g, 256, 0, stream>>>(A, W, bias, Cf, Cb, N, K, lda, ldw, gelu, accum);
    };

    // ---- weight conversion
    conv(enc_qw, enc_qw_b, 524288);
    conv(enc_ow, enc_ow_b, 524288);
    conv(enc_c1, enc_c1_b, 2097152);
    conv(enc_c2, enc_c2_b, 2097152);
    conv(ds_qw, ds_qw_b, 262144);
    conv(ds_ow, ds_ow_b, 262144);
    conv(dc_qw, dc_qw_b, 262144);
    conv(dc_kw, dc_kw_b, 262144);
    conv(dc_ow, dc_ow_b, 262144);
    conv(dec_c1, dec_c1_b, 1048576);
    conv(dec_c2, dec_c2_b, 1048576);

    // ---- twiddle tables
    dtab_kernel<<<cdiv(128 * 96, 256), 256, 0, stream>>>(TdbE, 48, 96, 96);
    dtab_kernel<<<cdiv(128 * 160, 256), 256, 0, stream>>>(TdbD, 64, 144, 160);
    itab_kernel<<<cdiv(96 * 96, 256), 256, 0, stream>>>(TibE, 48, 96, 96);
    itab_kernel<<<cdiv(144 * 128, 256), 256, 0, stream>>>(TibD, 64, 144, 128);

    // ---- preprocess + encoder embed
    preprocess_kernel<<<cdiv(128 * 144 * 7, 256), 256, 0, stream>>>(x_enc, SI, TI);
    embed_kernel<<<cdiv(128 * 96 * 512, 256), 256, 0, stream>>>(
        x_enc, x_mark_enc, enc_emb_conv_w, enc_emb_time_w, XE, XEb, 96);

    // ---- encoder layers (M=48)
    for (int l = 0; l < 2; l++) {
        const unsigned short* qwb = enc_qw_b + (size_t)l * 262144;
        const float* qb = enc_qb + (size_t)l * 512;
        const unsigned short* owb = enc_ow_b + (size_t)l * 262144;
        const float* ob = enc_ob + (size_t)l * 512;
        const float* fw = enc_fw + (size_t)l * 8 * 64 * 64 * 48 * 2;
        const unsigned short* c1b = enc_c1_b + (size_t)l * 1048576;
        const unsigned short* c2b = enc_c2_b + (size_t)l * 1048576;
        unsigned short* Pq = (unsigned short*)(SC);
        unsigned short* XT = (unsigned short*)(SC + 3145728);
        unsigned short* WB = (unsigned short*)(SC + 6291456);
        unsigned short* Yp = (unsigned short*)(SC + 9437184);
        unsigned short* Tidb = (unsigned short*)(SC);
        float* To = SC + 3145728;

        gemm(XEb, qwb, qb, nullptr, Pq, 12288, 512, 512, 512, 512, 0, 0);
        dft_mfma2<<<dim3(1, 512), 256, 0, stream>>>(Pq, TdbE, XT, 96, 96, 48);
        wtrans3<<<dim3(16, 8), 256, 0, stream>>>(fw, WB, 48);
        mix_v2<<<dim3(48, 8), 256, 0, stream>>>(XT, WB, Yp, 48);
        idft_v2<<<dim3(1, 512), 256, 0, stream>>>(Yp, TibE, Tidb, 96, 96, 48, 1.f / 96.f);
        gemm(Tidb, owb, ob, To, nullptr, 12288, 512, 512, 512, 512, 0, 0);
        decomp_kernel<<<dim3(128, 8), 256, 0, stream>>>(XE, To, XE, XEb, nullptr, 96, 0);
        unsigned short* hid = (unsigned short*)(SC);
        gemm(XEb, c1b, nullptr, nullptr, hid, 12288, 2048, 512, 512, 512, 1, 0);
        gemm(hid, c2b, nullptr, TS, nullptr, 12288, 512, 2048, 2048, 2048, 0, 0);
        decomp_kernel<<<dim3(128, 8), 256, 0, stream>>>(XE, TS, XE, XEb, nullptr, 96, 0);
    }
    ln_rows_kernel<<<12288, 256, 0, stream>>>(XE, enc_norm_w, enc_norm_b, XE);
    timesub_kernel<<<dim3(128, 8), 256, 0, stream>>>(XE, XEb, 96);

    // ---- decoder embed
    embed_kernel<<<cdiv(128 * 144 * 512, 256), 256, 0, stream>>>(
        SI, x_mark_dec, dec_emb_conv_w, dec_emb_time_w, XD, XDb, 144);

    // ---- decoder self fourier block (M=64)
    {
        unsigned short* Pq = (unsigned short*)(SC);
        unsigned short* XT = (unsigned short*)(SC + 4718592);
        unsigned short* WB = (unsigned short*)(SC + 8912896);
        unsigned short* Yp = (unsigned short*)(SC);
        unsigned short* Tidb = (unsigned short*)(SC + 9437184);
        float* To = SC;

        gemm(XDb, ds_qw_b, ds_qb, nullptr, Pq, 18432, 512, 512, 512, 512, 0, 0);
        dft_mfma2<<<dim3(1, 512), 256, 0, stream>>>(Pq, TdbD, XT, 144, 160, 64);
        wtrans3<<<dim3(16, 8), 256, 0, stream>>>(ds_fw, WB, 64);
        mix_v2<<<dim3(64, 8), 256, 0, stream>>>(XT, WB, Yp, 64);
        idft_v2<<<dim3(2, 512), 256, 0, stream>>>(Yp, TibD, Tidb, 144, 128, 64, 1.f / 144.f);
        gemm(Tidb, ds_ow_b, ds_ob, To, nullptr, 18432, 512, 512, 512, 512, 0, 0);
        decomp_kernel<<<dim3(128, 8), 256, 0, stream>>>(XD, To, XD, XDb, TS, 144, 1);
    }

    // ---- cross attention
    {
        unsigned short* Pq  = (unsigned short*)(SC);
        unsigned short* XTQ = (unsigned short*)(SC + 4718592);
        unsigned short* Pk  = (unsigned short*)(SC);
        unsigned short* XTK = (unsigned short*)(SC + 8912896);
        unsigned* G         = (unsigned*)(SC);
        unsigned short* VT  = (unsigned short*)(SC + 3145728);
        unsigned short* WB  = (unsigned short*)(SC + 7340032);
        unsigned short* Yp  = (unsigned short*)(SC + 11534336);
        unsigned short* Tidb = (unsigned short*)(SC);
        float* To = SC + 4718592;

        gemm(XDb, dc_qw_b, dc_qb, nullptr, Pq, 18432, 512, 512, 512, 512, 0, 0);
        dft_mfma2<<<dim3(1, 512), 256, 0, stream>>>(Pq, TdbD, XTQ, 144, 160, 64);
        gemm(XEb, dc_kw_b, dc_kb, nullptr, Pk, 12288, 512, 512, 512, 512, 0, 0);
        dft_mfma2<<<dim3(1, 512), 256, 0, stream>>>(Pk, TdbE, XTK, 96, 96, 48);
        xqk3<<<dim3(128, 8), 256, 0, stream>>>(XTQ, XTK, G);
        xqkv3<<<dim3(128, 8), 256, 0, stream>>>(G, XTK, VT);
        wtrans3<<<dim3(16, 8), 256, 0, stream>>>(dc_fw, WB, 64);
        mix_v2<<<dim3(64, 8), 256, 0, stream>>>(VT, WB, Yp, 64);
        idft_v2<<<dim3(2, 512), 256, 0, stream>>>(Yp, TibD, Tidb, 144, 128, 64,
                                                  1.f / (144.f * 262144.f));
        gemm(Tidb, dc_ow_b, dc_ob, To, nullptr, 18432, 512, 512, 512, 512, 0, 0);
        decomp_kernel<<<dim3(128, 8), 256, 0, stream>>>(XD, To, XD, XDb, TS, 144, 2);
    }

    // ---- decoder FFN: 2 chunks of N=1024; hid bf16 in SC, fout aliases XE+XEb
    {
        unsigned short* hid = (unsigned short*)(SC);
        float* fout = XE;
        for (int j0 = 0; j0 < 2048; j0 += 1024) {
            gemm(XDb, dec_c1_b + (size_t)j0 * 512, nullptr, nullptr, hid,
                 18432, 1024, 512, 512, 512, 1, 0);
            gemm(hid, dec_c2_b + j0, nullptr, fout, nullptr,
                 18432, 512, 1024, 1024, 2048, 0, j0 > 0);
        }
        decomp_kernel<<<dim3(128, 8), 256, 0, stream>>>(XD, fout, XD, nullptr, TS, 144, 2);
    }

    // ---- final norm + trend conv + projection
    ln_rows_kernel<<<18432, 256, 0, stream>>>(XD, dec_norm_w, dec_norm_b, XD);
    timesub_kernel<<<dim3(128, 8), 256, 0, stream>>>(XD, nullptr, 144);
    final_v2<<<12288, 256, 0, stream>>>(
        XD, TS, TI, dec_trend_w, proj_w, proj_b, (float*)d_out);
}